// Round 14
// baseline (291.599 us; speedup 1.0000x reference)
//
#include <hip/hip_runtime.h>
#include <hip/hip_bf16.h>
#include <stdint.h>
#include <math.h>

// Problem constants
#define N_TOK 48000     // 32*1500
#define DIMS  256
#define KCB   2048
// 1-pass bf16 approx score error: diff std ~6e-3, max over 1e8 pairs ~0.037.
// Packed-u32: score+32 (all in (0,64)), truncate low 11 bits -> quant error
// <= 64*2^-12 = 0.0156/side. WND = 0.10 >= 0.037 + 2*0.0156 with margin.
// True winner's packed score >= best - WND. Candidates = per-tile top-2; if a
// tile's THIRD value is in-window the winner may be unstored -> full re-scan.
#define WND 0.10f
#define BIAS 32.0f

typedef __attribute__((ext_vector_type(8))) short bf16x8;
typedef __attribute__((ext_vector_type(4))) float f32x4;
typedef __attribute__((ext_vector_type(8))) unsigned short u16x8;

// ---------------- bf16 helpers (explicit RNE) ----------------
__device__ __forceinline__ unsigned short bf16rn(float f) {
  uint32_t u = __float_as_uint(f);
  uint32_t r = (u + 0x7FFFu + ((u >> 16) & 1u)) >> 16;
  return (unsigned short)r;
}

// ---------------- packed sortable score ----------------
// input f = score + BIAS (>=0 after clamp): positive-float bits are monotone.
// high21 = value bits, low11 = 2047-k (ties -> smaller k wins at larger u32).
__device__ __forceinline__ uint32_t packBiased(float fb, uint32_t invIdx) {
  float c = fmaxf(fb, 0.0f);
  return (__float_as_uint(c) & ~0x7FFu) | invIdx;
}
__device__ __forceinline__ uint32_t packThrBiased(float fb) {
  float c = fmaxf(fb, 0.0f);
  return __float_as_uint(c) & ~0x7FFu;
}
__device__ __forceinline__ float unpackBiased(uint32_t u) {   // returns score+BIAS
  return __uint_as_float(u & ~0x7FFu);
}
// branch-free sorted top-3 insert (b>=s>=t), 5 u32 min/max ops
__device__ __forceinline__ void ins3u(uint32_t& b, uint32_t& s, uint32_t& t, uint32_t v) {
  uint32_t lo = min(b, v);
  b = max(b, v);
  uint32_t lo2 = min(s, lo);
  s = max(s, lo);
  t = max(t, lo2);
}

// ---------------- Threefry-2x32 (matches jax._src.prng, partitionable) ----------------
__device__ inline void tf2x32(uint32_t k0, uint32_t k1, uint32_t c0, uint32_t c1,
                              uint32_t& o0, uint32_t& o1) {
  uint32_t ks2 = k0 ^ k1 ^ 0x1BD11BDAu;
  uint32_t x0 = c0 + k0, x1 = c1 + k1;
#define TF_R(r) { x0 += x1; x1 = (x1 << (r)) | (x1 >> (32 - (r))); x1 ^= x0; }
  TF_R(13) TF_R(15) TF_R(26) TF_R(6)
  x0 += k1; x1 += ks2 + 1u;
  TF_R(17) TF_R(29) TF_R(16) TF_R(24)
  x0 += ks2; x1 += k0 + 2u;
  TF_R(13) TF_R(15) TF_R(26) TF_R(6)
  x0 += k0; x1 += k1 + 3u;
  TF_R(17) TF_R(29) TF_R(16) TF_R(24)
  x0 += k1; x1 += ks2 + 4u;
  TF_R(13) TF_R(15) TF_R(26) TF_R(6)
  x0 += ks2; x1 += k0 + 5u;
#undef TF_R
  o0 = x0; o1 = x1;
}

__device__ inline void get_round_key(int round, uint32_t& ka, uint32_t& kb) {
  const uint32_t b0 = 0u, b1 = 1u;  // jax.random.key(1) -> (0,1)
  uint32_t K1a, K1b, S1a, S1b;
  tf2x32(b0, b1, 0u, 0u, K1a, K1b);
  tf2x32(b0, b1, 0u, 1u, S1a, S1b);
  if (round == 1) { ka = S1a; kb = S1b; return; }
  uint32_t S2a, S2b;
  tf2x32(K1a, K1b, 0u, 1u, S2a, S2b);
  ka = S2a; kb = S2b;
}

__device__ inline uint32_t gen_key(int round, uint32_t i) {
  uint32_t ka, kb, o0, o1;
  get_round_key(round, ka, kb);
  tf2x32(ka, kb, 0u, i, o0, o1);
  return o0 ^ o1;
}

// ---------------- global_load_lds wrapper (16B) ----------------
__device__ __forceinline__ void gload_lds16(const void* g, void* l) {
  __builtin_amdgcn_global_load_lds(
      (const __attribute__((address_space(1))) uint32_t*)g,
      (__attribute__((address_space(3))) uint32_t*)l, 16, 0, 0);
}

// ---------------- fused: f32->bf16 split (x, embed) + e2 terms ----------------
// e2f[k] = BIAS - e2[k]  (so fmaf(2, dot, e2f) = score + BIAS directly)
__global__ void e2split(const float* __restrict__ x, unsigned short* __restrict__ xh,
                        const float* __restrict__ embed, unsigned short* __restrict__ eh,
                        float* __restrict__ e2f, double* __restrict__ e2d) {
  const int nx = N_TOK * DIMS / 8;
  const int ne = KCB * DIMS / 8;
  int i = blockIdx.x * blockDim.x + threadIdx.x;
  if (i < nx + ne) {
    const float* src; unsigned short* dst; int j;
    if (i < nx) { src = x; dst = xh; j = i; }
    else { src = embed; dst = eh; j = i - nx; }
    float4 a = ((const float4*)src)[j * 2];
    float4 b = ((const float4*)src)[j * 2 + 1];
    float v[8] = {a.x, a.y, a.z, a.w, b.x, b.y, b.z, b.w};
    u16x8 h;
#pragma unroll
    for (int q = 0; q < 8; ++q) h[q] = bf16rn(v[q]);
    *(u16x8*)&dst[(size_t)j * 8] = h;
    return;
  }
  int k = i - (nx + ne);
  if (k < KCB) {
    const float4* er = (const float4*)(embed + (size_t)k * DIMS);
    float s = 0.f;
    double sd = 0.0;
    for (int c = 0; c < DIMS / 4; ++c) {
      float4 v = er[c];
      s = fmaf(v.x, v.x, s); s = fmaf(v.y, v.y, s);
      s = fmaf(v.z, v.z, s); s = fmaf(v.w, v.w, s);
      sd += (double)v.x * v.x + (double)v.y * v.y
          + (double)v.z * v.z + (double)v.w * v.w;
    }
    e2f[k] = BIAS - s;
    e2d[k] = sd;
  }
}

// ---------------- MFMA distance top-3 (single bf16 pass, packed epilogue) ----------------
// approx score+BIAS = 2*(xh.eh) + e2f[k]; 128x256 tile, BK=32, 8 steps,
// double-buffered LDS, 3 blocks/CU (LDS 3x50688 = 148.5KB <= 160KB).
// Bank swizzle (both-sides involution): chunk ^= (row>>1)&3.
// Epilogue: biased packed u32 scores (3-op pack), sort3 init + 5 inserts,
// LDS table reduce split across all 256 threads.
__global__ __launch_bounds__(256, 3) void dist_mfma(
    const unsigned short* __restrict__ xh, const unsigned short* __restrict__ eh,
    const float* __restrict__ e2f,
    uint32_t* __restrict__ pb, uint32_t* __restrict__ ps, uint32_t* __restrict__ pt)
{
  // staging (49152 B) and reduction table (128*99*4 = 50688 B) alias
  __shared__ __align__(16) char smem[50688];
  short (*As)[128 * 32] = (short(*)[128 * 32])smem;            // 2 x 8 KB
  short (*Bs)[256 * 32] = (short(*)[256 * 32])(smem + 16384);  // 2 x 16 KB
  uint32_t* red = (uint32_t*)smem;                             // [128][99] u32

  const int tid = threadIdx.x;
  const int lane = tid & 63, w = tid >> 6;
  const int wr = w >> 1, wc = w & 1;      // wave tile: 64 rows x 128 cols
  const int l15 = lane & 15, lg = lane >> 4;

  // XCD grouping: the 8 y-tiles sharing an x-tile get bids == same (mod 8),
  // spaced 8 apart -> same XCD L2 -> x-tile fetched from HBM once per XCD.
  int bx, by;
  {
    const int bid = blockIdx.x;
    if (bid < 2944) { int g = bid >> 6, r = bid & 63; bx = g * 8 + (r & 7); by = r >> 3; }
    else            { int t2 = bid - 2944; bx = 368 + (t2 % 7); by = t2 / 7; }
  }
  const int n0 = bx * 128;   // token tile base
  const int c0 = by * 256;   // code tile base

  f32x4 acc[4][8];
#pragma unroll
  for (int mf = 0; mf < 4; ++mf)
#pragma unroll
    for (int nf = 0; nf < 8; ++nf) acc[mf][nf] = (f32x4){0.f, 0.f, 0.f, 0.f};

  // stage step t into buffer t&1 (linear LDS dest; source pre-swizzled)
  auto stage = [&](int t) {
    const int d0 = t << 5;     // d-chunk of 32 shorts
    const int q = t & 1;
#pragma unroll
    for (int i = 0; i < 2; ++i) {
      const int c = i * 256 + tid;
      const int row = c >> 2;
      const int sc = ((c & 3) ^ ((row >> 1) & 3)) << 3;   // swizzled source chunk
      gload_lds16(xh + (size_t)(n0 + row) * DIMS + d0 + sc, (void*)&As[q][c * 8]);
    }
#pragma unroll
    for (int i = 0; i < 4; ++i) {
      const int c = i * 256 + tid;
      const int row = c >> 2;
      const int sc = ((c & 3) ^ ((row >> 1) & 3)) << 3;
      gload_lds16(eh + (size_t)(c0 + row) * DIMS + d0 + sc, (void*)&Bs[q][c * 8]);
    }
  };

  stage(0);
  __syncthreads();   // buf0 ready

#pragma unroll 1
  for (int t = 0; t < 8; ++t) {
    if (t < 7) stage(t + 1);         // issue next-step loads (overlap w/ compute)
    const int q = t & 1;
    bf16x8 af[4], bfv[8];
#pragma unroll
    for (int mf = 0; mf < 4; ++mf) {
      const int r = wr * 64 + mf * 16 + l15;
      af[mf] = *(const bf16x8*)&As[q][r * 32 + ((lg ^ ((r >> 1) & 3)) << 3)];
    }
#pragma unroll
    for (int nf = 0; nf < 8; ++nf) {
      const int r = wc * 128 + nf * 16 + l15;
      bfv[nf] = *(const bf16x8*)&Bs[q][r * 32 + ((lg ^ ((r >> 1) & 3)) << 3)];
    }
#pragma unroll
    for (int mf = 0; mf < 4; ++mf)
#pragma unroll
      for (int nf = 0; nf < 8; ++nf)
        acc[mf][nf] = __builtin_amdgcn_mfma_f32_16x16x32_bf16(
            af[mf], bfv[nf], acc[mf][nf], 0, 0, 0);
    __syncthreads();                 // staged loads drained + rw hazards
  }
  // K-loop done; last barrier above makes staging LDS safe to reuse as `red`.

  float e2v[8];
  uint32_t inv[8];
#pragma unroll
  for (int nf = 0; nf < 8; ++nf) {
    int k = c0 + wc * 128 + nf * 16 + l15;
    e2v[nf] = e2f[k];
    inv[nf] = 2047u - (uint32_t)k;
  }

  const int colbase = wc * 16 + l15;
#pragma unroll
  for (int mf = 0; mf < 4; ++mf) {
#pragma unroll
    for (int reg = 0; reg < 4; ++reg) {
      uint32_t p0 = packBiased(fmaf(2.f, acc[mf][0][reg], e2v[0]), inv[0]);
      uint32_t p1 = packBiased(fmaf(2.f, acc[mf][1][reg], e2v[1]), inv[1]);
      uint32_t p2 = packBiased(fmaf(2.f, acc[mf][2][reg], e2v[2]), inv[2]);
      // sort3 init (6 ops, exact)
      uint32_t h1 = max(p0, p1), l1 = min(p0, p1);
      uint32_t b  = max(h1, p2), m  = min(h1, p2);
      uint32_t s  = max(l1, m),  t3 = min(l1, m);
#pragma unroll
      for (int nf = 3; nf < 8; ++nf) {
        float f = fmaf(2.f, acc[mf][nf][reg], e2v[nf]);
        ins3u(b, s, t3, packBiased(f, inv[nf]));
      }
      const int row = wr * 64 + mf * 16 + lg * 4 + reg;
      uint32_t* p = &red[row * 99 + colbase * 3];
      p[0] = b; p[1] = s; p[2] = t3;
    }
  }
  __syncthreads();
  {
    const int row = tid >> 1, half = tid & 1;
    uint32_t b = 0u, s = 0u, t3 = 0u;
    const uint32_t* p = &red[row * 99 + half * 48];
#pragma unroll 4
    for (int c = 0; c < 48; ++c) ins3u(b, s, t3, p[c]);
    if (half) {
      uint32_t* q = &red[row * 99 + 96];
      q[0] = b; q[1] = s; q[2] = t3;
    }
    __syncthreads();
    if (!half) {
      const uint32_t* q = &red[row * 99 + 96];
      ins3u(b, s, t3, q[0]);
      ins3u(b, s, t3, q[1]);
      ins3u(b, s, t3, q[2]);
      size_t o = (size_t)by * N_TOK + n0 + row;
      pb[o] = b; ps[o] = s; pt[o] = t3;
    }
  }
}

// ---------------- merge 8 column-tile partials + candidate collection ----------------
__global__ void merge8(const uint32_t* __restrict__ pb, const uint32_t* __restrict__ ps,
                       const uint32_t* __restrict__ pt,
                       int* __restrict__ ind,
                       int* __restrict__ candRows, int* __restrict__ candIdx,
                       int* __restrict__ candCnt, int* __restrict__ listC,
                       uint32_t* __restrict__ cntA, uint32_t* __restrict__ cntC) {
  int n = blockIdx.x * blockDim.x + threadIdx.x;
  if (n >= N_TOK) return;
  uint32_t tb[8], tsv[8], ttv[8];
#pragma unroll
  for (int tt = 0; tt < 8; ++tt) {
    size_t o = (size_t)tt * N_TOK + n;
    tb[tt] = pb[o]; tsv[tt] = ps[o]; ttv[tt] = pt[o];
  }
  uint32_t best = tb[0];
#pragma unroll
  for (int tt = 1; tt < 8; ++tt) best = max(best, tb[tt]);
  ind[n] = 2047 - (int)(best & 0x7FFu);   // provisional winner
  const uint32_t thr = packThrBiased(unpackBiased(best) - WND);
  int m = 0; bool full = false;
#pragma unroll
  for (int tt = 0; tt < 8; ++tt) {
    m += (tb[tt] >= thr) + (tsv[tt] >= thr);
    full = full || (ttv[tt] >= thr);   // a tile's unstored 3rd+ could be in-window
  }
  if (full) {
    listC[atomicAdd(cntC, 1u)] = n;
  } else if (m > 1) {
    uint32_t i = atomicAdd(cntA, 1u);
    candRows[i] = n; candCnt[i] = m;
    int j = 0;
#pragma unroll
    for (int tt = 0; tt < 8; ++tt) {
      if (tb[tt]  >= thr) candIdx[(size_t)i * 16 + (j++)] = 2047 - (int)(tb[tt]  & 0x7FFu);
      if (tsv[tt] >= thr) candIdx[(size_t)i * 16 + (j++)] = 2047 - (int)(tsv[tt] & 0x7FFu);
    }
  }
}

// ---------------- wave-per-row f64 candidate decider ----------------
__global__ void refine_cand(const float* __restrict__ x, const float* __restrict__ embed,
                            const double* __restrict__ e2d,
                            const int* __restrict__ candRows, const int* __restrict__ candIdx,
                            const int* __restrict__ candCnt, const uint32_t* __restrict__ cntA,
                            int* __restrict__ ind) {
  const uint32_t nA = cntA[0];
  const int lane = threadIdx.x & 63;
  const uint32_t wid = (blockIdx.x * blockDim.x + threadIdx.x) >> 6;
  const uint32_t nw = (gridDim.x * blockDim.x) >> 6;
  for (uint32_t i = wid; i < nA; i += nw) {
    const int n = candRows[i];
    const int m = candCnt[i];
    float4 xv = ((const float4*)x)[(size_t)n * 64 + lane];
    double best = -1e300; int bk = 0x7fffffff;
    for (int j = 0; j < m; ++j) {
      int k = candIdx[(size_t)i * 16 + j];
      float4 e4 = ((const float4*)embed)[(size_t)k * 64 + lane];
      double d = (double)xv.x * e4.x + (double)xv.y * e4.y
               + (double)xv.z * e4.z + (double)xv.w * e4.w;
#pragma unroll
      for (int mm = 1; mm < 64; mm <<= 1) d += __shfl_xor(d, mm);
      double v = 2.0 * d - e2d[k];
      if (v > best || (v == best && k < bk)) { best = v; bk = k; }
    }
    if (lane == 0) ind[n] = bk;
  }
}

// ---------------- full f64 re-scan, one row per block (rare) ----------------
__global__ void refine_fullC(const float* __restrict__ x, const float* __restrict__ embed,
                             const double* __restrict__ e2d,
                             const int* __restrict__ listC, const uint32_t* __restrict__ cntC,
                             int* __restrict__ ind) {
  __shared__ double xd[DIMS];
  __shared__ double rv[256];
  __shared__ int    rk[256];
  const int tid = threadIdx.x;
  const uint32_t nC = cntC[0];
  for (uint32_t it = blockIdx.x; it < nC; it += gridDim.x) {
    const int n = listC[it];
    __syncthreads();
    xd[tid] = (double)x[(size_t)n * DIMS + tid];
    __syncthreads();
    double best = -1e300; int bk = 0x7fffffff;
    for (int k = tid; k < KCB; k += 256) {
      const float4* er = (const float4*)(embed + (size_t)k * DIMS);
      double a0 = 0.0, a1 = 0.0, a2 = 0.0, a3 = 0.0;   // ILP-4 chains
      for (int c = 0; c < 64; c += 4) {
        float4 ea = er[c], eb = er[c + 1], ec = er[c + 2], ed = er[c + 3];
        int d = c * 4;
        a0 += xd[d + 0] * ea.x + xd[d + 1] * ea.y + xd[d + 2] * ea.z + xd[d + 3] * ea.w;
        a1 += xd[d + 4] * eb.x + xd[d + 5] * eb.y + xd[d + 6] * eb.z + xd[d + 7] * eb.w;
        a2 += xd[d + 8] * ec.x + xd[d + 9] * ec.y + xd[d + 10] * ec.z + xd[d + 11] * ec.w;
        a3 += xd[d + 12] * ed.x + xd[d + 13] * ed.y + xd[d + 14] * ed.z + xd[d + 15] * ed.w;
      }
      double v = 2.0 * (a0 + a1 + a2 + a3) - e2d[k];
      if (v > best || (v == best && k < bk)) { best = v; bk = k; }
    }
    rv[tid] = best; rk[tid] = bk;
    __syncthreads();
    for (int s = 128; s > 0; s >>= 1) {
      if (tid < s) {
        double v2 = rv[tid + s]; int k2 = rk[tid + s];
        if (v2 > rv[tid] || (v2 == rv[tid] && k2 < rk[tid])) { rv[tid] = v2; rk[tid] = k2; }
      }
      __syncthreads();
    }
    if (tid == 0) ind[n] = rk[0];
  }
}

// ---------------- quantize gather + codes + token histogram ----------------
__global__ void gather_q(const float* __restrict__ embed, const int* __restrict__ ind,
                         float* __restrict__ outq, float* __restrict__ outcodes,
                         uint32_t* __restrict__ cntTok) {
  int idx = blockIdx.x * blockDim.x + threadIdx.x;   // over N_TOK*64 float4s
  if (idx >= N_TOK * 64) return;
  int n = idx >> 6, c = idx & 63;
  int k = ind[n];
  ((float4*)outq)[idx] = ((const float4*)embed)[(size_t)k * 64 + c];
  if (c == 0) { outcodes[n] = (float)k; atomicAdd(&cntTok[k], 1u); }
}

// ---------------- token-count scan + EMA stats (fused, 1 block) ----------------
__global__ void scan_tok_ema(const uint32_t* __restrict__ cntTok, uint32_t* __restrict__ tokBase,
                             uint32_t* __restrict__ tokCur,
                             const float* __restrict__ cs, float* __restrict__ out_ncs,
                             int* __restrict__ expired, double* __restrict__ nsum) {
  __shared__ uint32_t buf[2][2048];
  __shared__ double sd[1024];
  int t = threadIdx.x;   // 1024
  double local = 0.0;
  for (int q = 0; q < 2; ++q) {
    int i = t + q * 1024;
    uint32_t c = cntTok[i];
    buf[0][i] = c;
    tokCur[i] = 0;
    double v = 0.99 * (double)cs[i] + 0.01 * (double)c;
    out_ncs[i] = (float)v;
    expired[i] = (v < 2.0) ? 1 : 0;
    local += v;
  }
  sd[t] = local;
  __syncthreads();
  int src = 0;
  for (int off = 1; off < 2048; off <<= 1) {
    for (int q = 0; q < 2; ++q) {
      int i = t + q * 1024;
      uint32_t v = buf[src][i];
      if (i >= off) v += buf[src][i - off];
      buf[src ^ 1][i] = v;
    }
    src ^= 1; __syncthreads();
  }
  for (int q = 0; q < 2; ++q) {
    int i = t + q * 1024;
    tokBase[i] = buf[src][i] - cntTok[i];   // exclusive
  }
  for (int s = 512; s > 0; s >>= 1) { if (t < s) sd[t] += sd[t + s]; __syncthreads(); }
  if (t == 0) nsum[0] = sd[0];
}

// ---------------- scatter token ids into code-major buckets ----------------
__global__ void scatter_tok(const int* __restrict__ ind, const uint32_t* __restrict__ tokBase,
                            uint32_t* __restrict__ cursor, uint32_t* __restrict__ tokBucket) {
  int n = blockIdx.x * blockDim.x + threadIdx.x;
  if (n >= N_TOK) return;
  int k = ind[n];
  uint32_t p = atomicAdd(&cursor[k], 1u);
  tokBucket[tokBase[k] + p] = (uint32_t)n;
}

// ---------------- esum[k] = sum of x rows assigned to k (wave per code) ----------------
__global__ void esum_bucket(const float* __restrict__ x, const uint32_t* __restrict__ tokBase,
                            const uint32_t* __restrict__ cntTok,
                            const uint32_t* __restrict__ tokBucket,
                            float* __restrict__ esum) {
  const uint32_t wv = (blockIdx.x * blockDim.x + threadIdx.x) >> 6;
  if (wv >= KCB) return;
  const int lane = threadIdx.x & 63;
  const uint32_t base = tokBase[wv], cnt = cntTok[wv];
  float4 a0 = {0.f, 0.f, 0.f, 0.f}, a1 = {0.f, 0.f, 0.f, 0.f};
  uint32_t i = 0;
  for (; i + 2 <= cnt; i += 2) {
    uint32_t n0 = tokBucket[base + i], n1 = tokBucket[base + i + 1];
    float4 v0 = ((const float4*)x)[(size_t)n0 * 64 + lane];
    float4 v1 = ((const float4*)x)[(size_t)n1 * 64 + lane];
    a0.x += v0.x; a0.y += v0.y; a0.z += v0.z; a0.w += v0.w;
    a1.x += v1.x; a1.y += v1.y; a1.z += v1.z; a1.w += v1.w;
  }
  if (i < cnt) {
    uint32_t n0 = tokBucket[base + i];
    float4 v0 = ((const float4*)x)[(size_t)n0 * 64 + lane];
    a0.x += v0.x; a0.y += v0.y; a0.z += v0.z; a0.w += v0.w;
  }
  float4 r; r.x = a0.x + a1.x; r.y = a0.y + a1.y; r.z = a0.z + a1.z; r.w = a0.w + a1.w;
  ((float4*)esum)[(size_t)wv * 64 + lane] = r;
}

// ---------------- new_embed_avg + new_embed ----------------
__global__ void final_embed(const float* __restrict__ x, const float* __restrict__ cs,
                            const uint32_t* __restrict__ cntTok,
                            const float* __restrict__ eavg, const float* __restrict__ esum,
                            const int* __restrict__ expired, const double* __restrict__ nsum,
                            const uint32_t* __restrict__ perm,
                            float* __restrict__ out_eavg, float* __restrict__ out_ne) {
  int idx = blockIdx.x * blockDim.x + threadIdx.x;   // over KCB*64 float4s
  if (idx >= KCB * 64) return;
  int k = idx >> 6, c = idx & 63;
  float4 ea = ((const float4*)eavg)[idx];
  float4 es = ((const float4*)esum)[idx];
  double ax = 0.99 * (double)ea.x + 0.01 * (double)es.x;
  double ay = 0.99 * (double)ea.y + 0.01 * (double)es.y;
  double az = 0.99 * (double)ea.z + 0.01 * (double)es.z;
  double aw = 0.99 * (double)ea.w + 0.01 * (double)es.w;
  float4 nv; nv.x = (float)ax; nv.y = (float)ay; nv.z = (float)az; nv.w = (float)aw;
  ((float4*)out_eavg)[idx] = nv;
  float4 r;
  if (expired[k]) {
    r = ((const float4*)x)[(size_t)perm[k] * 64 + c];
  } else {
    double ncs = 0.99 * (double)cs[k] + 0.01 * (double)cntTok[k];
    double n = nsum[0];
    double sm = (ncs + 1e-5) / (n + 2048.0 * 1e-5) * n;
    r.x = (float)(ax / sm); r.y = (float)(ay / sm);
    r.z = (float)(az / sm); r.w = (float)(aw / sm);
  }
  ((float4*)out_ne)[idx] = r;
}

// ---------------- permutation pipeline (stable sort by random keys) ----------------
// Both rounds' keys are pure functions of the index -> compute together.
__global__ void keys_both(uint32_t* __restrict__ keys1, uint32_t* __restrict__ keys2,
                          uint32_t* __restrict__ bcount1, uint32_t* __restrict__ bcount2) {
  int i = blockIdx.x * blockDim.x + threadIdx.x;
  if (i >= N_TOK) return;
  uint32_t k1 = gen_key(1, (uint32_t)i);
  uint32_t k2 = gen_key(2, (uint32_t)i);
  keys1[i] = k1; keys2[i] = k2;
  atomicAdd(&bcount1[k1 >> 21], 1u);
  atomicAdd(&bcount2[k2 >> 21], 1u);
}

// block 0 scans hist1 (+zero cursor1), block 1 scans hist2 (+zero cursor2)
__global__ void scan_both(const uint32_t* __restrict__ in1, uint32_t* __restrict__ out1,
                          uint32_t* __restrict__ cur1,
                          const uint32_t* __restrict__ in2, uint32_t* __restrict__ out2,
                          uint32_t* __restrict__ cur2) {
  const uint32_t* in = blockIdx.x ? in2 : in1;
  uint32_t* out = blockIdx.x ? out2 : out1;
  uint32_t* cz = blockIdx.x ? cur2 : cur1;
  __shared__ uint32_t buf[2][2048];
  int t = threadIdx.x;   // 1024
  for (int q = 0; q < 2; ++q) buf[0][t + q * 1024] = in[t + q * 1024];
  cz[t] = 0; cz[t + 1024] = 0;
  __syncthreads();
  int src = 0;
  for (int off = 1; off < 2048; off <<= 1) {
    for (int q = 0; q < 2; ++q) {
      int i = t + q * 1024;
      uint32_t v = buf[src][i];
      if (i >= off) v += buf[src][i - off];
      buf[src ^ 1][i] = v;
    }
    src ^= 1; __syncthreads();
  }
  for (int q = 0; q < 2; ++q) {
    int i = t + q * 1024;
    out[i] = buf[src][i] - in[i];   // exclusive
  }
}

// round-1 scatter: value == original position (input is iota)
__global__ void scatter1(const uint32_t* __restrict__ keys1, const uint32_t* __restrict__ bbase1,
                         uint32_t* __restrict__ cursor1,
                         uint32_t* __restrict__ bkey, uint32_t* __restrict__ bval) {
  int i = blockIdx.x * blockDim.x + threadIdx.x;
  if (i >= N_TOK) return;
  uint32_t k = keys1[i];
  uint32_t b = k >> 21;
  uint32_t p = atomicAdd(&cursor1[b], 1u);
  uint32_t s = bbase1[b] + p;
  bkey[s] = k; bval[s] = (uint32_t)i;   // value == tie-break position for round 1
}

// rank round-1 elements (stable by (key,pos)) and scatter directly into
// round-2 buckets: sorted position p gets round-2 key keys2[p].
__global__ void rank1_scatter2(const uint32_t* __restrict__ bkey, const uint32_t* __restrict__ bval,
                               const uint32_t* __restrict__ bbase1, const uint32_t* __restrict__ bcount1,
                               const uint32_t* __restrict__ keys2,
                               const uint32_t* __restrict__ bbase2, uint32_t* __restrict__ cursor2,
                               uint32_t* __restrict__ bkey2, uint32_t* __restrict__ bval2,
                               uint32_t* __restrict__ bpos2) {
  int b = blockIdx.x;
  uint32_t base = bbase1[b], cnt = bcount1[b];
  for (uint32_t t = threadIdx.x; t < cnt; t += blockDim.x) {
    uint32_t k = bkey[base + t], pv = bval[base + t];
    uint32_t r = 0;
    for (uint32_t j = 0; j < cnt; ++j) {
      uint32_t kj = bkey[base + j], pj = bval[base + j];
      r += (kj < k) | ((kj == k) & (pj < pv));
    }
    uint32_t p = base + r;          // global round-1 sorted position
    uint32_t k2 = keys2[p];
    uint32_t b2 = k2 >> 21;
    uint32_t q = atomicAdd(&cursor2[b2], 1u);
    uint32_t s = bbase2[b2] + q;
    bkey2[s] = k2; bval2[s] = pv; bpos2[s] = p;
  }
}

// round-2 rank; only output positions < KCB are consumed (perm[0..2047])
__global__ void rank2(const uint32_t* __restrict__ bkey2, const uint32_t* __restrict__ bval2,
                      const uint32_t* __restrict__ bpos2,
                      const uint32_t* __restrict__ bbase2, const uint32_t* __restrict__ bcount2,
                      uint32_t* __restrict__ perm) {
  int b = blockIdx.x;
  uint32_t base = bbase2[b];
  if (base >= KCB) return;          // every element lands at position >= 2048
  uint32_t cnt = bcount2[b];
  for (uint32_t t = threadIdx.x; t < cnt; t += blockDim.x) {
    uint32_t k = bkey2[base + t], p = bpos2[base + t];
    uint32_t r = 0;
    for (uint32_t j = 0; j < cnt; ++j) {
      uint32_t kj = bkey2[base + j], pj = bpos2[base + j];
      r += (kj < k) | ((kj == k) & (pj < p));
    }
    uint32_t pos = base + r;
    if (pos < KCB) perm[pos] = bval2[base + t];
  }
}

// ---------------- launch ----------------
extern "C" void kernel_launch(void* const* d_in, const int* in_sizes, int n_in,
                              void* d_out, int out_size, void* d_ws, size_t ws_size,
                              hipStream_t stream) {
  const float* x     = (const float*)d_in[0];
  const float* embed = (const float*)d_in[1];
  const float* cs    = (const float*)d_in[2];
  const float* eavg  = (const float*)d_in[3];

  float* out = (float*)d_out;
  float* outQ    = out;                  // 12,288,000
  float* outC    = out + 12288000;       // 48,000
  float* outNCS  = out + 12336000;       // 2,048
  float* outEAVG = out + 12338048;       // 524,288
  float* outNE   = out + 12862336;       // 524,288

  char* w = (char*)d_ws;
  size_t off = 0;
  auto alloc = [&](size_t bytes) -> void* {
    void* p = w + off; off += (bytes + 255) & ~(size_t)255; return p;
  };
  unsigned short* xh = (unsigned short*)alloc((size_t)N_TOK * DIMS * 2);
  unsigned short* eh = (unsigned short*)alloc((size_t)KCB * DIMS * 2);
  float*    e2f     = (float*)alloc(KCB * 4);
  double*   e2d     = (double*)alloc(KCB * 8);
  float*    esum    = (float*)alloc((size_t)KCB * DIMS * 4);
  uint32_t* pbest   = (uint32_t*)alloc((size_t)8 * N_TOK * 4);
  uint32_t* psecond = (uint32_t*)alloc((size_t)8 * N_TOK * 4);
  uint32_t* pthird  = (uint32_t*)alloc((size_t)8 * N_TOK * 4);
  int*      ind     = (int*)alloc(N_TOK * 4);
  int*      candRows= (int*)alloc(N_TOK * 4);
  int*      candCnt = (int*)alloc(N_TOK * 4);
  int*      candIdx = (int*)alloc((size_t)N_TOK * 16 * 4);
  int*      listC   = (int*)alloc(N_TOK * 4);
  double*   nsum    = (double*)alloc(256);
  int*      expired = (int*)alloc(KCB * 4);
  uint32_t* tokBase = (uint32_t*)alloc(KCB * 4);
  uint32_t* tokCur  = (uint32_t*)alloc(KCB * 4);
  uint32_t* tokBucket = (uint32_t*)alloc(N_TOK * 4);
  uint32_t* keys1   = (uint32_t*)alloc(N_TOK * 4);
  uint32_t* keys2   = (uint32_t*)alloc(N_TOK * 4);
  uint32_t* bkey    = (uint32_t*)alloc(N_TOK * 4);
  uint32_t* bval    = (uint32_t*)alloc(N_TOK * 4);
  uint32_t* bkey2   = (uint32_t*)alloc(N_TOK * 4);
  uint32_t* bval2   = (uint32_t*)alloc(N_TOK * 4);
  uint32_t* bpos2   = (uint32_t*)alloc(N_TOK * 4);
  uint32_t* bbase1  = (uint32_t*)alloc(KCB * 4);
  uint32_t* bbase2  = (uint32_t*)alloc(KCB * 4);
  uint32_t* cursor1 = (uint32_t*)alloc(KCB * 4);
  uint32_t* cursor2 = (uint32_t*)alloc(KCB * 4);
  uint32_t* perm    = (uint32_t*)alloc(KCB * 4);
  // contiguous zero region: cntAB(256) | cntTok | bcount1 | bcount2
  uint32_t* cntAB   = (uint32_t*)alloc(256);
  uint32_t* cntTok  = (uint32_t*)alloc(KCB * 4);
  uint32_t* bcount1 = (uint32_t*)alloc(KCB * 4);
  uint32_t* bcount2 = (uint32_t*)alloc(KCB * 4);

  hipMemsetAsync(cntAB, 0, 256 + 3 * KCB * 4, stream);   // one memset for all counters

  e2split<<<(N_TOK * DIMS / 8 + KCB * DIMS / 8 + KCB + 255) / 256, 256, 0, stream>>>(
      x, xh, embed, eh, e2f, e2d);

  // permutation keys/histograms (independent of main pipeline)
  keys_both<<<188, 256, 0, stream>>>(keys1, keys2, bcount1, bcount2);
  scan_both<<<2, 1024, 0, stream>>>(bcount1, bbase1, cursor1, bcount2, bbase2, cursor2);

  dist_mfma<<<3000, 256, 0, stream>>>(xh, eh, e2f, pbest, psecond, pthird);
  merge8<<<188, 256, 0, stream>>>(pbest, psecond, pthird,
                                  ind, candRows, candIdx, candCnt, listC,
                                  &cntAB[0], &cntAB[1]);
  refine_cand<<<512, 256, 0, stream>>>(x, embed, e2d, candRows, candIdx, candCnt,
                                       &cntAB[0], ind);
  refine_fullC<<<1024, 256, 0, stream>>>(x, embed, e2d, listC, &cntAB[1], ind);

  // quantize output + token histogram, then code-major segment sum (no f32 atomics)
  gather_q<<<12000, 256, 0, stream>>>(embed, ind, outQ, outC, cntTok);
  scan_tok_ema<<<1, 1024, 0, stream>>>(cntTok, tokBase, tokCur, cs, outNCS, expired, nsum);
  scatter_tok<<<188, 256, 0, stream>>>(ind, tokBase, tokCur, tokBucket);
  esum_bucket<<<512, 256, 0, stream>>>(x, tokBase, cntTok, tokBucket, esum);

  // permutation: scatter1 -> rank1(+scatter2 fused) -> rank2 (first 2048 only)
  scatter1<<<188, 256, 0, stream>>>(keys1, bbase1, cursor1, bkey, bval);
  rank1_scatter2<<<2048, 64, 0, stream>>>(bkey, bval, bbase1, bcount1,
                                          keys2, bbase2, cursor2, bkey2, bval2, bpos2);
  rank2<<<2048, 64, 0, stream>>>(bkey2, bval2, bpos2, bbase2, bcount2, perm);

  final_embed<<<512, 256, 0, stream>>>(x, cs, cntTok, eavg, esum, expired, nsum,
                                       perm, outEAVG, outNE);
}

// Round 15
// 260.660 us; speedup vs baseline: 1.1187x; 1.1187x over previous
//
#include <hip/hip_runtime.h>
#include <hip/hip_bf16.h>
#include <stdint.h>
#include <math.h>

// Problem constants
#define N_TOK 48000     // 32*1500
#define DIMS  256
#define KCB   2048
// 1-pass bf16 approx score error: diff std ~6e-3, max over 1e8 pairs ~0.037.
// Packed-u32: score+32 (all in (0,64)), truncate low 11 bits -> quant error
// <= 64*2^-12 = 0.0156/side. WND = 0.10 >= 0.037 + 2*0.0156 with margin.
// True winner's packed score >= best - WND. Candidates = per-tile top-2; if a
// tile's THIRD value is in-window the winner may be unstored -> full re-scan.
#define WND 0.10f
#define BIAS 32.0f

typedef __attribute__((ext_vector_type(8))) short bf16x8;
typedef __attribute__((ext_vector_type(4))) float f32x4;
typedef __attribute__((ext_vector_type(8))) unsigned short u16x8;

// ---------------- bf16 helpers (explicit RNE) ----------------
__device__ __forceinline__ unsigned short bf16rn(float f) {
  uint32_t u = __float_as_uint(f);
  uint32_t r = (u + 0x7FFFu + ((u >> 16) & 1u)) >> 16;
  return (unsigned short)r;
}

// ---------------- packed sortable score ----------------
// input f = score + BIAS (>=0 after clamp): positive-float bits are monotone.
// high21 = value bits, low11 = 2047-k (ties -> smaller k wins at larger u32).
__device__ __forceinline__ uint32_t packBiased(float fb, uint32_t invIdx) {
  float c = fmaxf(fb, 0.0f);
  return (__float_as_uint(c) & ~0x7FFu) | invIdx;
}
__device__ __forceinline__ uint32_t packThrBiased(float fb) {
  float c = fmaxf(fb, 0.0f);
  return __float_as_uint(c) & ~0x7FFu;
}
__device__ __forceinline__ float unpackBiased(uint32_t u) {   // returns score+BIAS
  return __uint_as_float(u & ~0x7FFu);
}
// branch-free sorted top-3 insert (b>=s>=t), 5 u32 min/max ops
__device__ __forceinline__ void ins3u(uint32_t& b, uint32_t& s, uint32_t& t, uint32_t v) {
  uint32_t lo = min(b, v);
  b = max(b, v);
  uint32_t lo2 = min(s, lo);
  s = max(s, lo);
  t = max(t, lo2);
}

// ---------------- Threefry-2x32 (matches jax._src.prng, partitionable) ----------------
__device__ inline void tf2x32(uint32_t k0, uint32_t k1, uint32_t c0, uint32_t c1,
                              uint32_t& o0, uint32_t& o1) {
  uint32_t ks2 = k0 ^ k1 ^ 0x1BD11BDAu;
  uint32_t x0 = c0 + k0, x1 = c1 + k1;
#define TF_R(r) { x0 += x1; x1 = (x1 << (r)) | (x1 >> (32 - (r))); x1 ^= x0; }
  TF_R(13) TF_R(15) TF_R(26) TF_R(6)
  x0 += k1; x1 += ks2 + 1u;
  TF_R(17) TF_R(29) TF_R(16) TF_R(24)
  x0 += ks2; x1 += k0 + 2u;
  TF_R(13) TF_R(15) TF_R(26) TF_R(6)
  x0 += k0; x1 += k1 + 3u;
  TF_R(17) TF_R(29) TF_R(16) TF_R(24)
  x0 += k1; x1 += ks2 + 4u;
  TF_R(13) TF_R(15) TF_R(26) TF_R(6)
  x0 += ks2; x1 += k0 + 5u;
#undef TF_R
  o0 = x0; o1 = x1;
}

__device__ inline void get_round_key(int round, uint32_t& ka, uint32_t& kb) {
  const uint32_t b0 = 0u, b1 = 1u;  // jax.random.key(1) -> (0,1)
  uint32_t K1a, K1b, S1a, S1b;
  tf2x32(b0, b1, 0u, 0u, K1a, K1b);
  tf2x32(b0, b1, 0u, 1u, S1a, S1b);
  if (round == 1) { ka = S1a; kb = S1b; return; }
  uint32_t S2a, S2b;
  tf2x32(K1a, K1b, 0u, 1u, S2a, S2b);
  ka = S2a; kb = S2b;
}

__device__ inline uint32_t gen_key(int round, uint32_t i) {
  uint32_t ka, kb, o0, o1;
  get_round_key(round, ka, kb);
  tf2x32(ka, kb, 0u, i, o0, o1);
  return o0 ^ o1;
}

// ---------------- global_load_lds wrapper (16B) ----------------
__device__ __forceinline__ void gload_lds16(const void* g, void* l) {
  __builtin_amdgcn_global_load_lds(
      (const __attribute__((address_space(1))) uint32_t*)g,
      (__attribute__((address_space(3))) uint32_t*)l, 16, 0, 0);
}

// ---------------- fused: f32->bf16 split (x, embed) + e2 terms ----------------
// e2f[k] = BIAS - e2[k]  (so fmaf(2, dot, e2f) = score + BIAS directly)
__global__ void e2split(const float* __restrict__ x, unsigned short* __restrict__ xh,
                        const float* __restrict__ embed, unsigned short* __restrict__ eh,
                        float* __restrict__ e2f, double* __restrict__ e2d) {
  const int nx = N_TOK * DIMS / 8;
  const int ne = KCB * DIMS / 8;
  int i = blockIdx.x * blockDim.x + threadIdx.x;
  if (i < nx + ne) {
    const float* src; unsigned short* dst; int j;
    if (i < nx) { src = x; dst = xh; j = i; }
    else { src = embed; dst = eh; j = i - nx; }
    float4 a = ((const float4*)src)[j * 2];
    float4 b = ((const float4*)src)[j * 2 + 1];
    float v[8] = {a.x, a.y, a.z, a.w, b.x, b.y, b.z, b.w};
    u16x8 h;
#pragma unroll
    for (int q = 0; q < 8; ++q) h[q] = bf16rn(v[q]);
    *(u16x8*)&dst[(size_t)j * 8] = h;
    return;
  }
  int k = i - (nx + ne);
  if (k < KCB) {
    const float4* er = (const float4*)(embed + (size_t)k * DIMS);
    float s = 0.f;
    double sd = 0.0;
    for (int c = 0; c < DIMS / 4; ++c) {
      float4 v = er[c];
      s = fmaf(v.x, v.x, s); s = fmaf(v.y, v.y, s);
      s = fmaf(v.z, v.z, s); s = fmaf(v.w, v.w, s);
      sd += (double)v.x * v.x + (double)v.y * v.y
          + (double)v.z * v.z + (double)v.w * v.w;
    }
    e2f[k] = BIAS - s;
    e2d[k] = sd;
  }
}

// ---------------- MFMA distance top-3 (single bf16 pass, packed epilogue) ----------------
// approx score+BIAS = 2*(xh.eh) + e2f[k]; 128x256 tile, BK=32, 8 steps,
// double-buffered LDS. Bank swizzle (both-sides involution): chunk ^= (row>>1)&3.
// Epilogue: biased packed u32 scores (3-op pack), sort3 init + 5 inserts,
// LDS table reduce split across all 256 threads.
// NOTE: launch_bounds (256,2) -- forcing 3 blocks/CU (r14) capped VGPR at 84
// and spilled acc to scratch (WRITE_SIZE 4.5->106 MB, 79->112 us).
__global__ __launch_bounds__(256, 2) void dist_mfma(
    const unsigned short* __restrict__ xh, const unsigned short* __restrict__ eh,
    const float* __restrict__ e2f,
    uint32_t* __restrict__ pb, uint32_t* __restrict__ ps, uint32_t* __restrict__ pt)
{
  // staging (49152 B) and reduction table (128*99*4 = 50688 B) alias
  __shared__ __align__(16) char smem[50688];
  short (*As)[128 * 32] = (short(*)[128 * 32])smem;            // 2 x 8 KB
  short (*Bs)[256 * 32] = (short(*)[256 * 32])(smem + 16384);  // 2 x 16 KB
  uint32_t* red = (uint32_t*)smem;                             // [128][99] u32

  const int tid = threadIdx.x;
  const int lane = tid & 63, w = tid >> 6;
  const int wr = w >> 1, wc = w & 1;      // wave tile: 64 rows x 128 cols
  const int l15 = lane & 15, lg = lane >> 4;

  // XCD grouping: the 8 y-tiles sharing an x-tile get bids == same (mod 8),
  // spaced 8 apart -> same XCD L2 -> x-tile fetched from HBM once per XCD.
  int bx, by;
  {
    const int bid = blockIdx.x;
    if (bid < 2944) { int g = bid >> 6, r = bid & 63; bx = g * 8 + (r & 7); by = r >> 3; }
    else            { int t2 = bid - 2944; bx = 368 + (t2 % 7); by = t2 / 7; }
  }
  const int n0 = bx * 128;   // token tile base
  const int c0 = by * 256;   // code tile base

  f32x4 acc[4][8];
#pragma unroll
  for (int mf = 0; mf < 4; ++mf)
#pragma unroll
    for (int nf = 0; nf < 8; ++nf) acc[mf][nf] = (f32x4){0.f, 0.f, 0.f, 0.f};

  // stage step t into buffer t&1 (linear LDS dest; source pre-swizzled)
  auto stage = [&](int t) {
    const int d0 = t << 5;     // d-chunk of 32 shorts
    const int q = t & 1;
#pragma unroll
    for (int i = 0; i < 2; ++i) {
      const int c = i * 256 + tid;
      const int row = c >> 2;
      const int sc = ((c & 3) ^ ((row >> 1) & 3)) << 3;   // swizzled source chunk
      gload_lds16(xh + (size_t)(n0 + row) * DIMS + d0 + sc, (void*)&As[q][c * 8]);
    }
#pragma unroll
    for (int i = 0; i < 4; ++i) {
      const int c = i * 256 + tid;
      const int row = c >> 2;
      const int sc = ((c & 3) ^ ((row >> 1) & 3)) << 3;
      gload_lds16(eh + (size_t)(c0 + row) * DIMS + d0 + sc, (void*)&Bs[q][c * 8]);
    }
  };

  stage(0);
  __syncthreads();   // buf0 ready

#pragma unroll 1
  for (int t = 0; t < 8; ++t) {
    if (t < 7) stage(t + 1);         // issue next-step loads (overlap w/ compute)
    const int q = t & 1;
    bf16x8 af[4], bfv[8];
#pragma unroll
    for (int mf = 0; mf < 4; ++mf) {
      const int r = wr * 64 + mf * 16 + l15;
      af[mf] = *(const bf16x8*)&As[q][r * 32 + ((lg ^ ((r >> 1) & 3)) << 3)];
    }
#pragma unroll
    for (int nf = 0; nf < 8; ++nf) {
      const int r = wc * 128 + nf * 16 + l15;
      bfv[nf] = *(const bf16x8*)&Bs[q][r * 32 + ((lg ^ ((r >> 1) & 3)) << 3)];
    }
#pragma unroll
    for (int mf = 0; mf < 4; ++mf)
#pragma unroll
      for (int nf = 0; nf < 8; ++nf)
        acc[mf][nf] = __builtin_amdgcn_mfma_f32_16x16x32_bf16(
            af[mf], bfv[nf], acc[mf][nf], 0, 0, 0);
    __syncthreads();                 // staged loads drained + rw hazards
  }
  // K-loop done; last barrier above makes staging LDS safe to reuse as `red`.

  float e2v[8];
  uint32_t inv[8];
#pragma unroll
  for (int nf = 0; nf < 8; ++nf) {
    int k = c0 + wc * 128 + nf * 16 + l15;
    e2v[nf] = e2f[k];
    inv[nf] = 2047u - (uint32_t)k;
  }

  const int colbase = wc * 16 + l15;
#pragma unroll
  for (int mf = 0; mf < 4; ++mf) {
#pragma unroll
    for (int reg = 0; reg < 4; ++reg) {
      uint32_t p0 = packBiased(fmaf(2.f, acc[mf][0][reg], e2v[0]), inv[0]);
      uint32_t p1 = packBiased(fmaf(2.f, acc[mf][1][reg], e2v[1]), inv[1]);
      uint32_t p2 = packBiased(fmaf(2.f, acc[mf][2][reg], e2v[2]), inv[2]);
      // sort3 init (6 ops, exact)
      uint32_t h1 = max(p0, p1), l1 = min(p0, p1);
      uint32_t b  = max(h1, p2), m  = min(h1, p2);
      uint32_t s  = max(l1, m),  t3 = min(l1, m);
#pragma unroll
      for (int nf = 3; nf < 8; ++nf) {
        float f = fmaf(2.f, acc[mf][nf][reg], e2v[nf]);
        ins3u(b, s, t3, packBiased(f, inv[nf]));
      }
      const int row = wr * 64 + mf * 16 + lg * 4 + reg;
      uint32_t* p = &red[row * 99 + colbase * 3];
      p[0] = b; p[1] = s; p[2] = t3;
    }
  }
  __syncthreads();
  {
    const int row = tid >> 1, half = tid & 1;
    uint32_t b = 0u, s = 0u, t3 = 0u;
    const uint32_t* p = &red[row * 99 + half * 48];
#pragma unroll 4
    for (int c = 0; c < 48; ++c) ins3u(b, s, t3, p[c]);
    if (half) {
      uint32_t* q = &red[row * 99 + 96];
      q[0] = b; q[1] = s; q[2] = t3;
    }
    __syncthreads();
    if (!half) {
      const uint32_t* q = &red[row * 99 + 96];
      ins3u(b, s, t3, q[0]);
      ins3u(b, s, t3, q[1]);
      ins3u(b, s, t3, q[2]);
      size_t o = (size_t)by * N_TOK + n0 + row;
      pb[o] = b; ps[o] = s; pt[o] = t3;
    }
  }
}

// ---------------- merge 8 column-tile partials + candidate collection ----------------
__global__ void merge8(const uint32_t* __restrict__ pb, const uint32_t* __restrict__ ps,
                       const uint32_t* __restrict__ pt,
                       int* __restrict__ ind,
                       int* __restrict__ candRows, int* __restrict__ candIdx,
                       int* __restrict__ candCnt, int* __restrict__ listC,
                       uint32_t* __restrict__ cntA, uint32_t* __restrict__ cntC) {
  int n = blockIdx.x * blockDim.x + threadIdx.x;
  if (n >= N_TOK) return;
  uint32_t tb[8], tsv[8], ttv[8];
#pragma unroll
  for (int tt = 0; tt < 8; ++tt) {
    size_t o = (size_t)tt * N_TOK + n;
    tb[tt] = pb[o]; tsv[tt] = ps[o]; ttv[tt] = pt[o];
  }
  uint32_t best = tb[0];
#pragma unroll
  for (int tt = 1; tt < 8; ++tt) best = max(best, tb[tt]);
  ind[n] = 2047 - (int)(best & 0x7FFu);   // provisional winner
  const uint32_t thr = packThrBiased(unpackBiased(best) - WND);
  int m = 0; bool full = false;
#pragma unroll
  for (int tt = 0; tt < 8; ++tt) {
    m += (tb[tt] >= thr) + (tsv[tt] >= thr);
    full = full || (ttv[tt] >= thr);   // a tile's unstored 3rd+ could be in-window
  }
  if (full) {
    listC[atomicAdd(cntC, 1u)] = n;
  } else if (m > 1) {
    uint32_t i = atomicAdd(cntA, 1u);
    candRows[i] = n; candCnt[i] = m;
    int j = 0;
#pragma unroll
    for (int tt = 0; tt < 8; ++tt) {
      if (tb[tt]  >= thr) candIdx[(size_t)i * 16 + (j++)] = 2047 - (int)(tb[tt]  & 0x7FFu);
      if (tsv[tt] >= thr) candIdx[(size_t)i * 16 + (j++)] = 2047 - (int)(tsv[tt] & 0x7FFu);
    }
  }
}

// ---------------- wave-per-row f64 candidate decider ----------------
__global__ void refine_cand(const float* __restrict__ x, const float* __restrict__ embed,
                            const double* __restrict__ e2d,
                            const int* __restrict__ candRows, const int* __restrict__ candIdx,
                            const int* __restrict__ candCnt, const uint32_t* __restrict__ cntA,
                            int* __restrict__ ind) {
  const uint32_t nA = cntA[0];
  const int lane = threadIdx.x & 63;
  const uint32_t wid = (blockIdx.x * blockDim.x + threadIdx.x) >> 6;
  const uint32_t nw = (gridDim.x * blockDim.x) >> 6;
  for (uint32_t i = wid; i < nA; i += nw) {
    const int n = candRows[i];
    const int m = candCnt[i];
    float4 xv = ((const float4*)x)[(size_t)n * 64 + lane];
    double best = -1e300; int bk = 0x7fffffff;
    for (int j = 0; j < m; ++j) {
      int k = candIdx[(size_t)i * 16 + j];
      float4 e4 = ((const float4*)embed)[(size_t)k * 64 + lane];
      double d = (double)xv.x * e4.x + (double)xv.y * e4.y
               + (double)xv.z * e4.z + (double)xv.w * e4.w;
#pragma unroll
      for (int mm = 1; mm < 64; mm <<= 1) d += __shfl_xor(d, mm);
      double v = 2.0 * d - e2d[k];
      if (v > best || (v == best && k < bk)) { best = v; bk = k; }
    }
    if (lane == 0) ind[n] = bk;
  }
}

// ---------------- full f64 re-scan, one row per block (rare) ----------------
__global__ void refine_fullC(const float* __restrict__ x, const float* __restrict__ embed,
                             const double* __restrict__ e2d,
                             const int* __restrict__ listC, const uint32_t* __restrict__ cntC,
                             int* __restrict__ ind) {
  __shared__ double xd[DIMS];
  __shared__ double rv[256];
  __shared__ int    rk[256];
  const int tid = threadIdx.x;
  const uint32_t nC = cntC[0];
  for (uint32_t it = blockIdx.x; it < nC; it += gridDim.x) {
    const int n = listC[it];
    __syncthreads();
    xd[tid] = (double)x[(size_t)n * DIMS + tid];
    __syncthreads();
    double best = -1e300; int bk = 0x7fffffff;
    for (int k = tid; k < KCB; k += 256) {
      const float4* er = (const float4*)(embed + (size_t)k * DIMS);
      double a0 = 0.0, a1 = 0.0, a2 = 0.0, a3 = 0.0;   // ILP-4 chains
      for (int c = 0; c < 64; c += 4) {
        float4 ea = er[c], eb = er[c + 1], ec = er[c + 2], ed = er[c + 3];
        int d = c * 4;
        a0 += xd[d + 0] * ea.x + xd[d + 1] * ea.y + xd[d + 2] * ea.z + xd[d + 3] * ea.w;
        a1 += xd[d + 4] * eb.x + xd[d + 5] * eb.y + xd[d + 6] * eb.z + xd[d + 7] * eb.w;
        a2 += xd[d + 8] * ec.x + xd[d + 9] * ec.y + xd[d + 10] * ec.z + xd[d + 11] * ec.w;
        a3 += xd[d + 12] * ed.x + xd[d + 13] * ed.y + xd[d + 14] * ed.z + xd[d + 15] * ed.w;
      }
      double v = 2.0 * (a0 + a1 + a2 + a3) - e2d[k];
      if (v > best || (v == best && k < bk)) { best = v; bk = k; }
    }
    rv[tid] = best; rk[tid] = bk;
    __syncthreads();
    for (int s = 128; s > 0; s >>= 1) {
      if (tid < s) {
        double v2 = rv[tid + s]; int k2 = rk[tid + s];
        if (v2 > rv[tid] || (v2 == rv[tid] && k2 < rk[tid])) { rv[tid] = v2; rk[tid] = k2; }
      }
      __syncthreads();
    }
    if (tid == 0) ind[n] = rk[0];
  }
}

// ---------------- quantize gather + codes + token histogram ----------------
__global__ void gather_q(const float* __restrict__ embed, const int* __restrict__ ind,
                         float* __restrict__ outq, float* __restrict__ outcodes,
                         uint32_t* __restrict__ cntTok) {
  int idx = blockIdx.x * blockDim.x + threadIdx.x;   // over N_TOK*64 float4s
  if (idx >= N_TOK * 64) return;
  int n = idx >> 6, c = idx & 63;
  int k = ind[n];
  ((float4*)outq)[idx] = ((const float4*)embed)[(size_t)k * 64 + c];
  if (c == 0) { outcodes[n] = (float)k; atomicAdd(&cntTok[k], 1u); }
}

// ---------------- token-count scan + EMA stats (fused, 1 block) ----------------
__global__ void scan_tok_ema(const uint32_t* __restrict__ cntTok, uint32_t* __restrict__ tokBase,
                             uint32_t* __restrict__ tokCur,
                             const float* __restrict__ cs, float* __restrict__ out_ncs,
                             int* __restrict__ expired, double* __restrict__ nsum) {
  __shared__ uint32_t buf[2][2048];
  __shared__ double sd[1024];
  int t = threadIdx.x;   // 1024
  double local = 0.0;
  for (int q = 0; q < 2; ++q) {
    int i = t + q * 1024;
    uint32_t c = cntTok[i];
    buf[0][i] = c;
    tokCur[i] = 0;
    double v = 0.99 * (double)cs[i] + 0.01 * (double)c;
    out_ncs[i] = (float)v;
    expired[i] = (v < 2.0) ? 1 : 0;
    local += v;
  }
  sd[t] = local;
  __syncthreads();
  int src = 0;
  for (int off = 1; off < 2048; off <<= 1) {
    for (int q = 0; q < 2; ++q) {
      int i = t + q * 1024;
      uint32_t v = buf[src][i];
      if (i >= off) v += buf[src][i - off];
      buf[src ^ 1][i] = v;
    }
    src ^= 1; __syncthreads();
  }
  for (int q = 0; q < 2; ++q) {
    int i = t + q * 1024;
    tokBase[i] = buf[src][i] - cntTok[i];   // exclusive
  }
  for (int s = 512; s > 0; s >>= 1) { if (t < s) sd[t] += sd[t + s]; __syncthreads(); }
  if (t == 0) nsum[0] = sd[0];
}

// ---------------- scatter token ids into code-major buckets ----------------
__global__ void scatter_tok(const int* __restrict__ ind, const uint32_t* __restrict__ tokBase,
                            uint32_t* __restrict__ cursor, uint32_t* __restrict__ tokBucket) {
  int n = blockIdx.x * blockDim.x + threadIdx.x;
  if (n >= N_TOK) return;
  int k = ind[n];
  uint32_t p = atomicAdd(&cursor[k], 1u);
  tokBucket[tokBase[k] + p] = (uint32_t)n;
}

// ---------------- esum[k] = sum of x rows assigned to k (wave per code) ----------------
__global__ void esum_bucket(const float* __restrict__ x, const uint32_t* __restrict__ tokBase,
                            const uint32_t* __restrict__ cntTok,
                            const uint32_t* __restrict__ tokBucket,
                            float* __restrict__ esum) {
  const uint32_t wv = (blockIdx.x * blockDim.x + threadIdx.x) >> 6;
  if (wv >= KCB) return;
  const int lane = threadIdx.x & 63;
  const uint32_t base = tokBase[wv], cnt = cntTok[wv];
  float4 a0 = {0.f, 0.f, 0.f, 0.f}, a1 = {0.f, 0.f, 0.f, 0.f};
  uint32_t i = 0;
  for (; i + 2 <= cnt; i += 2) {
    uint32_t n0 = tokBucket[base + i], n1 = tokBucket[base + i + 1];
    float4 v0 = ((const float4*)x)[(size_t)n0 * 64 + lane];
    float4 v1 = ((const float4*)x)[(size_t)n1 * 64 + lane];
    a0.x += v0.x; a0.y += v0.y; a0.z += v0.z; a0.w += v0.w;
    a1.x += v1.x; a1.y += v1.y; a1.z += v1.z; a1.w += v1.w;
  }
  if (i < cnt) {
    uint32_t n0 = tokBucket[base + i];
    float4 v0 = ((const float4*)x)[(size_t)n0 * 64 + lane];
    a0.x += v0.x; a0.y += v0.y; a0.z += v0.z; a0.w += v0.w;
  }
  float4 r; r.x = a0.x + a1.x; r.y = a0.y + a1.y; r.z = a0.z + a1.z; r.w = a0.w + a1.w;
  ((float4*)esum)[(size_t)wv * 64 + lane] = r;
}

// ---------------- new_embed_avg + new_embed ----------------
__global__ void final_embed(const float* __restrict__ x, const float* __restrict__ cs,
                            const uint32_t* __restrict__ cntTok,
                            const float* __restrict__ eavg, const float* __restrict__ esum,
                            const int* __restrict__ expired, const double* __restrict__ nsum,
                            const uint32_t* __restrict__ perm,
                            float* __restrict__ out_eavg, float* __restrict__ out_ne) {
  int idx = blockIdx.x * blockDim.x + threadIdx.x;   // over KCB*64 float4s
  if (idx >= KCB * 64) return;
  int k = idx >> 6, c = idx & 63;
  float4 ea = ((const float4*)eavg)[idx];
  float4 es = ((const float4*)esum)[idx];
  double ax = 0.99 * (double)ea.x + 0.01 * (double)es.x;
  double ay = 0.99 * (double)ea.y + 0.01 * (double)es.y;
  double az = 0.99 * (double)ea.z + 0.01 * (double)es.z;
  double aw = 0.99 * (double)ea.w + 0.01 * (double)es.w;
  float4 nv; nv.x = (float)ax; nv.y = (float)ay; nv.z = (float)az; nv.w = (float)aw;
  ((float4*)out_eavg)[idx] = nv;
  float4 r;
  if (expired[k]) {
    r = ((const float4*)x)[(size_t)perm[k] * 64 + c];
  } else {
    double ncs = 0.99 * (double)cs[k] + 0.01 * (double)cntTok[k];
    double n = nsum[0];
    double sm = (ncs + 1e-5) / (n + 2048.0 * 1e-5) * n;
    r.x = (float)(ax / sm); r.y = (float)(ay / sm);
    r.z = (float)(az / sm); r.w = (float)(aw / sm);
  }
  ((float4*)out_ne)[idx] = r;
}

// ---------------- permutation pipeline (stable sort by random keys) ----------------
// Both rounds' keys are pure functions of the index -> compute together.
__global__ void keys_both(uint32_t* __restrict__ keys1, uint32_t* __restrict__ keys2,
                          uint32_t* __restrict__ bcount1, uint32_t* __restrict__ bcount2) {
  int i = blockIdx.x * blockDim.x + threadIdx.x;
  if (i >= N_TOK) return;
  uint32_t k1 = gen_key(1, (uint32_t)i);
  uint32_t k2 = gen_key(2, (uint32_t)i);
  keys1[i] = k1; keys2[i] = k2;
  atomicAdd(&bcount1[k1 >> 21], 1u);
  atomicAdd(&bcount2[k2 >> 21], 1u);
}

// block 0 scans hist1 (+zero cursor1), block 1 scans hist2 (+zero cursor2)
__global__ void scan_both(const uint32_t* __restrict__ in1, uint32_t* __restrict__ out1,
                          uint32_t* __restrict__ cur1,
                          const uint32_t* __restrict__ in2, uint32_t* __restrict__ out2,
                          uint32_t* __restrict__ cur2) {
  const uint32_t* in = blockIdx.x ? in2 : in1;
  uint32_t* out = blockIdx.x ? out2 : out1;
  uint32_t* cz = blockIdx.x ? cur2 : cur1;
  __shared__ uint32_t buf[2][2048];
  int t = threadIdx.x;   // 1024
  for (int q = 0; q < 2; ++q) buf[0][t + q * 1024] = in[t + q * 1024];
  cz[t] = 0; cz[t + 1024] = 0;
  __syncthreads();
  int src = 0;
  for (int off = 1; off < 2048; off <<= 1) {
    for (int q = 0; q < 2; ++q) {
      int i = t + q * 1024;
      uint32_t v = buf[src][i];
      if (i >= off) v += buf[src][i - off];
      buf[src ^ 1][i] = v;
    }
    src ^= 1; __syncthreads();
  }
  for (int q = 0; q < 2; ++q) {
    int i = t + q * 1024;
    out[i] = buf[src][i] - in[i];   // exclusive
  }
}

// round-1 scatter: value == original position (input is iota)
__global__ void scatter1(const uint32_t* __restrict__ keys1, const uint32_t* __restrict__ bbase1,
                         uint32_t* __restrict__ cursor1,
                         uint32_t* __restrict__ bkey, uint32_t* __restrict__ bval) {
  int i = blockIdx.x * blockDim.x + threadIdx.x;
  if (i >= N_TOK) return;
  uint32_t k = keys1[i];
  uint32_t b = k >> 21;
  uint32_t p = atomicAdd(&cursor1[b], 1u);
  uint32_t s = bbase1[b] + p;
  bkey[s] = k; bval[s] = (uint32_t)i;   // value == tie-break position for round 1
}

// rank round-1 elements (stable by (key,pos)) and scatter directly into
// round-2 buckets: sorted position p gets round-2 key keys2[p].
__global__ void rank1_scatter2(const uint32_t* __restrict__ bkey, const uint32_t* __restrict__ bval,
                               const uint32_t* __restrict__ bbase1, const uint32_t* __restrict__ bcount1,
                               const uint32_t* __restrict__ keys2,
                               const uint32_t* __restrict__ bbase2, uint32_t* __restrict__ cursor2,
                               uint32_t* __restrict__ bkey2, uint32_t* __restrict__ bval2,
                               uint32_t* __restrict__ bpos2) {
  int b = blockIdx.x;
  uint32_t base = bbase1[b], cnt = bcount1[b];
  for (uint32_t t = threadIdx.x; t < cnt; t += blockDim.x) {
    uint32_t k = bkey[base + t], pv = bval[base + t];
    uint32_t r = 0;
    for (uint32_t j = 0; j < cnt; ++j) {
      uint32_t kj = bkey[base + j], pj = bval[base + j];
      r += (kj < k) | ((kj == k) & (pj < pv));
    }
    uint32_t p = base + r;          // global round-1 sorted position
    uint32_t k2 = keys2[p];
    uint32_t b2 = k2 >> 21;
    uint32_t q = atomicAdd(&cursor2[b2], 1u);
    uint32_t s = bbase2[b2] + q;
    bkey2[s] = k2; bval2[s] = pv; bpos2[s] = p;
  }
}

// round-2 rank; only output positions < KCB are consumed (perm[0..2047])
__global__ void rank2(const uint32_t* __restrict__ bkey2, const uint32_t* __restrict__ bval2,
                      const uint32_t* __restrict__ bpos2,
                      const uint32_t* __restrict__ bbase2, const uint32_t* __restrict__ bcount2,
                      uint32_t* __restrict__ perm) {
  int b = blockIdx.x;
  uint32_t base = bbase2[b];
  if (base >= KCB) return;          // every element lands at position >= 2048
  uint32_t cnt = bcount2[b];
  for (uint32_t t = threadIdx.x; t < cnt; t += blockDim.x) {
    uint32_t k = bkey2[base + t], p = bpos2[base + t];
    uint32_t r = 0;
    for (uint32_t j = 0; j < cnt; ++j) {
      uint32_t kj = bkey2[base + j], pj = bpos2[base + j];
      r += (kj < k) | ((kj == k) & (pj < p));
    }
    uint32_t pos = base + r;
    if (pos < KCB) perm[pos] = bval2[base + t];
  }
}

// ---------------- launch ----------------
extern "C" void kernel_launch(void* const* d_in, const int* in_sizes, int n_in,
                              void* d_out, int out_size, void* d_ws, size_t ws_size,
                              hipStream_t stream) {
  const float* x     = (const float*)d_in[0];
  const float* embed = (const float*)d_in[1];
  const float* cs    = (const float*)d_in[2];
  const float* eavg  = (const float*)d_in[3];

  float* out = (float*)d_out;
  float* outQ    = out;                  // 12,288,000
  float* outC    = out + 12288000;       // 48,000
  float* outNCS  = out + 12336000;       // 2,048
  float* outEAVG = out + 12338048;       // 524,288
  float* outNE   = out + 12862336;       // 524,288

  char* w = (char*)d_ws;
  size_t off = 0;
  auto alloc = [&](size_t bytes) -> void* {
    void* p = w + off; off += (bytes + 255) & ~(size_t)255; return p;
  };
  unsigned short* xh = (unsigned short*)alloc((size_t)N_TOK * DIMS * 2);
  unsigned short* eh = (unsigned short*)alloc((size_t)KCB * DIMS * 2);
  float*    e2f     = (float*)alloc(KCB * 4);
  double*   e2d     = (double*)alloc(KCB * 8);
  float*    esum    = (float*)alloc((size_t)KCB * DIMS * 4);
  uint32_t* pbest   = (uint32_t*)alloc((size_t)8 * N_TOK * 4);
  uint32_t* psecond = (uint32_t*)alloc((size_t)8 * N_TOK * 4);
  uint32_t* pthird  = (uint32_t*)alloc((size_t)8 * N_TOK * 4);
  int*      ind     = (int*)alloc(N_TOK * 4);
  int*      candRows= (int*)alloc(N_TOK * 4);
  int*      candCnt = (int*)alloc(N_TOK * 4);
  int*      candIdx = (int*)alloc((size_t)N_TOK * 16 * 4);
  int*      listC   = (int*)alloc(N_TOK * 4);
  double*   nsum    = (double*)alloc(256);
  int*      expired = (int*)alloc(KCB * 4);
  uint32_t* tokBase = (uint32_t*)alloc(KCB * 4);
  uint32_t* tokCur  = (uint32_t*)alloc(KCB * 4);
  uint32_t* tokBucket = (uint32_t*)alloc(N_TOK * 4);
  uint32_t* keys1   = (uint32_t*)alloc(N_TOK * 4);
  uint32_t* keys2   = (uint32_t*)alloc(N_TOK * 4);
  uint32_t* bkey    = (uint32_t*)alloc(N_TOK * 4);
  uint32_t* bval    = (uint32_t*)alloc(N_TOK * 4);
  uint32_t* bkey2   = (uint32_t*)alloc(N_TOK * 4);
  uint32_t* bval2   = (uint32_t*)alloc(N_TOK * 4);
  uint32_t* bpos2   = (uint32_t*)alloc(N_TOK * 4);
  uint32_t* bbase1  = (uint32_t*)alloc(KCB * 4);
  uint32_t* bbase2  = (uint32_t*)alloc(KCB * 4);
  uint32_t* cursor1 = (uint32_t*)alloc(KCB * 4);
  uint32_t* cursor2 = (uint32_t*)alloc(KCB * 4);
  uint32_t* perm    = (uint32_t*)alloc(KCB * 4);
  // contiguous zero region: cntAB(256) | cntTok | bcount1 | bcount2
  uint32_t* cntAB   = (uint32_t*)alloc(256);
  uint32_t* cntTok  = (uint32_t*)alloc(KCB * 4);
  uint32_t* bcount1 = (uint32_t*)alloc(KCB * 4);
  uint32_t* bcount2 = (uint32_t*)alloc(KCB * 4);

  hipMemsetAsync(cntAB, 0, 256 + 3 * KCB * 4, stream);   // one memset for all counters

  e2split<<<(N_TOK * DIMS / 8 + KCB * DIMS / 8 + KCB + 255) / 256, 256, 0, stream>>>(
      x, xh, embed, eh, e2f, e2d);

  // permutation keys/histograms (independent of main pipeline)
  keys_both<<<188, 256, 0, stream>>>(keys1, keys2, bcount1, bcount2);
  scan_both<<<2, 1024, 0, stream>>>(bcount1, bbase1, cursor1, bcount2, bbase2, cursor2);

  dist_mfma<<<3000, 256, 0, stream>>>(xh, eh, e2f, pbest, psecond, pthird);
  merge8<<<188, 256, 0, stream>>>(pbest, psecond, pthird,
                                  ind, candRows, candIdx, candCnt, listC,
                                  &cntAB[0], &cntAB[1]);
  refine_cand<<<512, 256, 0, stream>>>(x, embed, e2d, candRows, candIdx, candCnt,
                                       &cntAB[0], ind);
  refine_fullC<<<1024, 256, 0, stream>>>(x, embed, e2d, listC, &cntAB[1], ind);

  // quantize output + token histogram, then code-major segment sum (no f32 atomics)
  gather_q<<<12000, 256, 0, stream>>>(embed, ind, outQ, outC, cntTok);
  scan_tok_ema<<<1, 1024, 0, stream>>>(cntTok, tokBase, tokCur, cs, outNCS, expired, nsum);
  scatter_tok<<<188, 256, 0, stream>>>(ind, tokBase, tokCur, tokBucket);
  esum_bucket<<<512, 256, 0, stream>>>(x, tokBase, cntTok, tokBucket, esum);

  // permutation: scatter1 -> rank1(+scatter2 fused) -> rank2 (first 2048 only)
  scatter1<<<188, 256, 0, stream>>>(keys1, bbase1, cursor1, bkey, bval);
  rank1_scatter2<<<2048, 64, 0, stream>>>(bkey, bval, bbase1, bcount1,
                                          keys2, bbase2, cursor2, bkey2, bval2, bpos2);
  rank2<<<2048, 64, 0, stream>>>(bkey2, bval2, bpos2, bbase2, bcount2, perm);

  final_embed<<<512, 256, 0, stream>>>(x, cs, cntTok, eavg, esum, expired, nsum,
                                       perm, outEAVG, outNE);
}

// Round 16
// 235.535 us; speedup vs baseline: 1.2380x; 1.1067x over previous
//
#include <hip/hip_runtime.h>
#include <hip/hip_bf16.h>
#include <stdint.h>
#include <math.h>

// Problem constants
#define N_TOK 48000     // 32*1500
#define DIMS  256
#define KCB   2048
// 1-pass bf16 approx score error: diff std ~6e-3, max over 1e8 pairs ~0.037.
// Packed-u32: score+32 (all in (0,64)), truncate low 11 bits -> quant error
// <= 64*2^-12 = 0.0156/side. WND = 0.10 >= 0.037 + 2*0.0156 with margin.
// True winner's packed score >= best - WND. Candidates = per-tile top-2; if a
// tile's THIRD value is in-window the winner may be unstored -> full re-scan.
#define WND 0.10f
#define BIAS 32.0f

typedef __attribute__((ext_vector_type(8))) short bf16x8;
typedef __attribute__((ext_vector_type(4))) float f32x4;
typedef __attribute__((ext_vector_type(8))) unsigned short u16x8;

// ---------------- bf16 helpers (explicit RNE) ----------------
__device__ __forceinline__ unsigned short bf16rn(float f) {
  uint32_t u = __float_as_uint(f);
  uint32_t r = (u + 0x7FFFu + ((u >> 16) & 1u)) >> 16;
  return (unsigned short)r;
}

// ---------------- packed sortable score ----------------
__device__ __forceinline__ uint32_t packBiased(float fb, uint32_t invIdx) {
  float c = fmaxf(fb, 0.0f);
  return (__float_as_uint(c) & ~0x7FFu) | invIdx;
}
__device__ __forceinline__ uint32_t packThrBiased(float fb) {
  float c = fmaxf(fb, 0.0f);
  return __float_as_uint(c) & ~0x7FFu;
}
__device__ __forceinline__ float unpackBiased(uint32_t u) {   // returns score+BIAS
  return __uint_as_float(u & ~0x7FFu);
}
// branch-free sorted top-3 insert (b>=s>=t), 5 u32 min/max ops
__device__ __forceinline__ void ins3u(uint32_t& b, uint32_t& s, uint32_t& t, uint32_t v) {
  uint32_t lo = min(b, v);
  b = max(b, v);
  uint32_t lo2 = min(s, lo);
  s = max(s, lo);
  t = max(t, lo2);
}

// ---------------- Threefry-2x32 (matches jax._src.prng, partitionable) ----------------
__device__ inline void tf2x32(uint32_t k0, uint32_t k1, uint32_t c0, uint32_t c1,
                              uint32_t& o0, uint32_t& o1) {
  uint32_t ks2 = k0 ^ k1 ^ 0x1BD11BDAu;
  uint32_t x0 = c0 + k0, x1 = c1 + k1;
#define TF_R(r) { x0 += x1; x1 = (x1 << (r)) | (x1 >> (32 - (r))); x1 ^= x0; }
  TF_R(13) TF_R(15) TF_R(26) TF_R(6)
  x0 += k1; x1 += ks2 + 1u;
  TF_R(17) TF_R(29) TF_R(16) TF_R(24)
  x0 += ks2; x1 += k0 + 2u;
  TF_R(13) TF_R(15) TF_R(26) TF_R(6)
  x0 += k0; x1 += k1 + 3u;
  TF_R(17) TF_R(29) TF_R(16) TF_R(24)
  x0 += k1; x1 += ks2 + 4u;
  TF_R(13) TF_R(15) TF_R(26) TF_R(6)
  x0 += ks2; x1 += k0 + 5u;
#undef TF_R
  o0 = x0; o1 = x1;
}

__device__ inline void get_round_key(int round, uint32_t& ka, uint32_t& kb) {
  const uint32_t b0 = 0u, b1 = 1u;  // jax.random.key(1) -> (0,1)
  uint32_t K1a, K1b, S1a, S1b;
  tf2x32(b0, b1, 0u, 0u, K1a, K1b);
  tf2x32(b0, b1, 0u, 1u, S1a, S1b);
  if (round == 1) { ka = S1a; kb = S1b; return; }
  uint32_t S2a, S2b;
  tf2x32(K1a, K1b, 0u, 1u, S2a, S2b);
  ka = S2a; kb = S2b;
}

__device__ inline uint32_t gen_key(int round, uint32_t i) {
  uint32_t ka, kb, o0, o1;
  get_round_key(round, ka, kb);
  tf2x32(ka, kb, 0u, i, o0, o1);
  return o0 ^ o1;
}

// ---------------- global_load_lds wrapper (16B) ----------------
__device__ __forceinline__ void gload_lds16(const void* g, void* l) {
  __builtin_amdgcn_global_load_lds(
      (const __attribute__((address_space(1))) uint32_t*)g,
      (__attribute__((address_space(3))) uint32_t*)l, 16, 0, 0);
}

// ---------------- fused: bf16 split (x,embed) + e2 terms + permutation keys ----------------
// e2f[k] = BIAS - e2[k]  (so fmaf(2, dot, e2f) = score + BIAS directly)
__global__ void e2split_keys(const float* __restrict__ x, unsigned short* __restrict__ xh,
                             const float* __restrict__ embed, unsigned short* __restrict__ eh,
                             float* __restrict__ e2f, double* __restrict__ e2d,
                             uint32_t* __restrict__ keys1, uint32_t* __restrict__ keys2,
                             uint32_t* __restrict__ bcount1, uint32_t* __restrict__ bcount2) {
  const int nx = N_TOK * DIMS / 8;
  const int ne = KCB * DIMS / 8;
  int i = blockIdx.x * blockDim.x + threadIdx.x;
  if (i < nx + ne) {
    const float* src; unsigned short* dst; int j;
    if (i < nx) { src = x; dst = xh; j = i; }
    else { src = embed; dst = eh; j = i - nx; }
    float4 a = ((const float4*)src)[j * 2];
    float4 b = ((const float4*)src)[j * 2 + 1];
    float v[8] = {a.x, a.y, a.z, a.w, b.x, b.y, b.z, b.w};
    u16x8 h;
#pragma unroll
    for (int q = 0; q < 8; ++q) h[q] = bf16rn(v[q]);
    *(u16x8*)&dst[(size_t)j * 8] = h;
    return;
  }
  int k = i - (nx + ne);
  if (k < KCB) {
    const float4* er = (const float4*)(embed + (size_t)k * DIMS);
    float s = 0.f;
    double sd = 0.0;
    for (int c = 0; c < DIMS / 4; ++c) {
      float4 v = er[c];
      s = fmaf(v.x, v.x, s); s = fmaf(v.y, v.y, s);
      s = fmaf(v.z, v.z, s); s = fmaf(v.w, v.w, s);
      sd += (double)v.x * v.x + (double)v.y * v.y
          + (double)v.z * v.z + (double)v.w * v.w;
    }
    e2f[k] = BIAS - s;
    e2d[k] = sd;
    return;
  }
  int n = k - KCB;
  if (n < N_TOK) {
    uint32_t k1 = gen_key(1, (uint32_t)n);
    uint32_t k2 = gen_key(2, (uint32_t)n);
    keys1[n] = k1; keys2[n] = k2;
    atomicAdd(&bcount1[k1 >> 21], 1u);
    atomicAdd(&bcount2[k2 >> 21], 1u);
  }
}

// ---------------- MFMA distance top-3 (single bf16 pass, packed epilogue) ----------------
// approx score+BIAS = 2*(xh.eh) + e2f[k]; 128x256 tile, BK=32, 8 steps,
// double-buffered LDS. Bank swizzle (both-sides involution): chunk ^= (row>>1)&3.
// NOTE: launch_bounds (256,2) -- forcing 3 blocks/CU (r14) capped VGPR at 84
// and spilled acc to scratch (WRITE_SIZE 4.5->106 MB, 79->112 us).
__global__ __launch_bounds__(256, 2) void dist_mfma(
    const unsigned short* __restrict__ xh, const unsigned short* __restrict__ eh,
    const float* __restrict__ e2f,
    uint32_t* __restrict__ pb, uint32_t* __restrict__ ps, uint32_t* __restrict__ pt)
{
  // staging (49152 B) and reduction table (128*99*4 = 50688 B) alias
  __shared__ __align__(16) char smem[50688];
  short (*As)[128 * 32] = (short(*)[128 * 32])smem;            // 2 x 8 KB
  short (*Bs)[256 * 32] = (short(*)[256 * 32])(smem + 16384);  // 2 x 16 KB
  uint32_t* red = (uint32_t*)smem;                             // [128][99] u32

  const int tid = threadIdx.x;
  const int lane = tid & 63, w = tid >> 6;
  const int wr = w >> 1, wc = w & 1;      // wave tile: 64 rows x 128 cols
  const int l15 = lane & 15, lg = lane >> 4;

  // XCD grouping: the 8 y-tiles sharing an x-tile get bids == same (mod 8),
  // spaced 8 apart -> same XCD L2 -> x-tile fetched from HBM once per XCD.
  int bx, by;
  {
    const int bid = blockIdx.x;
    if (bid < 2944) { int g = bid >> 6, r = bid & 63; bx = g * 8 + (r & 7); by = r >> 3; }
    else            { int t2 = bid - 2944; bx = 368 + (t2 % 7); by = t2 / 7; }
  }
  const int n0 = bx * 128;   // token tile base
  const int c0 = by * 256;   // code tile base

  f32x4 acc[4][8];
#pragma unroll
  for (int mf = 0; mf < 4; ++mf)
#pragma unroll
    for (int nf = 0; nf < 8; ++nf) acc[mf][nf] = (f32x4){0.f, 0.f, 0.f, 0.f};

  // stage step t into buffer t&1 (linear LDS dest; source pre-swizzled)
  auto stage = [&](int t) {
    const int d0 = t << 5;     // d-chunk of 32 shorts
    const int q = t & 1;
#pragma unroll
    for (int i = 0; i < 2; ++i) {
      const int c = i * 256 + tid;
      const int row = c >> 2;
      const int sc = ((c & 3) ^ ((row >> 1) & 3)) << 3;   // swizzled source chunk
      gload_lds16(xh + (size_t)(n0 + row) * DIMS + d0 + sc, (void*)&As[q][c * 8]);
    }
#pragma unroll
    for (int i = 0; i < 4; ++i) {
      const int c = i * 256 + tid;
      const int row = c >> 2;
      const int sc = ((c & 3) ^ ((row >> 1) & 3)) << 3;
      gload_lds16(eh + (size_t)(c0 + row) * DIMS + d0 + sc, (void*)&Bs[q][c * 8]);
    }
  };

  stage(0);
  __syncthreads();   // buf0 ready

#pragma unroll 1
  for (int t = 0; t < 8; ++t) {
    if (t < 7) stage(t + 1);         // issue next-step loads (overlap w/ compute)
    const int q = t & 1;
    bf16x8 af[4], bfv[8];
#pragma unroll
    for (int mf = 0; mf < 4; ++mf) {
      const int r = wr * 64 + mf * 16 + l15;
      af[mf] = *(const bf16x8*)&As[q][r * 32 + ((lg ^ ((r >> 1) & 3)) << 3)];
    }
#pragma unroll
    for (int nf = 0; nf < 8; ++nf) {
      const int r = wc * 128 + nf * 16 + l15;
      bfv[nf] = *(const bf16x8*)&Bs[q][r * 32 + ((lg ^ ((r >> 1) & 3)) << 3)];
    }
#pragma unroll
    for (int mf = 0; mf < 4; ++mf)
#pragma unroll
      for (int nf = 0; nf < 8; ++nf)
        acc[mf][nf] = __builtin_amdgcn_mfma_f32_16x16x32_bf16(
            af[mf], bfv[nf], acc[mf][nf], 0, 0, 0);
    __syncthreads();                 // staged loads drained + rw hazards
  }
  // K-loop done; last barrier above makes staging LDS safe to reuse as `red`.

  float e2v[8];
  uint32_t inv[8];
#pragma unroll
  for (int nf = 0; nf < 8; ++nf) {
    int k = c0 + wc * 128 + nf * 16 + l15;
    e2v[nf] = e2f[k];
    inv[nf] = 2047u - (uint32_t)k;
  }

  const int colbase = wc * 16 + l15;
#pragma unroll
  for (int mf = 0; mf < 4; ++mf) {
#pragma unroll
    for (int reg = 0; reg < 4; ++reg) {
      uint32_t p0 = packBiased(fmaf(2.f, acc[mf][0][reg], e2v[0]), inv[0]);
      uint32_t p1 = packBiased(fmaf(2.f, acc[mf][1][reg], e2v[1]), inv[1]);
      uint32_t p2 = packBiased(fmaf(2.f, acc[mf][2][reg], e2v[2]), inv[2]);
      // sort3 init (6 ops, exact)
      uint32_t h1 = max(p0, p1), l1 = min(p0, p1);
      uint32_t b  = max(h1, p2), m  = min(h1, p2);
      uint32_t s  = max(l1, m),  t3 = min(l1, m);
#pragma unroll
      for (int nf = 3; nf < 8; ++nf) {
        float f = fmaf(2.f, acc[mf][nf][reg], e2v[nf]);
        ins3u(b, s, t3, packBiased(f, inv[nf]));
      }
      const int row = wr * 64 + mf * 16 + lg * 4 + reg;
      uint32_t* p = &red[row * 99 + colbase * 3];
      p[0] = b; p[1] = s; p[2] = t3;
    }
  }
  __syncthreads();
  {
    const int row = tid >> 1, half = tid & 1;
    uint32_t b = 0u, s = 0u, t3 = 0u;
    const uint32_t* p = &red[row * 99 + half * 48];
#pragma unroll 4
    for (int c = 0; c < 48; ++c) ins3u(b, s, t3, p[c]);
    if (half) {
      uint32_t* q = &red[row * 99 + 96];
      q[0] = b; q[1] = s; q[2] = t3;
    }
    __syncthreads();
    if (!half) {
      const uint32_t* q = &red[row * 99 + 96];
      ins3u(b, s, t3, q[0]);
      ins3u(b, s, t3, q[1]);
      ins3u(b, s, t3, q[2]);
      size_t o = (size_t)by * N_TOK + n0 + row;
      pb[o] = b; ps[o] = s; pt[o] = t3;
    }
  }
}

// ---------------- merge 8 column-tile partials + candidate collection ----------------
__global__ void merge8(const uint32_t* __restrict__ pb, const uint32_t* __restrict__ ps,
                       const uint32_t* __restrict__ pt,
                       int* __restrict__ ind,
                       int* __restrict__ candRows, int* __restrict__ candIdx,
                       int* __restrict__ candCnt, int* __restrict__ listC,
                       uint32_t* __restrict__ cntA, uint32_t* __restrict__ cntC) {
  int n = blockIdx.x * blockDim.x + threadIdx.x;
  if (n >= N_TOK) return;
  uint32_t tb[8], tsv[8], ttv[8];
#pragma unroll
  for (int tt = 0; tt < 8; ++tt) {
    size_t o = (size_t)tt * N_TOK + n;
    tb[tt] = pb[o]; tsv[tt] = ps[o]; ttv[tt] = pt[o];
  }
  uint32_t best = tb[0];
#pragma unroll
  for (int tt = 1; tt < 8; ++tt) best = max(best, tb[tt]);
  ind[n] = 2047 - (int)(best & 0x7FFu);   // provisional winner
  const uint32_t thr = packThrBiased(unpackBiased(best) - WND);
  int m = 0; bool full = false;
#pragma unroll
  for (int tt = 0; tt < 8; ++tt) {
    m += (tb[tt] >= thr) + (tsv[tt] >= thr);
    full = full || (ttv[tt] >= thr);   // a tile's unstored 3rd+ could be in-window
  }
  if (full) {
    listC[atomicAdd(cntC, 1u)] = n;
  } else if (m > 1) {
    uint32_t i = atomicAdd(cntA, 1u);
    candRows[i] = n; candCnt[i] = m;
    int j = 0;
#pragma unroll
    for (int tt = 0; tt < 8; ++tt) {
      if (tb[tt]  >= thr) candIdx[(size_t)i * 16 + (j++)] = 2047 - (int)(tb[tt]  & 0x7FFu);
      if (tsv[tt] >= thr) candIdx[(size_t)i * 16 + (j++)] = 2047 - (int)(tsv[tt] & 0x7FFu);
    }
  }
}

// ---------------- fused refine: blocks [0,512) candidate path, [512,1536) full scan ----------------
#define RC_BLOCKS 512
#define RF_BLOCKS 1024
__global__ void refine_both(const float* __restrict__ x, const float* __restrict__ embed,
                            const double* __restrict__ e2d,
                            const int* __restrict__ candRows, const int* __restrict__ candIdx,
                            const int* __restrict__ candCnt,
                            const int* __restrict__ listC,
                            const uint32_t* __restrict__ cntAB,
                            int* __restrict__ ind) {
  __shared__ double xd[DIMS];
  __shared__ double rv[256];
  __shared__ int    rk[256];
  const int tid = threadIdx.x;
  if (blockIdx.x < RC_BLOCKS) {
    // ---- wave-per-row f64 candidate decider ----
    const uint32_t nA = cntAB[0];
    const int lane = tid & 63;
    const uint32_t wid = ((uint32_t)blockIdx.x * 256 + tid) >> 6;
    const uint32_t nw = RC_BLOCKS * 4;
    for (uint32_t i = wid; i < nA; i += nw) {
      const int n = candRows[i];
      const int m = candCnt[i];
      float4 xv = ((const float4*)x)[(size_t)n * 64 + lane];
      double best = -1e300; int bk = 0x7fffffff;
      for (int j = 0; j < m; ++j) {
        int k = candIdx[(size_t)i * 16 + j];
        float4 e4 = ((const float4*)embed)[(size_t)k * 64 + lane];
        double d = (double)xv.x * e4.x + (double)xv.y * e4.y
                 + (double)xv.z * e4.z + (double)xv.w * e4.w;
#pragma unroll
        for (int mm = 1; mm < 64; mm <<= 1) d += __shfl_xor(d, mm);
        double v = 2.0 * d - e2d[k];
        if (v > best || (v == best && k < bk)) { best = v; bk = k; }
      }
      if (lane == 0) ind[n] = bk;
    }
    return;
  }
  // ---- full f64 re-scan, one row per block (rare) ----
  const uint32_t nC = cntAB[1];
  for (uint32_t it = blockIdx.x - RC_BLOCKS; it < nC; it += RF_BLOCKS) {
    const int n = listC[it];
    __syncthreads();
    xd[tid] = (double)x[(size_t)n * DIMS + tid];
    __syncthreads();
    double best = -1e300; int bk = 0x7fffffff;
    for (int k = tid; k < KCB; k += 256) {
      const float4* er = (const float4*)(embed + (size_t)k * DIMS);
      double a0 = 0.0, a1 = 0.0, a2 = 0.0, a3 = 0.0;   // ILP-4 chains
      for (int c = 0; c < 64; c += 4) {
        float4 ea = er[c], eb = er[c + 1], ec = er[c + 2], ed = er[c + 3];
        int d = c * 4;
        a0 += xd[d + 0] * ea.x + xd[d + 1] * ea.y + xd[d + 2] * ea.z + xd[d + 3] * ea.w;
        a1 += xd[d + 4] * eb.x + xd[d + 5] * eb.y + xd[d + 6] * eb.z + xd[d + 7] * eb.w;
        a2 += xd[d + 8] * ec.x + xd[d + 9] * ec.y + xd[d + 10] * ec.z + xd[d + 11] * ec.w;
        a3 += xd[d + 12] * ed.x + xd[d + 13] * ed.y + xd[d + 14] * ed.z + xd[d + 15] * ed.w;
      }
      double v = 2.0 * (a0 + a1 + a2 + a3) - e2d[k];
      if (v > best || (v == best && k < bk)) { best = v; bk = k; }
    }
    rv[tid] = best; rk[tid] = bk;
    __syncthreads();
    for (int s = 128; s > 0; s >>= 1) {
      if (tid < s) {
        double v2 = rv[tid + s]; int k2 = rk[tid + s];
        if (v2 > rv[tid] || (v2 == rv[tid] && k2 < rk[tid])) { rv[tid] = v2; rk[tid] = k2; }
      }
      __syncthreads();
    }
    if (tid == 0) ind[n] = rk[0];
  }
}

// ---------------- quantize gather + codes + token histogram ----------------
__global__ void gather_q(const float* __restrict__ embed, const int* __restrict__ ind,
                         float* __restrict__ outq, float* __restrict__ outcodes,
                         uint32_t* __restrict__ cntTok) {
  int idx = blockIdx.x * blockDim.x + threadIdx.x;   // over N_TOK*64 float4s
  if (idx >= N_TOK * 64) return;
  int n = idx >> 6, c = idx & 63;
  int k = ind[n];
  ((float4*)outq)[idx] = ((const float4*)embed)[(size_t)k * 64 + c];
  if (c == 0) { outcodes[n] = (float)k; atomicAdd(&cntTok[k], 1u); }
}

// ---------------- 3-block scan: b0 = token scan + EMA, b1/b2 = key histograms ----------------
__global__ void scan3(const uint32_t* __restrict__ cntTok, uint32_t* __restrict__ tokBase,
                      uint32_t* __restrict__ tokCur,
                      const float* __restrict__ cs, float* __restrict__ out_ncs,
                      int* __restrict__ expired, double* __restrict__ nsum,
                      const uint32_t* __restrict__ bcount1, uint32_t* __restrict__ bbase1,
                      uint32_t* __restrict__ cursor1,
                      const uint32_t* __restrict__ bcount2, uint32_t* __restrict__ bbase2,
                      uint32_t* __restrict__ cursor2) {
  __shared__ uint32_t buf[2][2048];
  __shared__ double sd[1024];
  int t = threadIdx.x;   // 1024
  const uint32_t* in; uint32_t* out; uint32_t* cz;
  if (blockIdx.x == 0)      { in = cntTok;  out = tokBase; cz = tokCur;  }
  else if (blockIdx.x == 1) { in = bcount1; out = bbase1;  cz = cursor1; }
  else                      { in = bcount2; out = bbase2;  cz = cursor2; }
  double local = 0.0;
  for (int q = 0; q < 2; ++q) {
    int i = t + q * 1024;
    uint32_t c = in[i];
    buf[0][i] = c;
    cz[i] = 0;
    if (blockIdx.x == 0) {
      double v = 0.99 * (double)cs[i] + 0.01 * (double)c;
      out_ncs[i] = (float)v;
      expired[i] = (v < 2.0) ? 1 : 0;
      local += v;
    }
  }
  if (blockIdx.x == 0) sd[t] = local;
  __syncthreads();
  int src = 0;
  for (int off = 1; off < 2048; off <<= 1) {
    for (int q = 0; q < 2; ++q) {
      int i = t + q * 1024;
      uint32_t v = buf[src][i];
      if (i >= off) v += buf[src][i - off];
      buf[src ^ 1][i] = v;
    }
    src ^= 1; __syncthreads();
  }
  for (int q = 0; q < 2; ++q) {
    int i = t + q * 1024;
    out[i] = buf[src][i] - in[i];   // exclusive
  }
  if (blockIdx.x == 0) {
    for (int s = 512; s > 0; s >>= 1) { if (t < s) sd[t] += sd[t + s]; __syncthreads(); }
    if (t == 0) nsum[0] = sd[0];
  }
}

// ---------------- fused scatter: token buckets + round-1 key buckets ----------------
__global__ void scatter_both(const int* __restrict__ ind, const uint32_t* __restrict__ tokBase,
                             uint32_t* __restrict__ tokCur, uint32_t* __restrict__ tokBucket,
                             const uint32_t* __restrict__ keys1, const uint32_t* __restrict__ bbase1,
                             uint32_t* __restrict__ cursor1,
                             uint32_t* __restrict__ bkey, uint32_t* __restrict__ bval) {
  int n = blockIdx.x * blockDim.x + threadIdx.x;
  if (n >= N_TOK) return;
  int k = ind[n];
  uint32_t p = atomicAdd(&tokCur[k], 1u);
  tokBucket[tokBase[k] + p] = (uint32_t)n;
  uint32_t k1 = keys1[n];
  uint32_t b = k1 >> 21;
  uint32_t q = atomicAdd(&cursor1[b], 1u);
  uint32_t s = bbase1[b] + q;
  bkey[s] = k1; bval[s] = (uint32_t)n;   // value == tie-break position for round 1
}

// ---------------- fused: blocks [0,512) esum segment-sum, [512,2560) rank1+scatter2 ----------------
#define ES_BLOCKS 512
__global__ void esum_rank1(const float* __restrict__ x, const uint32_t* __restrict__ tokBase,
                           const uint32_t* __restrict__ cntTok,
                           const uint32_t* __restrict__ tokBucket,
                           float* __restrict__ esum,
                           const uint32_t* __restrict__ bkey, const uint32_t* __restrict__ bval,
                           const uint32_t* __restrict__ bbase1, const uint32_t* __restrict__ bcount1,
                           const uint32_t* __restrict__ keys2,
                           const uint32_t* __restrict__ bbase2, uint32_t* __restrict__ cursor2,
                           uint32_t* __restrict__ bkey2, uint32_t* __restrict__ bval2,
                           uint32_t* __restrict__ bpos2) {
  const int tid = threadIdx.x;
  if (blockIdx.x < ES_BLOCKS) {
    // esum[k] = sum of x rows assigned to k (wave per code)
    const uint32_t wv = ((uint32_t)blockIdx.x * 256 + tid) >> 6;
    const int lane = tid & 63;
    const uint32_t base = tokBase[wv], cnt = cntTok[wv];
    float4 a0 = {0.f, 0.f, 0.f, 0.f}, a1 = {0.f, 0.f, 0.f, 0.f};
    uint32_t i = 0;
    for (; i + 2 <= cnt; i += 2) {
      uint32_t n0 = tokBucket[base + i], n1 = tokBucket[base + i + 1];
      float4 v0 = ((const float4*)x)[(size_t)n0 * 64 + lane];
      float4 v1 = ((const float4*)x)[(size_t)n1 * 64 + lane];
      a0.x += v0.x; a0.y += v0.y; a0.z += v0.z; a0.w += v0.w;
      a1.x += v1.x; a1.y += v1.y; a1.z += v1.z; a1.w += v1.w;
    }
    if (i < cnt) {
      uint32_t n0 = tokBucket[base + i];
      float4 v0 = ((const float4*)x)[(size_t)n0 * 64 + lane];
      a0.x += v0.x; a0.y += v0.y; a0.z += v0.z; a0.w += v0.w;
    }
    float4 r; r.x = a0.x + a1.x; r.y = a0.y + a1.y; r.z = a0.z + a1.z; r.w = a0.w + a1.w;
    ((float4*)esum)[(size_t)wv * 64 + lane] = r;
    return;
  }
  // rank round-1 elements (stable by (key,pos)) and scatter into round-2 buckets
  int b = blockIdx.x - ES_BLOCKS;   // [0, 2048)
  uint32_t base = bbase1[b], cnt = bcount1[b];
  for (uint32_t t = tid; t < cnt; t += 256) {
    uint32_t k = bkey[base + t], pv = bval[base + t];
    uint32_t r = 0;
    for (uint32_t j = 0; j < cnt; ++j) {
      uint32_t kj = bkey[base + j], pj = bval[base + j];
      r += (kj < k) | ((kj == k) & (pj < pv));
    }
    uint32_t p = base + r;          // global round-1 sorted position
    uint32_t k2 = keys2[p];
    uint32_t b2 = k2 >> 21;
    uint32_t q = atomicAdd(&cursor2[b2], 1u);
    uint32_t s = bbase2[b2] + q;
    bkey2[s] = k2; bval2[s] = pv; bpos2[s] = p;
  }
}

// ---------------- round-2 rank; only positions < KCB consumed ----------------
__global__ void rank2(const uint32_t* __restrict__ bkey2, const uint32_t* __restrict__ bval2,
                      const uint32_t* __restrict__ bpos2,
                      const uint32_t* __restrict__ bbase2, const uint32_t* __restrict__ bcount2,
                      uint32_t* __restrict__ perm) {
  int b = blockIdx.x;
  uint32_t base = bbase2[b];
  if (base >= KCB) return;          // every element lands at position >= 2048
  uint32_t cnt = bcount2[b];
  for (uint32_t t = threadIdx.x; t < cnt; t += blockDim.x) {
    uint32_t k = bkey2[base + t], p = bpos2[base + t];
    uint32_t r = 0;
    for (uint32_t j = 0; j < cnt; ++j) {
      uint32_t kj = bkey2[base + j], pj = bpos2[base + j];
      r += (kj < k) | ((kj == k) & (pj < p));
    }
    uint32_t pos = base + r;
    if (pos < KCB) perm[pos] = bval2[base + t];
  }
}

// ---------------- new_embed_avg + new_embed ----------------
__global__ void final_embed(const float* __restrict__ x, const float* __restrict__ cs,
                            const uint32_t* __restrict__ cntTok,
                            const float* __restrict__ eavg, const float* __restrict__ esum,
                            const int* __restrict__ expired, const double* __restrict__ nsum,
                            const uint32_t* __restrict__ perm,
                            float* __restrict__ out_eavg, float* __restrict__ out_ne) {
  int idx = blockIdx.x * blockDim.x + threadIdx.x;   // over KCB*64 float4s
  if (idx >= KCB * 64) return;
  int k = idx >> 6, c = idx & 63;
  float4 ea = ((const float4*)eavg)[idx];
  float4 es = ((const float4*)esum)[idx];
  double ax = 0.99 * (double)ea.x + 0.01 * (double)es.x;
  double ay = 0.99 * (double)ea.y + 0.01 * (double)es.y;
  double az = 0.99 * (double)ea.z + 0.01 * (double)es.z;
  double aw = 0.99 * (double)ea.w + 0.01 * (double)es.w;
  float4 nv; nv.x = (float)ax; nv.y = (float)ay; nv.z = (float)az; nv.w = (float)aw;
  ((float4*)out_eavg)[idx] = nv;
  float4 r;
  if (expired[k]) {
    r = ((const float4*)x)[(size_t)perm[k] * 64 + c];
  } else {
    double ncs = 0.99 * (double)cs[k] + 0.01 * (double)cntTok[k];
    double n = nsum[0];
    double sm = (ncs + 1e-5) / (n + 2048.0 * 1e-5) * n;
    r.x = (float)(ax / sm); r.y = (float)(ay / sm);
    r.z = (float)(az / sm); r.w = (float)(aw / sm);
  }
  ((float4*)out_ne)[idx] = r;
}

// ---------------- launch ----------------
extern "C" void kernel_launch(void* const* d_in, const int* in_sizes, int n_in,
                              void* d_out, int out_size, void* d_ws, size_t ws_size,
                              hipStream_t stream) {
  const float* x     = (const float*)d_in[0];
  const float* embed = (const float*)d_in[1];
  const float* cs    = (const float*)d_in[2];
  const float* eavg  = (const float*)d_in[3];

  float* out = (float*)d_out;
  float* outQ    = out;                  // 12,288,000
  float* outC    = out + 12288000;       // 48,000
  float* outNCS  = out + 12336000;       // 2,048
  float* outEAVG = out + 12338048;       // 524,288
  float* outNE   = out + 12862336;       // 524,288

  char* w = (char*)d_ws;
  size_t off = 0;
  auto alloc = [&](size_t bytes) -> void* {
    void* p = w + off; off += (bytes + 255) & ~(size_t)255; return p;
  };
  unsigned short* xh = (unsigned short*)alloc((size_t)N_TOK * DIMS * 2);
  unsigned short* eh = (unsigned short*)alloc((size_t)KCB * DIMS * 2);
  float*    e2f     = (float*)alloc(KCB * 4);
  double*   e2d     = (double*)alloc(KCB * 8);
  float*    esum    = (float*)alloc((size_t)KCB * DIMS * 4);
  uint32_t* pbest   = (uint32_t*)alloc((size_t)8 * N_TOK * 4);
  uint32_t* psecond = (uint32_t*)alloc((size_t)8 * N_TOK * 4);
  uint32_t* pthird  = (uint32_t*)alloc((size_t)8 * N_TOK * 4);
  int*      ind     = (int*)alloc(N_TOK * 4);
  int*      candRows= (int*)alloc(N_TOK * 4);
  int*      candCnt = (int*)alloc(N_TOK * 4);
  int*      candIdx = (int*)alloc((size_t)N_TOK * 16 * 4);
  int*      listC   = (int*)alloc(N_TOK * 4);
  double*   nsum    = (double*)alloc(256);
  int*      expired = (int*)alloc(KCB * 4);
  uint32_t* tokBase = (uint32_t*)alloc(KCB * 4);
  uint32_t* tokCur  = (uint32_t*)alloc(KCB * 4);
  uint32_t* tokBucket = (uint32_t*)alloc(N_TOK * 4);
  uint32_t* keys1   = (uint32_t*)alloc(N_TOK * 4);
  uint32_t* keys2   = (uint32_t*)alloc(N_TOK * 4);
  uint32_t* bkey    = (uint32_t*)alloc(N_TOK * 4);
  uint32_t* bval    = (uint32_t*)alloc(N_TOK * 4);
  uint32_t* bkey2   = (uint32_t*)alloc(N_TOK * 4);
  uint32_t* bval2   = (uint32_t*)alloc(N_TOK * 4);
  uint32_t* bpos2   = (uint32_t*)alloc(N_TOK * 4);
  uint32_t* bbase1  = (uint32_t*)alloc(KCB * 4);
  uint32_t* bbase2  = (uint32_t*)alloc(KCB * 4);
  uint32_t* cursor1 = (uint32_t*)alloc(KCB * 4);
  uint32_t* cursor2 = (uint32_t*)alloc(KCB * 4);
  uint32_t* perm    = (uint32_t*)alloc(KCB * 4);
  // contiguous zero region: cntAB(256) | cntTok | bcount1 | bcount2
  uint32_t* cntAB   = (uint32_t*)alloc(256);
  uint32_t* cntTok  = (uint32_t*)alloc(KCB * 4);
  uint32_t* bcount1 = (uint32_t*)alloc(KCB * 4);
  uint32_t* bcount2 = (uint32_t*)alloc(KCB * 4);

  hipMemsetAsync(cntAB, 0, 256 + 3 * KCB * 4, stream);   // one memset for all counters

  // split + e2 + both permutation key rounds (independent ranges, one kernel)
  e2split_keys<<<(N_TOK * DIMS / 8 + KCB * DIMS / 8 + KCB + N_TOK + 255) / 256, 256, 0,
                 stream>>>(x, xh, embed, eh, e2f, e2d, keys1, keys2, bcount1, bcount2);

  dist_mfma<<<3000, 256, 0, stream>>>(xh, eh, e2f, pbest, psecond, pthird);
  merge8<<<188, 256, 0, stream>>>(pbest, psecond, pthird,
                                  ind, candRows, candIdx, candCnt, listC,
                                  &cntAB[0], &cntAB[1]);
  refine_both<<<RC_BLOCKS + RF_BLOCKS, 256, 0, stream>>>(
      x, embed, e2d, candRows, candIdx, candCnt, listC, cntAB, ind);

  // quantize output + token histogram, then code-major segment sum (no f32 atomics)
  gather_q<<<12000, 256, 0, stream>>>(embed, ind, outQ, outC, cntTok);
  scan3<<<3, 1024, 0, stream>>>(cntTok, tokBase, tokCur, cs, outNCS, expired, nsum,
                                bcount1, bbase1, cursor1, bcount2, bbase2, cursor2);
  scatter_both<<<188, 256, 0, stream>>>(ind, tokBase, tokCur, tokBucket,
                                        keys1, bbase1, cursor1, bkey, bval);
  esum_rank1<<<ES_BLOCKS + KCB, 256, 0, stream>>>(
      x, tokBase, cntTok, tokBucket, esum,
      bkey, bval, bbase1, bcount1, keys2, bbase2, cursor2, bkey2, bval2, bpos2);
  rank2<<<2048, 64, 0, stream>>>(bkey2, bval2, bpos2, bbase2, bcount2, perm);

  final_embed<<<512, 256, 0, stream>>>(x, cs, cntTok, eavg, esum, expired, nsum,
                                       perm, outEAVG, outNE);
}

// Round 17
// 226.256 us; speedup vs baseline: 1.2888x; 1.0410x over previous
//
#include <hip/hip_runtime.h>
#include <hip/hip_bf16.h>
#include <stdint.h>
#include <math.h>

// Problem constants
#define N_TOK 48000     // 32*1500
#define DIMS  256
#define KCB   2048
// 1-pass bf16 approx score error: diff std ~6e-3, max over 1e8 pairs ~0.037.
// Packed-u32: score+32 (all in (0,64)), truncate low 11 bits -> quant error
// <= 64*2^-12 = 0.0156/side. WND = 0.10 >= 0.037 + 2*0.0156 with margin.
// True winner's packed score >= best - WND. Candidates = per-tile top-2; if a
// tile's THIRD value is in-window the winner may be unstored -> full re-scan.
#define WND 0.10f
#define BIAS 32.0f

typedef __attribute__((ext_vector_type(8))) short bf16x8;
typedef __attribute__((ext_vector_type(4))) float f32x4;
typedef __attribute__((ext_vector_type(8))) unsigned short u16x8;

// ---------------- bf16 helpers (explicit RNE) ----------------
__device__ __forceinline__ unsigned short bf16rn(float f) {
  uint32_t u = __float_as_uint(f);
  uint32_t r = (u + 0x7FFFu + ((u >> 16) & 1u)) >> 16;
  return (unsigned short)r;
}

// ---------------- 3-input u32 ALU (single VOP3 each on gfx950) ----------------
__device__ __forceinline__ uint32_t max3u(uint32_t a, uint32_t b, uint32_t c) {
  uint32_t d; asm("v_max3_u32 %0, %1, %2, %3" : "=v"(d) : "v"(a), "v"(b), "v"(c));
  return d;
}
__device__ __forceinline__ uint32_t med3u(uint32_t a, uint32_t b, uint32_t c) {
  uint32_t d; asm("v_med3_u32 %0, %1, %2, %3" : "=v"(d) : "v"(a), "v"(b), "v"(c));
  return d;
}
__device__ __forceinline__ uint32_t min3u(uint32_t a, uint32_t b, uint32_t c) {
  uint32_t d; asm("v_min3_u32 %0, %1, %2, %3" : "=v"(d) : "v"(a), "v"(b), "v"(c));
  return d;
}

// ---------------- packed sortable score ----------------
__device__ __forceinline__ uint32_t packBiased(float fb, uint32_t invIdx) {
  float c = fmaxf(fb, 0.0f);
  return (__float_as_uint(c) & ~0x7FFu) | invIdx;
}
__device__ __forceinline__ uint32_t packThrBiased(float fb) {
  float c = fmaxf(fb, 0.0f);
  return __float_as_uint(c) & ~0x7FFu;
}
__device__ __forceinline__ float unpackBiased(uint32_t u) {   // returns score+BIAS
  return __uint_as_float(u & ~0x7FFu);
}
// sorted top-3 insert (b>=s>=t): 4 ops via med3/min3
// cases: v>b -> (v,b,s); s<v<=b -> (b,v,s); t<v<=s -> (b,s,v); v<=t -> unchanged
__device__ __forceinline__ void ins3u(uint32_t& b, uint32_t& s, uint32_t& t, uint32_t v) {
  uint32_t b0 = b;
  b = max(b, v);
  t = max(t, min3u(b0, s, v));
  s = med3u(b0, s, v);
}

// ---------------- Threefry-2x32 (matches jax._src.prng, partitionable) ----------------
__device__ inline void tf2x32(uint32_t k0, uint32_t k1, uint32_t c0, uint32_t c1,
                              uint32_t& o0, uint32_t& o1) {
  uint32_t ks2 = k0 ^ k1 ^ 0x1BD11BDAu;
  uint32_t x0 = c0 + k0, x1 = c1 + k1;
#define TF_R(r) { x0 += x1; x1 = (x1 << (r)) | (x1 >> (32 - (r))); x1 ^= x0; }
  TF_R(13) TF_R(15) TF_R(26) TF_R(6)
  x0 += k1; x1 += ks2 + 1u;
  TF_R(17) TF_R(29) TF_R(16) TF_R(24)
  x0 += ks2; x1 += k0 + 2u;
  TF_R(13) TF_R(15) TF_R(26) TF_R(6)
  x0 += k0; x1 += k1 + 3u;
  TF_R(17) TF_R(29) TF_R(16) TF_R(24)
  x0 += k1; x1 += ks2 + 4u;
  TF_R(13) TF_R(15) TF_R(26) TF_R(6)
  x0 += ks2; x1 += k0 + 5u;
#undef TF_R
  o0 = x0; o1 = x1;
}

__device__ inline void get_round_key(int round, uint32_t& ka, uint32_t& kb) {
  const uint32_t b0 = 0u, b1 = 1u;  // jax.random.key(1) -> (0,1)
  uint32_t K1a, K1b, S1a, S1b;
  tf2x32(b0, b1, 0u, 0u, K1a, K1b);
  tf2x32(b0, b1, 0u, 1u, S1a, S1b);
  if (round == 1) { ka = S1a; kb = S1b; return; }
  uint32_t S2a, S2b;
  tf2x32(K1a, K1b, 0u, 1u, S2a, S2b);
  ka = S2a; kb = S2b;
}

__device__ inline uint32_t gen_key(int round, uint32_t i) {
  uint32_t ka, kb, o0, o1;
  get_round_key(round, ka, kb);
  tf2x32(ka, kb, 0u, i, o0, o1);
  return o0 ^ o1;
}

// ---------------- global_load_lds wrapper (16B) ----------------
__device__ __forceinline__ void gload_lds16(const void* g, void* l) {
  __builtin_amdgcn_global_load_lds(
      (const __attribute__((address_space(1))) uint32_t*)g,
      (__attribute__((address_space(3))) uint32_t*)l, 16, 0, 0);
}

// ---------------- fused: bf16 split (x,embed) + e2 terms + permutation keys ----------------
// e2f[k] = BIAS - e2[k]  (so fmaf(2, dot, e2f) = score + BIAS directly)
__global__ void e2split_keys(const float* __restrict__ x, unsigned short* __restrict__ xh,
                             const float* __restrict__ embed, unsigned short* __restrict__ eh,
                             float* __restrict__ e2f, double* __restrict__ e2d,
                             uint32_t* __restrict__ keys1, uint32_t* __restrict__ keys2,
                             uint32_t* __restrict__ bcount1, uint32_t* __restrict__ bcount2) {
  const int nx = N_TOK * DIMS / 8;
  const int ne = KCB * DIMS / 8;
  int i = blockIdx.x * blockDim.x + threadIdx.x;
  if (i < nx + ne) {
    const float* src; unsigned short* dst; int j;
    if (i < nx) { src = x; dst = xh; j = i; }
    else { src = embed; dst = eh; j = i - nx; }
    float4 a = ((const float4*)src)[j * 2];
    float4 b = ((const float4*)src)[j * 2 + 1];
    float v[8] = {a.x, a.y, a.z, a.w, b.x, b.y, b.z, b.w};
    u16x8 h;
#pragma unroll
    for (int q = 0; q < 8; ++q) h[q] = bf16rn(v[q]);
    *(u16x8*)&dst[(size_t)j * 8] = h;
    return;
  }
  int k = i - (nx + ne);
  if (k < KCB) {
    const float4* er = (const float4*)(embed + (size_t)k * DIMS);
    float s = 0.f;
    double sd = 0.0;
    for (int c = 0; c < DIMS / 4; ++c) {
      float4 v = er[c];
      s = fmaf(v.x, v.x, s); s = fmaf(v.y, v.y, s);
      s = fmaf(v.z, v.z, s); s = fmaf(v.w, v.w, s);
      sd += (double)v.x * v.x + (double)v.y * v.y
          + (double)v.z * v.z + (double)v.w * v.w;
    }
    e2f[k] = BIAS - s;
    e2d[k] = sd;
    return;
  }
  int n = k - KCB;
  if (n < N_TOK) {
    uint32_t k1 = gen_key(1, (uint32_t)n);
    uint32_t k2 = gen_key(2, (uint32_t)n);
    keys1[n] = k1; keys2[n] = k2;
    atomicAdd(&bcount1[k1 >> 21], 1u);
    atomicAdd(&bcount2[k2 >> 21], 1u);
  }
}

// ---------------- MFMA distance top-3 (single bf16 pass, packed epilogue) ----------------
// approx score+BIAS = 2*(xh.eh) + e2f[k]; 128x256 tile, BK=32, 8 steps,
// double-buffered LDS. Bank swizzle (both-sides involution): chunk ^= (row>>1)&3.
// NOTE: launch_bounds (256,2) -- forcing 3 blocks/CU (r14) capped VGPR at 84
// and spilled acc to scratch (WRITE_SIZE 4.5->106 MB, 79->112 us).
__global__ __launch_bounds__(256, 2) void dist_mfma(
    const unsigned short* __restrict__ xh, const unsigned short* __restrict__ eh,
    const float* __restrict__ e2f,
    uint32_t* __restrict__ pb, uint32_t* __restrict__ ps, uint32_t* __restrict__ pt)
{
  // staging (49152 B) and reduction table (128*99*4 = 50688 B) alias
  __shared__ __align__(16) char smem[50688];
  short (*As)[128 * 32] = (short(*)[128 * 32])smem;            // 2 x 8 KB
  short (*Bs)[256 * 32] = (short(*)[256 * 32])(smem + 16384);  // 2 x 16 KB
  uint32_t* red = (uint32_t*)smem;                             // [128][99] u32

  const int tid = threadIdx.x;
  const int lane = tid & 63, w = tid >> 6;
  const int wr = w >> 1, wc = w & 1;      // wave tile: 64 rows x 128 cols
  const int l15 = lane & 15, lg = lane >> 4;

  // XCD grouping: the 8 y-tiles sharing an x-tile get bids == same (mod 8),
  // spaced 8 apart -> same XCD L2 -> x-tile fetched from HBM once per XCD.
  int bx, by;
  {
    const int bid = blockIdx.x;
    if (bid < 2944) { int g = bid >> 6, r = bid & 63; bx = g * 8 + (r & 7); by = r >> 3; }
    else            { int t2 = bid - 2944; bx = 368 + (t2 % 7); by = t2 / 7; }
  }
  const int n0 = bx * 128;   // token tile base
  const int c0 = by * 256;   // code tile base

  f32x4 acc[4][8];
#pragma unroll
  for (int mf = 0; mf < 4; ++mf)
#pragma unroll
    for (int nf = 0; nf < 8; ++nf) acc[mf][nf] = (f32x4){0.f, 0.f, 0.f, 0.f};

  // stage step t into buffer t&1 (linear LDS dest; source pre-swizzled)
  auto stage = [&](int t) {
    const int d0 = t << 5;     // d-chunk of 32 shorts
    const int q = t & 1;
#pragma unroll
    for (int i = 0; i < 2; ++i) {
      const int c = i * 256 + tid;
      const int row = c >> 2;
      const int sc = ((c & 3) ^ ((row >> 1) & 3)) << 3;   // swizzled source chunk
      gload_lds16(xh + (size_t)(n0 + row) * DIMS + d0 + sc, (void*)&As[q][c * 8]);
    }
#pragma unroll
    for (int i = 0; i < 4; ++i) {
      const int c = i * 256 + tid;
      const int row = c >> 2;
      const int sc = ((c & 3) ^ ((row >> 1) & 3)) << 3;
      gload_lds16(eh + (size_t)(c0 + row) * DIMS + d0 + sc, (void*)&Bs[q][c * 8]);
    }
  };

  stage(0);
  __syncthreads();   // buf0 ready

#pragma unroll 1
  for (int t = 0; t < 8; ++t) {
    if (t < 7) stage(t + 1);         // issue next-step loads (overlap w/ compute)
    const int q = t & 1;
    bf16x8 af[4], bfv[8];
#pragma unroll
    for (int mf = 0; mf < 4; ++mf) {
      const int r = wr * 64 + mf * 16 + l15;
      af[mf] = *(const bf16x8*)&As[q][r * 32 + ((lg ^ ((r >> 1) & 3)) << 3)];
    }
#pragma unroll
    for (int nf = 0; nf < 8; ++nf) {
      const int r = wc * 128 + nf * 16 + l15;
      bfv[nf] = *(const bf16x8*)&Bs[q][r * 32 + ((lg ^ ((r >> 1) & 3)) << 3)];
    }
#pragma unroll
    for (int mf = 0; mf < 4; ++mf)
#pragma unroll
      for (int nf = 0; nf < 8; ++nf)
        acc[mf][nf] = __builtin_amdgcn_mfma_f32_16x16x32_bf16(
            af[mf], bfv[nf], acc[mf][nf], 0, 0, 0);
    __syncthreads();                 // staged loads drained + rw hazards
  }
  // K-loop done; last barrier above makes staging LDS safe to reuse as `red`.

  float e2v[8];
  uint32_t inv[8];
#pragma unroll
  for (int nf = 0; nf < 8; ++nf) {
    int k = c0 + wc * 128 + nf * 16 + l15;
    e2v[nf] = e2f[k];
    inv[nf] = 2047u - (uint32_t)k;
  }

  const int colbase = wc * 16 + l15;
#pragma unroll
  for (int mf = 0; mf < 4; ++mf) {
#pragma unroll
    for (int reg = 0; reg < 4; ++reg) {
      uint32_t p0 = packBiased(fmaf(2.f, acc[mf][0][reg], e2v[0]), inv[0]);
      uint32_t p1 = packBiased(fmaf(2.f, acc[mf][1][reg], e2v[1]), inv[1]);
      uint32_t p2 = packBiased(fmaf(2.f, acc[mf][2][reg], e2v[2]), inv[2]);
      // sort3 init via 3-input ops (3 VALU, exact)
      uint32_t b  = max3u(p0, p1, p2);
      uint32_t s  = med3u(p0, p1, p2);
      uint32_t t3 = min3u(p0, p1, p2);
#pragma unroll
      for (int nf = 3; nf < 8; ++nf) {
        float f = fmaf(2.f, acc[mf][nf][reg], e2v[nf]);
        ins3u(b, s, t3, packBiased(f, inv[nf]));
      }
      const int row = wr * 64 + mf * 16 + lg * 4 + reg;
      uint32_t* p = &red[row * 99 + colbase * 3];
      p[0] = b; p[1] = s; p[2] = t3;
    }
  }
  __syncthreads();
  {
    const int row = tid >> 1, half = tid & 1;
    uint32_t b = 0u, s = 0u, t3 = 0u;
    const uint32_t* p = &red[row * 99 + half * 48];
#pragma unroll 4
    for (int c = 0; c < 48; ++c) ins3u(b, s, t3, p[c]);
    if (half) {
      uint32_t* q = &red[row * 99 + 96];
      q[0] = b; q[1] = s; q[2] = t3;
    }
    __syncthreads();
    if (!half) {
      const uint32_t* q = &red[row * 99 + 96];
      ins3u(b, s, t3, q[0]);
      ins3u(b, s, t3, q[1]);
      ins3u(b, s, t3, q[2]);
      size_t o = (size_t)by * N_TOK + n0 + row;
      pb[o] = b; ps[o] = s; pt[o] = t3;
    }
  }
}

// ---------------- merge 8 column-tile partials + candidates + final-row stats ----------------
__global__ void merge8(const uint32_t* __restrict__ pb, const uint32_t* __restrict__ ps,
                       const uint32_t* __restrict__ pt,
                       int* __restrict__ ind,
                       int* __restrict__ candRows, int* __restrict__ candIdx,
                       int* __restrict__ candCnt, int* __restrict__ listC,
                       uint32_t* __restrict__ cntA, uint32_t* __restrict__ cntC,
                       float* __restrict__ outcodes, uint32_t* __restrict__ cntTok) {
  int n = blockIdx.x * blockDim.x + threadIdx.x;
  if (n >= N_TOK) return;
  uint32_t tb[8], tsv[8], ttv[8];
#pragma unroll
  for (int tt = 0; tt < 8; ++tt) {
    size_t o = (size_t)tt * N_TOK + n;
    tb[tt] = pb[o]; tsv[tt] = ps[o]; ttv[tt] = pt[o];
  }
  uint32_t best = tb[0];
#pragma unroll
  for (int tt = 1; tt < 8; ++tt) best = max(best, tb[tt]);
  int kb = 2047 - (int)(best & 0x7FFu);
  ind[n] = kb;   // provisional winner (final unless refined below)
  const uint32_t thr = packThrBiased(unpackBiased(best) - WND);
  int m = 0; bool full = false;
#pragma unroll
  for (int tt = 0; tt < 8; ++tt) {
    m += (tb[tt] >= thr) + (tsv[tt] >= thr);
    full = full || (ttv[tt] >= thr);   // a tile's unstored 3rd+ could be in-window
  }
  if (full) {
    listC[atomicAdd(cntC, 1u)] = n;
  } else if (m > 1) {
    uint32_t i = atomicAdd(cntA, 1u);
    candRows[i] = n; candCnt[i] = m;
    int j = 0;
#pragma unroll
    for (int tt = 0; tt < 8; ++tt) {
      if (tb[tt]  >= thr) candIdx[(size_t)i * 16 + (j++)] = 2047 - (int)(tb[tt]  & 0x7FFu);
      if (tsv[tt] >= thr) candIdx[(size_t)i * 16 + (j++)] = 2047 - (int)(tsv[tt] & 0x7FFu);
    }
  } else {
    // row is final here: codes + histogram
    outcodes[n] = (float)kb;
    atomicAdd(&cntTok[kb], 1u);
  }
}

// ---------------- fused refine: blocks [0,512) candidate path, [512,1536) full scan ----------------
#define RC_BLOCKS 512
#define RF_BLOCKS 1024
__global__ void refine_both(const float* __restrict__ x, const float* __restrict__ embed,
                            const double* __restrict__ e2d,
                            const int* __restrict__ candRows, const int* __restrict__ candIdx,
                            const int* __restrict__ candCnt,
                            const int* __restrict__ listC,
                            const uint32_t* __restrict__ cntAB,
                            int* __restrict__ ind,
                            float* __restrict__ outcodes, uint32_t* __restrict__ cntTok) {
  __shared__ double xd[DIMS];
  __shared__ double rv[256];
  __shared__ int    rk[256];
  const int tid = threadIdx.x;
  if (blockIdx.x < RC_BLOCKS) {
    // ---- wave-per-row f64 candidate decider ----
    const uint32_t nA = cntAB[0];
    const int lane = tid & 63;
    const uint32_t wid = ((uint32_t)blockIdx.x * 256 + tid) >> 6;
    const uint32_t nw = RC_BLOCKS * 4;
    for (uint32_t i = wid; i < nA; i += nw) {
      const int n = candRows[i];
      const int m = candCnt[i];
      float4 xv = ((const float4*)x)[(size_t)n * 64 + lane];
      double best = -1e300; int bk = 0x7fffffff;
      for (int j = 0; j < m; ++j) {
        int k = candIdx[(size_t)i * 16 + j];
        float4 e4 = ((const float4*)embed)[(size_t)k * 64 + lane];
        double d = (double)xv.x * e4.x + (double)xv.y * e4.y
                 + (double)xv.z * e4.z + (double)xv.w * e4.w;
#pragma unroll
        for (int mm = 1; mm < 64; mm <<= 1) d += __shfl_xor(d, mm);
        double v = 2.0 * d - e2d[k];
        if (v > best || (v == best && k < bk)) { best = v; bk = k; }
      }
      if (lane == 0) {
        ind[n] = bk;
        outcodes[n] = (float)bk;
        atomicAdd(&cntTok[bk], 1u);
      }
    }
    return;
  }
  // ---- full f64 re-scan, one row per block (rare) ----
  const uint32_t nC = cntAB[1];
  for (uint32_t it = blockIdx.x - RC_BLOCKS; it < nC; it += RF_BLOCKS) {
    const int n = listC[it];
    __syncthreads();
    xd[tid] = (double)x[(size_t)n * DIMS + tid];
    __syncthreads();
    double best = -1e300; int bk = 0x7fffffff;
    for (int k = tid; k < KCB; k += 256) {
      const float4* er = (const float4*)(embed + (size_t)k * DIMS);
      double a0 = 0.0, a1 = 0.0, a2 = 0.0, a3 = 0.0;   // ILP-4 chains
      for (int c = 0; c < 64; c += 4) {
        float4 ea = er[c], eb = er[c + 1], ec = er[c + 2], ed = er[c + 3];
        int d = c * 4;
        a0 += xd[d + 0] * ea.x + xd[d + 1] * ea.y + xd[d + 2] * ea.z + xd[d + 3] * ea.w;
        a1 += xd[d + 4] * eb.x + xd[d + 5] * eb.y + xd[d + 6] * eb.z + xd[d + 7] * eb.w;
        a2 += xd[d + 8] * ec.x + xd[d + 9] * ec.y + xd[d + 10] * ec.z + xd[d + 11] * ec.w;
        a3 += xd[d + 12] * ed.x + xd[d + 13] * ed.y + xd[d + 14] * ed.z + xd[d + 15] * ed.w;
      }
      double v = 2.0 * (a0 + a1 + a2 + a3) - e2d[k];
      if (v > best || (v == best && k < bk)) { best = v; bk = k; }
    }
    rv[tid] = best; rk[tid] = bk;
    __syncthreads();
    for (int s = 128; s > 0; s >>= 1) {
      if (tid < s) {
        double v2 = rv[tid + s]; int k2 = rk[tid + s];
        if (v2 > rv[tid] || (v2 == rv[tid] && k2 < rk[tid])) { rv[tid] = v2; rk[tid] = k2; }
      }
      __syncthreads();
    }
    if (tid == 0) {
      ind[n] = rk[0];
      outcodes[n] = (float)rk[0];
      atomicAdd(&cntTok[rk[0]], 1u);
    }
  }
}

// ---------------- fused: blocks 0-2 = three 2048-scans (+EMA), rest = outQ gather ----------------
__global__ void gather_scan(const float* __restrict__ embed, const int* __restrict__ ind,
                            float* __restrict__ outq,
                            const uint32_t* __restrict__ cntTok, uint32_t* __restrict__ tokBase,
                            uint32_t* __restrict__ tokCur,
                            const float* __restrict__ cs, float* __restrict__ out_ncs,
                            int* __restrict__ expired, double* __restrict__ nsum,
                            const uint32_t* __restrict__ bcount1, uint32_t* __restrict__ bbase1,
                            uint32_t* __restrict__ cursor1,
                            const uint32_t* __restrict__ bcount2, uint32_t* __restrict__ bbase2,
                            uint32_t* __restrict__ cursor2) {
  __shared__ uint32_t buf[2][2048];
  __shared__ double sd[1024];
  const int t = threadIdx.x;   // 1024
  if (blockIdx.x >= 3) {
    // pure gather over N_TOK*64 float4s
    int idx = (blockIdx.x - 3) * 1024 + t;
    if (idx < N_TOK * 64) {
      int n = idx >> 6, c = idx & 63;
      ((float4*)outq)[idx] = ((const float4*)embed)[(size_t)ind[n] * 64 + c];
    }
    return;
  }
  const uint32_t* in; uint32_t* out; uint32_t* cz;
  if (blockIdx.x == 0)      { in = cntTok;  out = tokBase; cz = tokCur;  }
  else if (blockIdx.x == 1) { in = bcount1; out = bbase1;  cz = cursor1; }
  else                      { in = bcount2; out = bbase2;  cz = cursor2; }
  double local = 0.0;
  for (int q = 0; q < 2; ++q) {
    int i = t + q * 1024;
    uint32_t c = in[i];
    buf[0][i] = c;
    cz[i] = 0;
    if (blockIdx.x == 0) {
      double v = 0.99 * (double)cs[i] + 0.01 * (double)c;
      out_ncs[i] = (float)v;
      expired[i] = (v < 2.0) ? 1 : 0;
      local += v;
    }
  }
  if (blockIdx.x == 0) sd[t] = local;
  __syncthreads();
  int src = 0;
  for (int off = 1; off < 2048; off <<= 1) {
    for (int q = 0; q < 2; ++q) {
      int i = t + q * 1024;
      uint32_t v = buf[src][i];
      if (i >= off) v += buf[src][i - off];
      buf[src ^ 1][i] = v;
    }
    src ^= 1; __syncthreads();
  }
  for (int q = 0; q < 2; ++q) {
    int i = t + q * 1024;
    out[i] = buf[src][i] - in[i];   // exclusive
  }
  if (blockIdx.x == 0) {
    for (int s = 512; s > 0; s >>= 1) { if (t < s) sd[t] += sd[t + s]; __syncthreads(); }
    if (t == 0) nsum[0] = sd[0];
  }
}

// ---------------- fused scatter: token buckets + round-1 key buckets ----------------
__global__ void scatter_both(const int* __restrict__ ind, const uint32_t* __restrict__ tokBase,
                             uint32_t* __restrict__ tokCur, uint32_t* __restrict__ tokBucket,
                             const uint32_t* __restrict__ keys1, const uint32_t* __restrict__ bbase1,
                             uint32_t* __restrict__ cursor1,
                             uint32_t* __restrict__ bkey, uint32_t* __restrict__ bval) {
  int n = blockIdx.x * blockDim.x + threadIdx.x;
  if (n >= N_TOK) return;
  int k = ind[n];
  uint32_t p = atomicAdd(&tokCur[k], 1u);
  tokBucket[tokBase[k] + p] = (uint32_t)n;
  uint32_t k1 = keys1[n];
  uint32_t b = k1 >> 21;
  uint32_t q = atomicAdd(&cursor1[b], 1u);
  uint32_t s = bbase1[b] + q;
  bkey[s] = k1; bval[s] = (uint32_t)n;   // value == tie-break position for round 1
}

// ---------------- fused: blocks [0,512) esum segment-sum, [512,2560) rank1+scatter2 ----------------
#define ES_BLOCKS 512
__global__ void esum_rank1(const float* __restrict__ x, const uint32_t* __restrict__ tokBase,
                           const uint32_t* __restrict__ cntTok,
                           const uint32_t* __restrict__ tokBucket,
                           float* __restrict__ esum,
                           const uint32_t* __restrict__ bkey, const uint32_t* __restrict__ bval,
                           const uint32_t* __restrict__ bbase1, const uint32_t* __restrict__ bcount1,
                           const uint32_t* __restrict__ keys2,
                           const uint32_t* __restrict__ bbase2, uint32_t* __restrict__ cursor2,
                           uint32_t* __restrict__ bkey2, uint32_t* __restrict__ bval2,
                           uint32_t* __restrict__ bpos2) {
  const int tid = threadIdx.x;
  if (blockIdx.x < ES_BLOCKS) {
    // esum[k] = sum of x rows assigned to k (wave per code)
    const uint32_t wv = ((uint32_t)blockIdx.x * 256 + tid) >> 6;
    const int lane = tid & 63;
    const uint32_t base = tokBase[wv], cnt = cntTok[wv];
    float4 a0 = {0.f, 0.f, 0.f, 0.f}, a1 = {0.f, 0.f, 0.f, 0.f};
    uint32_t i = 0;
    for (; i + 2 <= cnt; i += 2) {
      uint32_t n0 = tokBucket[base + i], n1 = tokBucket[base + i + 1];
      float4 v0 = ((const float4*)x)[(size_t)n0 * 64 + lane];
      float4 v1 = ((const float4*)x)[(size_t)n1 * 64 + lane];
      a0.x += v0.x; a0.y += v0.y; a0.z += v0.z; a0.w += v0.w;
      a1.x += v1.x; a1.y += v1.y; a1.z += v1.z; a1.w += v1.w;
    }
    if (i < cnt) {
      uint32_t n0 = tokBucket[base + i];
      float4 v0 = ((const float4*)x)[(size_t)n0 * 64 + lane];
      a0.x += v0.x; a0.y += v0.y; a0.z += v0.z; a0.w += v0.w;
    }
    float4 r; r.x = a0.x + a1.x; r.y = a0.y + a1.y; r.z = a0.z + a1.z; r.w = a0.w + a1.w;
    ((float4*)esum)[(size_t)wv * 64 + lane] = r;
    return;
  }
  // rank round-1 elements (stable by (key,pos)) and scatter into round-2 buckets
  int b = blockIdx.x - ES_BLOCKS;   // [0, 2048)
  uint32_t base = bbase1[b], cnt = bcount1[b];
  for (uint32_t t = tid; t < cnt; t += 256) {
    uint32_t k = bkey[base + t], pv = bval[base + t];
    uint32_t r = 0;
    for (uint32_t j = 0; j < cnt; ++j) {
      uint32_t kj = bkey[base + j], pj = bval[base + j];
      r += (kj < k) | ((kj == k) & (pj < pv));
    }
    uint32_t p = base + r;          // global round-1 sorted position
    uint32_t k2 = keys2[p];
    uint32_t b2 = k2 >> 21;
    uint32_t q = atomicAdd(&cursor2[b2], 1u);
    uint32_t s = bbase2[b2] + q;
    bkey2[s] = k2; bval2[s] = pv; bpos2[s] = p;
  }
}

// ---------------- round-2 rank; only positions < KCB consumed ----------------
__global__ void rank2(const uint32_t* __restrict__ bkey2, const uint32_t* __restrict__ bval2,
                      const uint32_t* __restrict__ bpos2,
                      const uint32_t* __restrict__ bbase2, const uint32_t* __restrict__ bcount2,
                      uint32_t* __restrict__ perm) {
  int b = blockIdx.x;
  uint32_t base = bbase2[b];
  if (base >= KCB) return;          // every element lands at position >= 2048
  uint32_t cnt = bcount2[b];
  for (uint32_t t = threadIdx.x; t < cnt; t += blockDim.x) {
    uint32_t k = bkey2[base + t], p = bpos2[base + t];
    uint32_t r = 0;
    for (uint32_t j = 0; j < cnt; ++j) {
      uint32_t kj = bkey2[base + j], pj = bpos2[base + j];
      r += (kj < k) | ((kj == k) & (pj < p));
    }
    uint32_t pos = base + r;
    if (pos < KCB) perm[pos] = bval2[base + t];
  }
}

// ---------------- new_embed_avg + new_embed ----------------
__global__ void final_embed(const float* __restrict__ x, const float* __restrict__ cs,
                            const uint32_t* __restrict__ cntTok,
                            const float* __restrict__ eavg, const float* __restrict__ esum,
                            const int* __restrict__ expired, const double* __restrict__ nsum,
                            const uint32_t* __restrict__ perm,
                            float* __restrict__ out_eavg, float* __restrict__ out_ne) {
  int idx = blockIdx.x * blockDim.x + threadIdx.x;   // over KCB*64 float4s
  if (idx >= KCB * 64) return;
  int k = idx >> 6, c = idx & 63;
  float4 ea = ((const float4*)eavg)[idx];
  float4 es = ((const float4*)esum)[idx];
  double ax = 0.99 * (double)ea.x + 0.01 * (double)es.x;
  double ay = 0.99 * (double)ea.y + 0.01 * (double)es.y;
  double az = 0.99 * (double)ea.z + 0.01 * (double)es.z;
  double aw = 0.99 * (double)ea.w + 0.01 * (double)es.w;
  float4 nv; nv.x = (float)ax; nv.y = (float)ay; nv.z = (float)az; nv.w = (float)aw;
  ((float4*)out_eavg)[idx] = nv;
  float4 r;
  if (expired[k]) {
    r = ((const float4*)x)[(size_t)perm[k] * 64 + c];
  } else {
    double ncs = 0.99 * (double)cs[k] + 0.01 * (double)cntTok[k];
    double n = nsum[0];
    double sm = (ncs + 1e-5) / (n + 2048.0 * 1e-5) * n;
    r.x = (float)(ax / sm); r.y = (float)(ay / sm);
    r.z = (float)(az / sm); r.w = (float)(aw / sm);
  }
  ((float4*)out_ne)[idx] = r;
}

// ---------------- launch ----------------
extern "C" void kernel_launch(void* const* d_in, const int* in_sizes, int n_in,
                              void* d_out, int out_size, void* d_ws, size_t ws_size,
                              hipStream_t stream) {
  const float* x     = (const float*)d_in[0];
  const float* embed = (const float*)d_in[1];
  const float* cs    = (const float*)d_in[2];
  const float* eavg  = (const float*)d_in[3];

  float* out = (float*)d_out;
  float* outQ    = out;                  // 12,288,000
  float* outC    = out + 12288000;       // 48,000
  float* outNCS  = out + 12336000;       // 2,048
  float* outEAVG = out + 12338048;       // 524,288
  float* outNE   = out + 12862336;       // 524,288

  char* w = (char*)d_ws;
  size_t off = 0;
  auto alloc = [&](size_t bytes) -> void* {
    void* p = w + off; off += (bytes + 255) & ~(size_t)255; return p;
  };
  unsigned short* xh = (unsigned short*)alloc((size_t)N_TOK * DIMS * 2);
  unsigned short* eh = (unsigned short*)alloc((size_t)KCB * DIMS * 2);
  float*    e2f     = (float*)alloc(KCB * 4);
  double*   e2d     = (double*)alloc(KCB * 8);
  float*    esum    = (float*)alloc((size_t)KCB * DIMS * 4);
  uint32_t* pbest   = (uint32_t*)alloc((size_t)8 * N_TOK * 4);
  uint32_t* psecond = (uint32_t*)alloc((size_t)8 * N_TOK * 4);
  uint32_t* pthird  = (uint32_t*)alloc((size_t)8 * N_TOK * 4);
  int*      ind     = (int*)alloc(N_TOK * 4);
  int*      candRows= (int*)alloc(N_TOK * 4);
  int*      candCnt = (int*)alloc(N_TOK * 4);
  int*      candIdx = (int*)alloc((size_t)N_TOK * 16 * 4);
  int*      listC   = (int*)alloc(N_TOK * 4);
  double*   nsum    = (double*)alloc(256);
  int*      expired = (int*)alloc(KCB * 4);
  uint32_t* tokBase = (uint32_t*)alloc(KCB * 4);
  uint32_t* tokCur  = (uint32_t*)alloc(KCB * 4);
  uint32_t* tokBucket = (uint32_t*)alloc(N_TOK * 4);
  uint32_t* keys1   = (uint32_t*)alloc(N_TOK * 4);
  uint32_t* keys2   = (uint32_t*)alloc(N_TOK * 4);
  uint32_t* bkey    = (uint32_t*)alloc(N_TOK * 4);
  uint32_t* bval    = (uint32_t*)alloc(N_TOK * 4);
  uint32_t* bkey2   = (uint32_t*)alloc(N_TOK * 4);
  uint32_t* bval2   = (uint32_t*)alloc(N_TOK * 4);
  uint32_t* bpos2   = (uint32_t*)alloc(N_TOK * 4);
  uint32_t* bbase1  = (uint32_t*)alloc(KCB * 4);
  uint32_t* bbase2  = (uint32_t*)alloc(KCB * 4);
  uint32_t* cursor1 = (uint32_t*)alloc(KCB * 4);
  uint32_t* cursor2 = (uint32_t*)alloc(KCB * 4);
  uint32_t* perm    = (uint32_t*)alloc(KCB * 4);
  // contiguous zero region: cntAB(256) | cntTok | bcount1 | bcount2
  uint32_t* cntAB   = (uint32_t*)alloc(256);
  uint32_t* cntTok  = (uint32_t*)alloc(KCB * 4);
  uint32_t* bcount1 = (uint32_t*)alloc(KCB * 4);
  uint32_t* bcount2 = (uint32_t*)alloc(KCB * 4);

  hipMemsetAsync(cntAB, 0, 256 + 3 * KCB * 4, stream);   // one memset for all counters

  // split + e2 + both permutation key rounds (independent ranges, one kernel)
  e2split_keys<<<(N_TOK * DIMS / 8 + KCB * DIMS / 8 + KCB + N_TOK + 255) / 256, 256, 0,
                 stream>>>(x, xh, embed, eh, e2f, e2d, keys1, keys2, bcount1, bcount2);

  dist_mfma<<<3000, 256, 0, stream>>>(xh, eh, e2f, pbest, psecond, pthird);
  merge8<<<188, 256, 0, stream>>>(pbest, psecond, pthird,
                                  ind, candRows, candIdx, candCnt, listC,
                                  &cntAB[0], &cntAB[1], outC, cntTok);
  refine_both<<<RC_BLOCKS + RF_BLOCKS, 256, 0, stream>>>(
      x, embed, e2d, candRows, candIdx, candCnt, listC, cntAB, ind, outC, cntTok);

  // blocks 0-2: scans (token + both key rounds) + EMA; blocks 3+: outQ gather
  gather_scan<<<3 + (N_TOK * 64 + 1023) / 1024, 1024, 0, stream>>>(
      embed, ind, outQ,
      cntTok, tokBase, tokCur, cs, outNCS, expired, nsum,
      bcount1, bbase1, cursor1, bcount2, bbase2, cursor2);
  scatter_both<<<188, 256, 0, stream>>>(ind, tokBase, tokCur, tokBucket,
                                        keys1, bbase1, cursor1, bkey, bval);
  esum_rank1<<<ES_BLOCKS + KCB, 256, 0, stream>>>(
      x, tokBase, cntTok, tokBucket, esum,
      bkey, bval, bbase1, bcount1, keys2, bbase2, cursor2, bkey2, bval2, bpos2);
  rank2<<<2048, 64, 0, stream>>>(bkey2, bval2, bpos2, bbase2, bcount2, perm);

  final_embed<<<512, 256, 0, stream>>>(x, cs, cntTok, eavg, esum, expired, nsum,
                                       perm, outEAVG, outNE);
}

// Round 18
// 221.989 us; speedup vs baseline: 1.3136x; 1.0192x over previous
//
#include <hip/hip_runtime.h>
#include <hip/hip_bf16.h>
#include <stdint.h>
#include <math.h>

// Problem constants
#define N_TOK 48000     // 32*1500
#define DIMS  256
#define KCB   2048
// 1-pass bf16 approx score error: diff std ~6e-3, max over 1e8 pairs ~0.037.
// Packed-u32: score+32 (all in (0,64)), truncate low 11 bits -> quant error
// <= 64*2^-12 = 0.0156/side. WND = 0.10 >= 0.037 + 2*0.0156 with margin.
// True winner's packed score >= best - WND. Candidates = per-tile top-2; if a
// tile's THIRD value is in-window the winner may be unstored -> full re-scan.
#define WND 0.10f
#define BIAS 32.0f

typedef __attribute__((ext_vector_type(8))) short bf16x8;
typedef __attribute__((ext_vector_type(4))) float f32x4;
typedef __attribute__((ext_vector_type(8))) unsigned short u16x8;

// ---------------- bf16 helpers (explicit RNE) ----------------
__device__ __forceinline__ unsigned short bf16rn(float f) {
  uint32_t u = __float_as_uint(f);
  uint32_t r = (u + 0x7FFFu + ((u >> 16) & 1u)) >> 16;
  return (unsigned short)r;
}
__device__ __forceinline__ float bf16f(unsigned short h) {
  return __uint_as_float(((uint32_t)h) << 16);
}

// ---------------- 3-input u32 ALU (single VOP3 each on gfx950) ----------------
__device__ __forceinline__ uint32_t max3u(uint32_t a, uint32_t b, uint32_t c) {
  uint32_t d; asm("v_max3_u32 %0, %1, %2, %3" : "=v"(d) : "v"(a), "v"(b), "v"(c));
  return d;
}
__device__ __forceinline__ uint32_t med3u(uint32_t a, uint32_t b, uint32_t c) {
  uint32_t d; asm("v_med3_u32 %0, %1, %2, %3" : "=v"(d) : "v"(a), "v"(b), "v"(c));
  return d;
}
__device__ __forceinline__ uint32_t min3u(uint32_t a, uint32_t b, uint32_t c) {
  uint32_t d; asm("v_min3_u32 %0, %1, %2, %3" : "=v"(d) : "v"(a), "v"(b), "v"(c));
  return d;
}

// ---------------- packed sortable score ----------------
__device__ __forceinline__ uint32_t packBiased(float fb, uint32_t invIdx) {
  float c = fmaxf(fb, 0.0f);
  return (__float_as_uint(c) & ~0x7FFu) | invIdx;
}
__device__ __forceinline__ uint32_t packThrBiased(float fb) {
  float c = fmaxf(fb, 0.0f);
  return __float_as_uint(c) & ~0x7FFu;
}
__device__ __forceinline__ float unpackBiased(uint32_t u) {   // returns score+BIAS
  return __uint_as_float(u & ~0x7FFu);
}
// sorted top-3 insert (b>=s>=t): 4 ops via med3/min3
__device__ __forceinline__ void ins3u(uint32_t& b, uint32_t& s, uint32_t& t, uint32_t v) {
  uint32_t b0 = b;
  b = max(b, v);
  t = max(t, min3u(b0, s, v));
  s = med3u(b0, s, v);
}

// ---------------- Threefry-2x32 (matches jax._src.prng, partitionable) ----------------
__device__ inline void tf2x32(uint32_t k0, uint32_t k1, uint32_t c0, uint32_t c1,
                              uint32_t& o0, uint32_t& o1) {
  uint32_t ks2 = k0 ^ k1 ^ 0x1BD11BDAu;
  uint32_t x0 = c0 + k0, x1 = c1 + k1;
#define TF_R(r) { x0 += x1; x1 = (x1 << (r)) | (x1 >> (32 - (r))); x1 ^= x0; }
  TF_R(13) TF_R(15) TF_R(26) TF_R(6)
  x0 += k1; x1 += ks2 + 1u;
  TF_R(17) TF_R(29) TF_R(16) TF_R(24)
  x0 += ks2; x1 += k0 + 2u;
  TF_R(13) TF_R(15) TF_R(26) TF_R(6)
  x0 += k0; x1 += k1 + 3u;
  TF_R(17) TF_R(29) TF_R(16) TF_R(24)
  x0 += k1; x1 += ks2 + 4u;
  TF_R(13) TF_R(15) TF_R(26) TF_R(6)
  x0 += ks2; x1 += k0 + 5u;
#undef TF_R
  o0 = x0; o1 = x1;
}

__device__ inline void get_round_key(int round, uint32_t& ka, uint32_t& kb) {
  const uint32_t b0 = 0u, b1 = 1u;  // jax.random.key(1) -> (0,1)
  uint32_t K1a, K1b, S1a, S1b;
  tf2x32(b0, b1, 0u, 0u, K1a, K1b);
  tf2x32(b0, b1, 0u, 1u, S1a, S1b);
  if (round == 1) { ka = S1a; kb = S1b; return; }
  uint32_t S2a, S2b;
  tf2x32(K1a, K1b, 0u, 1u, S2a, S2b);
  ka = S2a; kb = S2b;
}

__device__ inline uint32_t gen_key(int round, uint32_t i) {
  uint32_t ka, kb, o0, o1;
  get_round_key(round, ka, kb);
  tf2x32(ka, kb, 0u, i, o0, o1);
  return o0 ^ o1;
}

// ---------------- global_load_lds wrapper (16B) ----------------
__device__ __forceinline__ void gload_lds16(const void* g, void* l) {
  __builtin_amdgcn_global_load_lds(
      (const __attribute__((address_space(1))) uint32_t*)g,
      (__attribute__((address_space(3))) uint32_t*)l, 16, 0, 0);
}

// ---------------- fused: bf16 split + e2 terms + keys + counter zeroing ----------------
// e2f[k] = BIAS - e2[k]. Also zeroes cntAB|cntTok|bcount1|bcount2 (contiguous,
// 6208 u32) -- safe: first touched by merge8 (key histograms moved there).
#define NZERO 6208
__global__ void e2split_keys(const float* __restrict__ x, unsigned short* __restrict__ xh,
                             const float* __restrict__ embed, unsigned short* __restrict__ eh,
                             float* __restrict__ e2f, double* __restrict__ e2d,
                             uint32_t* __restrict__ keys1, uint32_t* __restrict__ keys2,
                             uint32_t* __restrict__ zeroBase) {
  const int nx = N_TOK * DIMS / 8;
  const int ne = KCB * DIMS / 8;
  int i = blockIdx.x * blockDim.x + threadIdx.x;
  if (i < nx + ne) {
    const float* src; unsigned short* dst; int j;
    if (i < nx) { src = x; dst = xh; j = i; }
    else { src = embed; dst = eh; j = i - nx; }
    float4 a = ((const float4*)src)[j * 2];
    float4 b = ((const float4*)src)[j * 2 + 1];
    float v[8] = {a.x, a.y, a.z, a.w, b.x, b.y, b.z, b.w};
    u16x8 h;
#pragma unroll
    for (int q = 0; q < 8; ++q) h[q] = bf16rn(v[q]);
    *(u16x8*)&dst[(size_t)j * 8] = h;
    return;
  }
  int k = i - (nx + ne);
  if (k < KCB) {
    const float4* er = (const float4*)(embed + (size_t)k * DIMS);
    float s = 0.f;
    double sd = 0.0;
    for (int c = 0; c < DIMS / 4; ++c) {
      float4 v = er[c];
      s = fmaf(v.x, v.x, s); s = fmaf(v.y, v.y, s);
      s = fmaf(v.z, v.z, s); s = fmaf(v.w, v.w, s);
      sd += (double)v.x * v.x + (double)v.y * v.y
          + (double)v.z * v.z + (double)v.w * v.w;
    }
    e2f[k] = BIAS - s;
    e2d[k] = sd;
    return;
  }
  int n = k - KCB;
  if (n < N_TOK) {
    keys1[n] = gen_key(1, (uint32_t)n);
    keys2[n] = gen_key(2, (uint32_t)n);
    return;
  }
  int z = n - N_TOK;
  if (z < NZERO) zeroBase[z] = 0u;
}

// ---------------- MFMA distance top-3 (single bf16 pass, packed epilogue) ----------------
// approx score+BIAS = 2*(xh.eh) + e2f[k]; 128x256 tile, BK=32, 8 steps,
// double-buffered LDS. Bank swizzle (both-sides involution): chunk ^= (row>>1)&3.
// NOTE: launch_bounds (256,2) -- forcing 3 blocks/CU (r14) capped VGPR at 84
// and spilled acc to scratch (WRITE_SIZE 4.5->106 MB, 79->112 us).
__global__ __launch_bounds__(256, 2) void dist_mfma(
    const unsigned short* __restrict__ xh, const unsigned short* __restrict__ eh,
    const float* __restrict__ e2f,
    uint32_t* __restrict__ pb, uint32_t* __restrict__ ps, uint32_t* __restrict__ pt)
{
  // staging (49152 B) and reduction table (128*100*4 = 51200 B) alias
  __shared__ __align__(16) char smem[51200];
  short (*As)[128 * 32] = (short(*)[128 * 32])smem;            // 2 x 8 KB
  short (*Bs)[256 * 32] = (short(*)[256 * 32])(smem + 16384);  // 2 x 16 KB
  uint32_t* red = (uint32_t*)smem;                             // [128][100] u32

  const int tid = threadIdx.x;
  const int lane = tid & 63, w = tid >> 6;
  const int wr = w >> 1, wc = w & 1;      // wave tile: 64 rows x 128 cols
  const int l15 = lane & 15, lg = lane >> 4;

  // XCD grouping: the 8 y-tiles sharing an x-tile get bids == same (mod 8),
  // spaced 8 apart -> same XCD L2 -> x-tile fetched from HBM once per XCD.
  int bx, by;
  {
    const int bid = blockIdx.x;
    if (bid < 2944) { int g = bid >> 6, r = bid & 63; bx = g * 8 + (r & 7); by = r >> 3; }
    else            { int t2 = bid - 2944; bx = 368 + (t2 % 7); by = t2 / 7; }
  }
  const int n0 = bx * 128;   // token tile base
  const int c0 = by * 256;   // code tile base

  f32x4 acc[4][8];
#pragma unroll
  for (int mf = 0; mf < 4; ++mf)
#pragma unroll
    for (int nf = 0; nf < 8; ++nf) acc[mf][nf] = (f32x4){0.f, 0.f, 0.f, 0.f};

  // stage step t into buffer t&1 (linear LDS dest; source pre-swizzled)
  auto stage = [&](int t) {
    const int d0 = t << 5;     // d-chunk of 32 shorts
    const int q = t & 1;
#pragma unroll
    for (int i = 0; i < 2; ++i) {
      const int c = i * 256 + tid;
      const int row = c >> 2;
      const int sc = ((c & 3) ^ ((row >> 1) & 3)) << 3;   // swizzled source chunk
      gload_lds16(xh + (size_t)(n0 + row) * DIMS + d0 + sc, (void*)&As[q][c * 8]);
    }
#pragma unroll
    for (int i = 0; i < 4; ++i) {
      const int c = i * 256 + tid;
      const int row = c >> 2;
      const int sc = ((c & 3) ^ ((row >> 1) & 3)) << 3;
      gload_lds16(eh + (size_t)(c0 + row) * DIMS + d0 + sc, (void*)&Bs[q][c * 8]);
    }
  };

  stage(0);
  __syncthreads();   // buf0 ready

#pragma unroll 1
  for (int t = 0; t < 8; ++t) {
    if (t < 7) stage(t + 1);         // issue next-step loads (overlap w/ compute)
    const int q = t & 1;
    bf16x8 af[4], bfv[8];
#pragma unroll
    for (int mf = 0; mf < 4; ++mf) {
      const int r = wr * 64 + mf * 16 + l15;
      af[mf] = *(const bf16x8*)&As[q][r * 32 + ((lg ^ ((r >> 1) & 3)) << 3)];
    }
#pragma unroll
    for (int nf = 0; nf < 8; ++nf) {
      const int r = wc * 128 + nf * 16 + l15;
      bfv[nf] = *(const bf16x8*)&Bs[q][r * 32 + ((lg ^ ((r >> 1) & 3)) << 3)];
    }
#pragma unroll
    for (int mf = 0; mf < 4; ++mf)
#pragma unroll
      for (int nf = 0; nf < 8; ++nf)
        acc[mf][nf] = __builtin_amdgcn_mfma_f32_16x16x32_bf16(
            af[mf], bfv[nf], acc[mf][nf], 0, 0, 0);
    __syncthreads();                 // staged loads drained + rw hazards
  }
  // K-loop done; last barrier above makes staging LDS safe to reuse as `red`.

  float e2v[8];
  uint32_t inv[8];
#pragma unroll
  for (int nf = 0; nf < 8; ++nf) {
    int k = c0 + wc * 128 + nf * 16 + l15;
    e2v[nf] = e2f[k];
    inv[nf] = 2047u - (uint32_t)k;
  }

  const int colbase = wc * 16 + l15;
#pragma unroll
  for (int mf = 0; mf < 4; ++mf) {
#pragma unroll
    for (int reg = 0; reg < 4; ++reg) {
      uint32_t p0 = packBiased(fmaf(2.f, acc[mf][0][reg], e2v[0]), inv[0]);
      uint32_t p1 = packBiased(fmaf(2.f, acc[mf][1][reg], e2v[1]), inv[1]);
      uint32_t p2 = packBiased(fmaf(2.f, acc[mf][2][reg], e2v[2]), inv[2]);
      // sort3 init via 3-input ops (3 VALU, exact)
      uint32_t b  = max3u(p0, p1, p2);
      uint32_t s  = med3u(p0, p1, p2);
      uint32_t t3 = min3u(p0, p1, p2);
#pragma unroll
      for (int nf = 3; nf < 8; ++nf) {
        float f = fmaf(2.f, acc[mf][nf][reg], e2v[nf]);
        ins3u(b, s, t3, packBiased(f, inv[nf]));
      }
      const int row = wr * 64 + mf * 16 + lg * 4 + reg;
      uint32_t* p = &red[row * 100 + colbase * 3];
      p[0] = b; p[1] = s; p[2] = t3;
    }
  }
  __syncthreads();
  {
    const int row = tid >> 1, half = tid & 1;
    uint32_t b = 0u, s = 0u, t3 = 0u;
    const uint4* p4 = (const uint4*)&red[row * 100 + half * 48];   // 16B-aligned
#pragma unroll
    for (int c = 0; c < 12; ++c) {
      uint4 v = p4[c];
      ins3u(b, s, t3, v.x); ins3u(b, s, t3, v.y);
      ins3u(b, s, t3, v.z); ins3u(b, s, t3, v.w);
    }
    if (half) {
      uint32_t* q = &red[row * 100 + 96];
      q[0] = b; q[1] = s; q[2] = t3;
    }
    __syncthreads();
    if (!half) {
      const uint32_t* q = &red[row * 100 + 96];
      ins3u(b, s, t3, q[0]);
      ins3u(b, s, t3, q[1]);
      ins3u(b, s, t3, q[2]);
      size_t o = (size_t)by * N_TOK + n0 + row;
      pb[o] = b; ps[o] = s; pt[o] = t3;
    }
  }
}

// ---------------- merge 8 partials + candidates + final-row stats + key hists ----------------
__global__ void merge8(const uint32_t* __restrict__ pb, const uint32_t* __restrict__ ps,
                       const uint32_t* __restrict__ pt,
                       int* __restrict__ ind,
                       int* __restrict__ candRows, int* __restrict__ candIdx,
                       int* __restrict__ candCnt, int* __restrict__ listC,
                       uint32_t* __restrict__ cntA, uint32_t* __restrict__ cntC,
                       float* __restrict__ outcodes, uint32_t* __restrict__ cntTok,
                       const uint32_t* __restrict__ keys1, const uint32_t* __restrict__ keys2,
                       uint32_t* __restrict__ bcount1, uint32_t* __restrict__ bcount2) {
  int n = blockIdx.x * blockDim.x + threadIdx.x;
  if (n >= N_TOK) return;
  // permutation key histograms (moved here so e2split can zero the counters)
  atomicAdd(&bcount1[keys1[n] >> 21], 1u);
  atomicAdd(&bcount2[keys2[n] >> 21], 1u);
  uint32_t tb[8], tsv[8], ttv[8];
#pragma unroll
  for (int tt = 0; tt < 8; ++tt) {
    size_t o = (size_t)tt * N_TOK + n;
    tb[tt] = pb[o]; tsv[tt] = ps[o]; ttv[tt] = pt[o];
  }
  uint32_t best = tb[0];
#pragma unroll
  for (int tt = 1; tt < 8; ++tt) best = max(best, tb[tt]);
  int kb = 2047 - (int)(best & 0x7FFu);
  ind[n] = kb;   // provisional winner (final unless refined below)
  const uint32_t thr = packThrBiased(unpackBiased(best) - WND);
  int m = 0; bool full = false;
#pragma unroll
  for (int tt = 0; tt < 8; ++tt) {
    m += (tb[tt] >= thr) + (tsv[tt] >= thr);
    full = full || (ttv[tt] >= thr);   // a tile's unstored 3rd+ could be in-window
  }
  if (full) {
    listC[atomicAdd(cntC, 1u)] = n;
  } else if (m > 1) {
    uint32_t i = atomicAdd(cntA, 1u);
    candRows[i] = n; candCnt[i] = m;
    int j = 0;
#pragma unroll
    for (int tt = 0; tt < 8; ++tt) {
      if (tb[tt]  >= thr) candIdx[(size_t)i * 16 + (j++)] = 2047 - (int)(tb[tt]  & 0x7FFu);
      if (tsv[tt] >= thr) candIdx[(size_t)i * 16 + (j++)] = 2047 - (int)(tsv[tt] & 0x7FFu);
    }
  } else {
    // row is final here: codes + histogram
    outcodes[n] = (float)kb;
    atomicAdd(&cntTok[kb], 1u);
  }
}

// ---------------- fused refine: blocks [0,512) candidate path, [512,1536) full scan ----------------
#define RC_BLOCKS 512
#define RF_BLOCKS 1024
__global__ void refine_both(const float* __restrict__ x, const float* __restrict__ embed,
                            const double* __restrict__ e2d,
                            const int* __restrict__ candRows, const int* __restrict__ candIdx,
                            const int* __restrict__ candCnt,
                            const int* __restrict__ listC,
                            const uint32_t* __restrict__ cntAB,
                            int* __restrict__ ind,
                            float* __restrict__ outcodes, uint32_t* __restrict__ cntTok) {
  __shared__ double xd[DIMS];
  __shared__ double rv[256];
  __shared__ int    rk[256];
  const int tid = threadIdx.x;
  if (blockIdx.x < RC_BLOCKS) {
    // ---- wave-per-row f64 candidate decider ----
    const uint32_t nA = cntAB[0];
    const int lane = tid & 63;
    const uint32_t wid = ((uint32_t)blockIdx.x * 256 + tid) >> 6;
    const uint32_t nw = RC_BLOCKS * 4;
    for (uint32_t i = wid; i < nA; i += nw) {
      const int n = candRows[i];
      const int m = candCnt[i];
      float4 xv = ((const float4*)x)[(size_t)n * 64 + lane];
      double best = -1e300; int bk = 0x7fffffff;
      for (int j = 0; j < m; ++j) {
        int k = candIdx[(size_t)i * 16 + j];
        float4 e4 = ((const float4*)embed)[(size_t)k * 64 + lane];
        double d = (double)xv.x * e4.x + (double)xv.y * e4.y
                 + (double)xv.z * e4.z + (double)xv.w * e4.w;
#pragma unroll
        for (int mm = 1; mm < 64; mm <<= 1) d += __shfl_xor(d, mm);
        double v = 2.0 * d - e2d[k];
        if (v > best || (v == best && k < bk)) { best = v; bk = k; }
      }
      if (lane == 0) {
        ind[n] = bk;
        outcodes[n] = (float)bk;
        atomicAdd(&cntTok[bk], 1u);
      }
    }
    return;
  }
  // ---- full f64 re-scan, one row per block (rare) ----
  const uint32_t nC = cntAB[1];
  for (uint32_t it = blockIdx.x - RC_BLOCKS; it < nC; it += RF_BLOCKS) {
    const int n = listC[it];
    __syncthreads();
    xd[tid] = (double)x[(size_t)n * DIMS + tid];
    __syncthreads();
    double best = -1e300; int bk = 0x7fffffff;
    for (int k = tid; k < KCB; k += 256) {
      const float4* er = (const float4*)(embed + (size_t)k * DIMS);
      double a0 = 0.0, a1 = 0.0, a2 = 0.0, a3 = 0.0;   // ILP-4 chains
      for (int c = 0; c < 64; c += 4) {
        float4 ea = er[c], eb = er[c + 1], ec = er[c + 2], ed = er[c + 3];
        int d = c * 4;
        a0 += xd[d + 0] * ea.x + xd[d + 1] * ea.y + xd[d + 2] * ea.z + xd[d + 3] * ea.w;
        a1 += xd[d + 4] * eb.x + xd[d + 5] * eb.y + xd[d + 6] * eb.z + xd[d + 7] * eb.w;
        a2 += xd[d + 8] * ec.x + xd[d + 9] * ec.y + xd[d + 10] * ec.z + xd[d + 11] * ec.w;
        a3 += xd[d + 12] * ed.x + xd[d + 13] * ed.y + xd[d + 14] * ed.z + xd[d + 15] * ed.w;
      }
      double v = 2.0 * (a0 + a1 + a2 + a3) - e2d[k];
      if (v > best || (v == best && k < bk)) { best = v; bk = k; }
    }
    rv[tid] = best; rk[tid] = bk;
    __syncthreads();
    for (int s = 128; s > 0; s >>= 1) {
      if (tid < s) {
        double v2 = rv[tid + s]; int k2 = rk[tid + s];
        if (v2 > rv[tid] || (v2 == rv[tid] && k2 < rk[tid])) { rv[tid] = v2; rk[tid] = k2; }
      }
      __syncthreads();
    }
    if (tid == 0) {
      ind[n] = rk[0];
      outcodes[n] = (float)rk[0];
      atomicAdd(&cntTok[rk[0]], 1u);
    }
  }
}

// ---------------- fused: blocks 0-2 = three 2048-scans (+EMA), rest = outQ gather ----------------
__global__ void gather_scan(const float* __restrict__ embed, const int* __restrict__ ind,
                            float* __restrict__ outq,
                            const uint32_t* __restrict__ cntTok, uint32_t* __restrict__ tokBase,
                            uint32_t* __restrict__ tokCur,
                            const float* __restrict__ cs, float* __restrict__ out_ncs,
                            int* __restrict__ expired, double* __restrict__ nsum,
                            const uint32_t* __restrict__ bcount1, uint32_t* __restrict__ bbase1,
                            uint32_t* __restrict__ cursor1,
                            const uint32_t* __restrict__ bcount2, uint32_t* __restrict__ bbase2,
                            uint32_t* __restrict__ cursor2) {
  __shared__ uint32_t buf[2][2048];
  __shared__ double sd[1024];
  const int t = threadIdx.x;   // 1024
  if (blockIdx.x >= 3) {
    // pure gather over N_TOK*64 float4s
    int idx = (blockIdx.x - 3) * 1024 + t;
    if (idx < N_TOK * 64) {
      int n = idx >> 6, c = idx & 63;
      ((float4*)outq)[idx] = ((const float4*)embed)[(size_t)ind[n] * 64 + c];
    }
    return;
  }
  const uint32_t* in; uint32_t* out; uint32_t* cz;
  if (blockIdx.x == 0)      { in = cntTok;  out = tokBase; cz = tokCur;  }
  else if (blockIdx.x == 1) { in = bcount1; out = bbase1;  cz = cursor1; }
  else                      { in = bcount2; out = bbase2;  cz = cursor2; }
  double local = 0.0;
  for (int q = 0; q < 2; ++q) {
    int i = t + q * 1024;
    uint32_t c = in[i];
    buf[0][i] = c;
    cz[i] = 0;
    if (blockIdx.x == 0) {
      double v = 0.99 * (double)cs[i] + 0.01 * (double)c;
      out_ncs[i] = (float)v;
      expired[i] = (v < 2.0) ? 1 : 0;
      local += v;
    }
  }
  if (blockIdx.x == 0) sd[t] = local;
  __syncthreads();
  int src = 0;
  for (int off = 1; off < 2048; off <<= 1) {
    for (int q = 0; q < 2; ++q) {
      int i = t + q * 1024;
      uint32_t v = buf[src][i];
      if (i >= off) v += buf[src][i - off];
      buf[src ^ 1][i] = v;
    }
    src ^= 1; __syncthreads();
  }
  for (int q = 0; q < 2; ++q) {
    int i = t + q * 1024;
    out[i] = buf[src][i] - in[i];   // exclusive
  }
  if (blockIdx.x == 0) {
    for (int s = 512; s > 0; s >>= 1) { if (t < s) sd[t] += sd[t + s]; __syncthreads(); }
    if (t == 0) nsum[0] = sd[0];
  }
}

// ---------------- fused scatter: token buckets + round-1 key buckets ----------------
__global__ void scatter_both(const int* __restrict__ ind, const uint32_t* __restrict__ tokBase,
                             uint32_t* __restrict__ tokCur, uint32_t* __restrict__ tokBucket,
                             const uint32_t* __restrict__ keys1, const uint32_t* __restrict__ bbase1,
                             uint32_t* __restrict__ cursor1,
                             uint32_t* __restrict__ bkey, uint32_t* __restrict__ bval) {
  int n = blockIdx.x * blockDim.x + threadIdx.x;
  if (n >= N_TOK) return;
  int k = ind[n];
  uint32_t p = atomicAdd(&tokCur[k], 1u);
  tokBucket[tokBase[k] + p] = (uint32_t)n;
  uint32_t k1 = keys1[n];
  uint32_t b = k1 >> 21;
  uint32_t q = atomicAdd(&cursor1[b], 1u);
  uint32_t s = bbase1[b] + q;
  bkey[s] = k1; bval[s] = (uint32_t)n;   // value == tie-break position for round 1
}

// ---------------- fused: blocks [0,512) esum segment-sum (bf16 src), rest rank1+scatter2 ----------------
#define ES_BLOCKS 512
__global__ void esum_rank1(const unsigned short* __restrict__ xh, const uint32_t* __restrict__ tokBase,
                           const uint32_t* __restrict__ cntTok,
                           const uint32_t* __restrict__ tokBucket,
                           float* __restrict__ esum,
                           const uint32_t* __restrict__ bkey, const uint32_t* __restrict__ bval,
                           const uint32_t* __restrict__ bbase1, const uint32_t* __restrict__ bcount1,
                           const uint32_t* __restrict__ keys2,
                           const uint32_t* __restrict__ bbase2, uint32_t* __restrict__ cursor2,
                           uint32_t* __restrict__ bkey2, uint32_t* __restrict__ bval2,
                           uint32_t* __restrict__ bpos2) {
  const int tid = threadIdx.x;
  if (blockIdx.x < ES_BLOCKS) {
    // esum[k] = sum of x rows (bf16-rounded: err ~2e-4 on eavg, thr >= 3.9e-3)
    const uint32_t wv = ((uint32_t)blockIdx.x * 256 + tid) >> 6;
    const int lane = tid & 63;
    const uint32_t base = tokBase[wv], cnt = cntTok[wv];
    float4 a0 = {0.f, 0.f, 0.f, 0.f}, a1 = {0.f, 0.f, 0.f, 0.f};
    uint32_t i = 0;
    for (; i + 2 <= cnt; i += 2) {
      uint32_t n0 = tokBucket[base + i], n1 = tokBucket[base + i + 1];
      ushort4 h0 = ((const ushort4*)xh)[(size_t)n0 * 64 + lane];
      ushort4 h1 = ((const ushort4*)xh)[(size_t)n1 * 64 + lane];
      a0.x += bf16f(h0.x); a0.y += bf16f(h0.y); a0.z += bf16f(h0.z); a0.w += bf16f(h0.w);
      a1.x += bf16f(h1.x); a1.y += bf16f(h1.y); a1.z += bf16f(h1.z); a1.w += bf16f(h1.w);
    }
    if (i < cnt) {
      uint32_t n0 = tokBucket[base + i];
      ushort4 h0 = ((const ushort4*)xh)[(size_t)n0 * 64 + lane];
      a0.x += bf16f(h0.x); a0.y += bf16f(h0.y); a0.z += bf16f(h0.z); a0.w += bf16f(h0.w);
    }
    float4 r; r.x = a0.x + a1.x; r.y = a0.y + a1.y; r.z = a0.z + a1.z; r.w = a0.w + a1.w;
    ((float4*)esum)[(size_t)wv * 64 + lane] = r;
    return;
  }
  // rank round-1 elements (stable by (key,pos)) and scatter into round-2 buckets
  int b = blockIdx.x - ES_BLOCKS;   // [0, 2048)
  uint32_t base = bbase1[b], cnt = bcount1[b];
  for (uint32_t t = tid; t < cnt; t += 256) {
    uint32_t k = bkey[base + t], pv = bval[base + t];
    uint32_t r = 0;
    for (uint32_t j = 0; j < cnt; ++j) {
      uint32_t kj = bkey[base + j], pj = bval[base + j];
      r += (kj < k) | ((kj == k) & (pj < pv));
    }
    uint32_t p = base + r;          // global round-1 sorted position
    uint32_t k2 = keys2[p];
    uint32_t b2 = k2 >> 21;
    uint32_t q = atomicAdd(&cursor2[b2], 1u);
    uint32_t s = bbase2[b2] + q;
    bkey2[s] = k2; bval2[s] = pv; bpos2[s] = p;
  }
}

// ---------------- round-2 rank; expired rows written directly to out_ne ----------------
__global__ void rank2(const uint32_t* __restrict__ bkey2, const uint32_t* __restrict__ bval2,
                      const uint32_t* __restrict__ bpos2,
                      const uint32_t* __restrict__ bbase2, const uint32_t* __restrict__ bcount2,
                      const int* __restrict__ expired, const float* __restrict__ x,
                      float* __restrict__ out_ne) {
  int b = blockIdx.x;
  uint32_t base = bbase2[b];
  if (base >= KCB) return;          // every element lands at position >= 2048
  uint32_t cnt = bcount2[b];
  for (uint32_t t = threadIdx.x; t < cnt; t += blockDim.x) {
    uint32_t k = bkey2[base + t], p = bpos2[base + t];
    uint32_t r = 0;
    for (uint32_t j = 0; j < cnt; ++j) {
      uint32_t kj = bkey2[base + j], pj = bpos2[base + j];
      r += (kj < k) | ((kj == k) & (pj < p));
    }
    uint32_t pos = base + r;
    if (pos < KCB && expired[pos]) {
      uint32_t val = bval2[base + t];         // perm[pos] = token id
      const float4* src = (const float4*)x + (size_t)val * 64;
      float4* dst = (float4*)out_ne + (size_t)pos * 64;
      for (int c = 0; c < 64; ++c) dst[c] = src[c];
    }
  }
}

// ---------------- new_embed_avg + new_embed (non-expired; expired by rank2) ----------------
__global__ void final_embed(const float* __restrict__ cs,
                            const uint32_t* __restrict__ cntTok,
                            const float* __restrict__ eavg, const float* __restrict__ esum,
                            const int* __restrict__ expired, const double* __restrict__ nsum,
                            float* __restrict__ out_eavg, float* __restrict__ out_ne) {
  int idx = blockIdx.x * blockDim.x + threadIdx.x;   // over KCB*64 float4s
  if (idx >= KCB * 64) return;
  int k = idx >> 6;
  float4 ea = ((const float4*)eavg)[idx];
  float4 es = ((const float4*)esum)[idx];
  double ax = 0.99 * (double)ea.x + 0.01 * (double)es.x;
  double ay = 0.99 * (double)ea.y + 0.01 * (double)es.y;
  double az = 0.99 * (double)ea.z + 0.01 * (double)es.z;
  double aw = 0.99 * (double)ea.w + 0.01 * (double)es.w;
  float4 nv; nv.x = (float)ax; nv.y = (float)ay; nv.z = (float)az; nv.w = (float)aw;
  ((float4*)out_eavg)[idx] = nv;
  if (!expired[k]) {
    double ncs = 0.99 * (double)cs[k] + 0.01 * (double)cntTok[k];
    double n = nsum[0];
    double sm = (ncs + 1e-5) / (n + 2048.0 * 1e-5) * n;
    float4 r;
    r.x = (float)(ax / sm); r.y = (float)(ay / sm);
    r.z = (float)(az / sm); r.w = (float)(aw / sm);
    ((float4*)out_ne)[idx] = r;
  }
}

// ---------------- launch ----------------
extern "C" void kernel_launch(void* const* d_in, const int* in_sizes, int n_in,
                              void* d_out, int out_size, void* d_ws, size_t ws_size,
                              hipStream_t stream) {
  const float* x     = (const float*)d_in[0];
  const float* embed = (const float*)d_in[1];
  const float* cs    = (const float*)d_in[2];
  const float* eavg  = (const float*)d_in[3];

  float* out = (float*)d_out;
  float* outQ    = out;                  // 12,288,000
  float* outC    = out + 12288000;       // 48,000
  float* outNCS  = out + 12336000;       // 2,048
  float* outEAVG = out + 12338048;       // 524,288
  float* outNE   = out + 12862336;       // 524,288

  char* w = (char*)d_ws;
  size_t off = 0;
  auto alloc = [&](size_t bytes) -> void* {
    void* p = w + off; off += (bytes + 255) & ~(size_t)255; return p;
  };
  unsigned short* xh = (unsigned short*)alloc((size_t)N_TOK * DIMS * 2);
  unsigned short* eh = (unsigned short*)alloc((size_t)KCB * DIMS * 2);
  float*    e2f     = (float*)alloc(KCB * 4);
  double*   e2d     = (double*)alloc(KCB * 8);
  float*    esum    = (float*)alloc((size_t)KCB * DIMS * 4);
  uint32_t* pbest   = (uint32_t*)alloc((size_t)8 * N_TOK * 4);
  uint32_t* psecond = (uint32_t*)alloc((size_t)8 * N_TOK * 4);
  uint32_t* pthird  = (uint32_t*)alloc((size_t)8 * N_TOK * 4);
  int*      ind     = (int*)alloc(N_TOK * 4);
  int*      candRows= (int*)alloc(N_TOK * 4);
  int*      candCnt = (int*)alloc(N_TOK * 4);
  int*      candIdx = (int*)alloc((size_t)N_TOK * 16 * 4);
  int*      listC   = (int*)alloc(N_TOK * 4);
  double*   nsum    = (double*)alloc(256);
  int*      expired = (int*)alloc(KCB * 4);
  uint32_t* tokBase = (uint32_t*)alloc(KCB * 4);
  uint32_t* tokCur  = (uint32_t*)alloc(KCB * 4);
  uint32_t* tokBucket = (uint32_t*)alloc(N_TOK * 4);
  uint32_t* keys1   = (uint32_t*)alloc(N_TOK * 4);
  uint32_t* keys2   = (uint32_t*)alloc(N_TOK * 4);
  uint32_t* bkey    = (uint32_t*)alloc(N_TOK * 4);
  uint32_t* bval    = (uint32_t*)alloc(N_TOK * 4);
  uint32_t* bkey2   = (uint32_t*)alloc(N_TOK * 4);
  uint32_t* bval2   = (uint32_t*)alloc(N_TOK * 4);
  uint32_t* bpos2   = (uint32_t*)alloc(N_TOK * 4);
  uint32_t* bbase1  = (uint32_t*)alloc(KCB * 4);
  uint32_t* bbase2  = (uint32_t*)alloc(KCB * 4);
  uint32_t* cursor1 = (uint32_t*)alloc(KCB * 4);
  uint32_t* cursor2 = (uint32_t*)alloc(KCB * 4);
  // contiguous zero region: cntAB(256B=64 u32) | cntTok | bcount1 | bcount2 = 6208 u32
  uint32_t* cntAB   = (uint32_t*)alloc(256);
  uint32_t* cntTok  = (uint32_t*)alloc(KCB * 4);
  uint32_t* bcount1 = (uint32_t*)alloc(KCB * 4);
  uint32_t* bcount2 = (uint32_t*)alloc(KCB * 4);

  // split + e2 + permutation keys + counter zeroing (one kernel, no memset)
  e2split_keys<<<(N_TOK * DIMS / 8 + KCB * DIMS / 8 + KCB + N_TOK + NZERO + 255) / 256,
                 256, 0, stream>>>(x, xh, embed, eh, e2f, e2d, keys1, keys2, cntAB);

  dist_mfma<<<3000, 256, 0, stream>>>(xh, eh, e2f, pbest, psecond, pthird);
  merge8<<<188, 256, 0, stream>>>(pbest, psecond, pthird,
                                  ind, candRows, candIdx, candCnt, listC,
                                  &cntAB[0], &cntAB[1], outC, cntTok,
                                  keys1, keys2, bcount1, bcount2);
  refine_both<<<RC_BLOCKS + RF_BLOCKS, 256, 0, stream>>>(
      x, embed, e2d, candRows, candIdx, candCnt, listC, cntAB, ind, outC, cntTok);

  // blocks 0-2: scans (token + both key rounds) + EMA; blocks 3+: outQ gather
  gather_scan<<<3 + (N_TOK * 64 + 1023) / 1024, 1024, 0, stream>>>(
      embed, ind, outQ,
      cntTok, tokBase, tokCur, cs, outNCS, expired, nsum,
      bcount1, bbase1, cursor1, bcount2, bbase2, cursor2);
  scatter_both<<<188, 256, 0, stream>>>(ind, tokBase, tokCur, tokBucket,
                                        keys1, bbase1, cursor1, bkey, bval);
  esum_rank1<<<ES_BLOCKS + KCB, 256, 0, stream>>>(
      xh, tokBase, cntTok, tokBucket, esum,
      bkey, bval, bbase1, bcount1, keys2, bbase2, cursor2, bkey2, bval2, bpos2);
  rank2<<<2048, 64, 0, stream>>>(bkey2, bval2, bpos2, bbase2, bcount2,
                                 expired, x, outNE);

  final_embed<<<512, 256, 0, stream>>>(cs, cntTok, eavg, esum, expired, nsum,
                                       outEAVG, outNE);
}

// Round 19
// 219.677 us; speedup vs baseline: 1.3274x; 1.0105x over previous
//
#include <hip/hip_runtime.h>
#include <hip/hip_bf16.h>
#include <stdint.h>
#include <math.h>

// Problem constants
#define N_TOK 48000     // 32*1500
#define DIMS  256
#define KCB   2048
// 1-pass bf16 approx score error: diff std ~6e-3, max over 1e8 pairs ~0.037.
// Packed-u32: score+32 (all in (0,64)), truncate low 11 bits -> quant error
// <= 64*2^-12 = 0.0156/side. WND = 0.10 >= 0.037 + 2*0.0156 with margin.
// True winner's packed score >= best - WND. Candidates = per-tile top-2; if a
// tile's THIRD value is in-window the winner may be unstored -> full re-scan.
#define WND 0.10f
#define BIAS 32.0f

typedef __attribute__((ext_vector_type(8))) short bf16x8;
typedef __attribute__((ext_vector_type(4))) float f32x4;
typedef __attribute__((ext_vector_type(8))) unsigned short u16x8;

// ---------------- bf16 helpers (explicit RNE) ----------------
__device__ __forceinline__ unsigned short bf16rn(float f) {
  uint32_t u = __float_as_uint(f);
  uint32_t r = (u + 0x7FFFu + ((u >> 16) & 1u)) >> 16;
  return (unsigned short)r;
}
__device__ __forceinline__ float bf16f(unsigned short h) {
  return __uint_as_float(((uint32_t)h) << 16);
}

// ---------------- 3-input u32 ALU (single VOP3 each on gfx950) ----------------
__device__ __forceinline__ uint32_t max3u(uint32_t a, uint32_t b, uint32_t c) {
  uint32_t d; asm("v_max3_u32 %0, %1, %2, %3" : "=v"(d) : "v"(a), "v"(b), "v"(c));
  return d;
}
__device__ __forceinline__ uint32_t med3u(uint32_t a, uint32_t b, uint32_t c) {
  uint32_t d; asm("v_med3_u32 %0, %1, %2, %3" : "=v"(d) : "v"(a), "v"(b), "v"(c));
  return d;
}
__device__ __forceinline__ uint32_t min3u(uint32_t a, uint32_t b, uint32_t c) {
  uint32_t d; asm("v_min3_u32 %0, %1, %2, %3" : "=v"(d) : "v"(a), "v"(b), "v"(c));
  return d;
}

// ---------------- packed sortable score ----------------
__device__ __forceinline__ uint32_t packBiased(float fb, uint32_t invIdx) {
  float c = fmaxf(fb, 0.0f);
  return (__float_as_uint(c) & ~0x7FFu) | invIdx;
}
__device__ __forceinline__ uint32_t packThrBiased(float fb) {
  float c = fmaxf(fb, 0.0f);
  return __float_as_uint(c) & ~0x7FFu;
}
__device__ __forceinline__ float unpackBiased(uint32_t u) {   // returns score+BIAS
  return __uint_as_float(u & ~0x7FFu);
}
// sorted top-3 insert (b>=s>=t): 4 ops via med3/min3
__device__ __forceinline__ void ins3u(uint32_t& b, uint32_t& s, uint32_t& t, uint32_t v) {
  uint32_t b0 = b;
  b = max(b, v);
  t = max(t, min3u(b0, s, v));
  s = med3u(b0, s, v);
}

// ---------------- Threefry-2x32 (matches jax._src.prng, partitionable) ----------------
__device__ inline void tf2x32(uint32_t k0, uint32_t k1, uint32_t c0, uint32_t c1,
                              uint32_t& o0, uint32_t& o1) {
  uint32_t ks2 = k0 ^ k1 ^ 0x1BD11BDAu;
  uint32_t x0 = c0 + k0, x1 = c1 + k1;
#define TF_R(r) { x0 += x1; x1 = (x1 << (r)) | (x1 >> (32 - (r))); x1 ^= x0; }
  TF_R(13) TF_R(15) TF_R(26) TF_R(6)
  x0 += k1; x1 += ks2 + 1u;
  TF_R(17) TF_R(29) TF_R(16) TF_R(24)
  x0 += ks2; x1 += k0 + 2u;
  TF_R(13) TF_R(15) TF_R(26) TF_R(6)
  x0 += k0; x1 += k1 + 3u;
  TF_R(17) TF_R(29) TF_R(16) TF_R(24)
  x0 += k1; x1 += ks2 + 4u;
  TF_R(13) TF_R(15) TF_R(26) TF_R(6)
  x0 += ks2; x1 += k0 + 5u;
#undef TF_R
  o0 = x0; o1 = x1;
}

__device__ inline void get_round_key(int round, uint32_t& ka, uint32_t& kb) {
  const uint32_t b0 = 0u, b1 = 1u;  // jax.random.key(1) -> (0,1)
  uint32_t K1a, K1b, S1a, S1b;
  tf2x32(b0, b1, 0u, 0u, K1a, K1b);
  tf2x32(b0, b1, 0u, 1u, S1a, S1b);
  if (round == 1) { ka = S1a; kb = S1b; return; }
  uint32_t S2a, S2b;
  tf2x32(K1a, K1b, 0u, 1u, S2a, S2b);
  ka = S2a; kb = S2b;
}

__device__ inline uint32_t gen_key(int round, uint32_t i) {
  uint32_t ka, kb, o0, o1;
  get_round_key(round, ka, kb);
  tf2x32(ka, kb, 0u, i, o0, o1);
  return o0 ^ o1;
}

// ---------------- global_load_lds wrapper (16B) ----------------
__device__ __forceinline__ void gload_lds16(const void* g, void* l) {
  __builtin_amdgcn_global_load_lds(
      (const __attribute__((address_space(1))) uint32_t*)g,
      (__attribute__((address_space(3))) uint32_t*)l, 16, 0, 0);
}

// ---------------- fused: bf16 split + e2 terms + keys + counter zeroing ----------------
// e2f[k] = BIAS - e2[k]. Also zeroes cntAB|cntTok|bcount1|bcount2 (contiguous,
// 6208 u32) -- safe: first touched by merge8 (key histograms moved there).
#define NZERO 6208
__global__ void e2split_keys(const float* __restrict__ x, unsigned short* __restrict__ xh,
                             const float* __restrict__ embed, unsigned short* __restrict__ eh,
                             float* __restrict__ e2f, double* __restrict__ e2d,
                             uint32_t* __restrict__ keys1, uint32_t* __restrict__ keys2,
                             uint32_t* __restrict__ zeroBase) {
  const int nx = N_TOK * DIMS / 8;
  const int ne = KCB * DIMS / 8;
  int i = blockIdx.x * blockDim.x + threadIdx.x;
  if (i < nx + ne) {
    const float* src; unsigned short* dst; int j;
    if (i < nx) { src = x; dst = xh; j = i; }
    else { src = embed; dst = eh; j = i - nx; }
    float4 a = ((const float4*)src)[j * 2];
    float4 b = ((const float4*)src)[j * 2 + 1];
    float v[8] = {a.x, a.y, a.z, a.w, b.x, b.y, b.z, b.w};
    u16x8 h;
#pragma unroll
    for (int q = 0; q < 8; ++q) h[q] = bf16rn(v[q]);
    *(u16x8*)&dst[(size_t)j * 8] = h;
    return;
  }
  int k = i - (nx + ne);
  if (k < KCB) {
    const float4* er = (const float4*)(embed + (size_t)k * DIMS);
    float s = 0.f;
    double sd = 0.0;
    for (int c = 0; c < DIMS / 4; ++c) {
      float4 v = er[c];
      s = fmaf(v.x, v.x, s); s = fmaf(v.y, v.y, s);
      s = fmaf(v.z, v.z, s); s = fmaf(v.w, v.w, s);
      sd += (double)v.x * v.x + (double)v.y * v.y
          + (double)v.z * v.z + (double)v.w * v.w;
    }
    e2f[k] = BIAS - s;
    e2d[k] = sd;
    return;
  }
  int n = k - KCB;
  if (n < N_TOK) {
    keys1[n] = gen_key(1, (uint32_t)n);
    keys2[n] = gen_key(2, (uint32_t)n);
    return;
  }
  int z = n - N_TOK;
  if (z < NZERO) zeroBase[z] = 0u;
}

// ---------------- MFMA distance top-3 (single bf16 pass, packed epilogue) ----------------
// approx score+BIAS = 2*(xh.eh) + e2f[k]; 128x256 tile, BK=32, 8 steps,
// double-buffered LDS. Bank swizzle (both-sides involution): chunk ^= (row>>1)&3.
// NOTE: launch_bounds (256,2) -- forcing 3 blocks/CU (r14) capped VGPR at 84
// and spilled acc to scratch (WRITE_SIZE 4.5->106 MB, 79->112 us).
__global__ __launch_bounds__(256, 2) void dist_mfma(
    const unsigned short* __restrict__ xh, const unsigned short* __restrict__ eh,
    const float* __restrict__ e2f,
    uint32_t* __restrict__ pb, uint32_t* __restrict__ ps, uint32_t* __restrict__ pt)
{
  // staging (49152 B) and reduction table (128*100*4 = 51200 B) alias
  __shared__ __align__(16) char smem[51200];
  short (*As)[128 * 32] = (short(*)[128 * 32])smem;            // 2 x 8 KB
  short (*Bs)[256 * 32] = (short(*)[256 * 32])(smem + 16384);  // 2 x 16 KB
  uint32_t* red = (uint32_t*)smem;                             // [128][100] u32

  const int tid = threadIdx.x;
  const int lane = tid & 63, w = tid >> 6;
  const int wr = w >> 1, wc = w & 1;      // wave tile: 64 rows x 128 cols
  const int l15 = lane & 15, lg = lane >> 4;

  // XCD grouping: the 8 y-tiles sharing an x-tile get bids == same (mod 8),
  // spaced 8 apart -> same XCD L2 -> x-tile fetched from HBM once per XCD.
  int bx, by;
  {
    const int bid = blockIdx.x;
    if (bid < 2944) { int g = bid >> 6, r = bid & 63; bx = g * 8 + (r & 7); by = r >> 3; }
    else            { int t2 = bid - 2944; bx = 368 + (t2 % 7); by = t2 / 7; }
  }
  const int n0 = bx * 128;   // token tile base
  const int c0 = by * 256;   // code tile base

  f32x4 acc[4][8];
#pragma unroll
  for (int mf = 0; mf < 4; ++mf)
#pragma unroll
    for (int nf = 0; nf < 8; ++nf) acc[mf][nf] = (f32x4){0.f, 0.f, 0.f, 0.f};

  // stage step t into buffer t&1 (linear LDS dest; source pre-swizzled)
  auto stage = [&](int t) {
    const int d0 = t << 5;     // d-chunk of 32 shorts
    const int q = t & 1;
#pragma unroll
    for (int i = 0; i < 2; ++i) {
      const int c = i * 256 + tid;
      const int row = c >> 2;
      const int sc = ((c & 3) ^ ((row >> 1) & 3)) << 3;   // swizzled source chunk
      gload_lds16(xh + (size_t)(n0 + row) * DIMS + d0 + sc, (void*)&As[q][c * 8]);
    }
#pragma unroll
    for (int i = 0; i < 4; ++i) {
      const int c = i * 256 + tid;
      const int row = c >> 2;
      const int sc = ((c & 3) ^ ((row >> 1) & 3)) << 3;
      gload_lds16(eh + (size_t)(c0 + row) * DIMS + d0 + sc, (void*)&Bs[q][c * 8]);
    }
  };

  stage(0);
  __syncthreads();   // buf0 ready

#pragma unroll 1
  for (int t = 0; t < 8; ++t) {
    if (t < 7) stage(t + 1);         // issue next-step loads (overlap w/ compute)
    const int q = t & 1;
    bf16x8 af[4], bfv[8];
#pragma unroll
    for (int mf = 0; mf < 4; ++mf) {
      const int r = wr * 64 + mf * 16 + l15;
      af[mf] = *(const bf16x8*)&As[q][r * 32 + ((lg ^ ((r >> 1) & 3)) << 3)];
    }
#pragma unroll
    for (int nf = 0; nf < 8; ++nf) {
      const int r = wc * 128 + nf * 16 + l15;
      bfv[nf] = *(const bf16x8*)&Bs[q][r * 32 + ((lg ^ ((r >> 1) & 3)) << 3)];
    }
#pragma unroll
    for (int mf = 0; mf < 4; ++mf)
#pragma unroll
      for (int nf = 0; nf < 8; ++nf)
        acc[mf][nf] = __builtin_amdgcn_mfma_f32_16x16x32_bf16(
            af[mf], bfv[nf], acc[mf][nf], 0, 0, 0);
    __syncthreads();                 // staged loads drained + rw hazards
  }
  // K-loop done; last barrier above makes staging LDS safe to reuse as `red`.

  float e2v[8];
  uint32_t inv[8];
#pragma unroll
  for (int nf = 0; nf < 8; ++nf) {
    int k = c0 + wc * 128 + nf * 16 + l15;
    e2v[nf] = e2f[k];
    inv[nf] = 2047u - (uint32_t)k;
  }

  const int colbase = wc * 16 + l15;
#pragma unroll
  for (int mf = 0; mf < 4; ++mf) {
#pragma unroll
    for (int reg = 0; reg < 4; ++reg) {
      uint32_t p0 = packBiased(fmaf(2.f, acc[mf][0][reg], e2v[0]), inv[0]);
      uint32_t p1 = packBiased(fmaf(2.f, acc[mf][1][reg], e2v[1]), inv[1]);
      uint32_t p2 = packBiased(fmaf(2.f, acc[mf][2][reg], e2v[2]), inv[2]);
      // sort3 init via 3-input ops (3 VALU, exact)
      uint32_t b  = max3u(p0, p1, p2);
      uint32_t s  = med3u(p0, p1, p2);
      uint32_t t3 = min3u(p0, p1, p2);
#pragma unroll
      for (int nf = 3; nf < 8; ++nf) {
        float f = fmaf(2.f, acc[mf][nf][reg], e2v[nf]);
        ins3u(b, s, t3, packBiased(f, inv[nf]));
      }
      const int row = wr * 64 + mf * 16 + lg * 4 + reg;
      uint32_t* p = &red[row * 100 + colbase * 3];
      p[0] = b; p[1] = s; p[2] = t3;
    }
  }
  __syncthreads();
  {
    const int row = tid >> 1, half = tid & 1;
    uint32_t b = 0u, s = 0u, t3 = 0u;
    const uint4* p4 = (const uint4*)&red[row * 100 + half * 48];   // 16B-aligned
#pragma unroll
    for (int c = 0; c < 12; ++c) {
      uint4 v = p4[c];
      ins3u(b, s, t3, v.x); ins3u(b, s, t3, v.y);
      ins3u(b, s, t3, v.z); ins3u(b, s, t3, v.w);
    }
    if (half) {
      uint32_t* q = &red[row * 100 + 96];
      q[0] = b; q[1] = s; q[2] = t3;
    }
    __syncthreads();
    if (!half) {
      const uint32_t* q = &red[row * 100 + 96];
      ins3u(b, s, t3, q[0]);
      ins3u(b, s, t3, q[1]);
      ins3u(b, s, t3, q[2]);
      size_t o = (size_t)by * N_TOK + n0 + row;
      pb[o] = b; ps[o] = s; pt[o] = t3;
    }
  }
}

// ---------------- merge 8 partials + candidates + final-row stats + key hists ----------------
__global__ void merge8(const uint32_t* __restrict__ pb, const uint32_t* __restrict__ ps,
                       const uint32_t* __restrict__ pt,
                       int* __restrict__ ind,
                       int* __restrict__ candRows, int* __restrict__ candIdx,
                       int* __restrict__ candCnt, int* __restrict__ listC,
                       uint32_t* __restrict__ cntA, uint32_t* __restrict__ cntC,
                       float* __restrict__ outcodes, uint32_t* __restrict__ cntTok,
                       const uint32_t* __restrict__ keys1, const uint32_t* __restrict__ keys2,
                       uint32_t* __restrict__ bcount1, uint32_t* __restrict__ bcount2) {
  int n = blockIdx.x * blockDim.x + threadIdx.x;
  if (n >= N_TOK) return;
  // permutation key histograms (moved here so e2split can zero the counters)
  atomicAdd(&bcount1[keys1[n] >> 21], 1u);
  atomicAdd(&bcount2[keys2[n] >> 21], 1u);
  uint32_t tb[8], tsv[8], ttv[8];
#pragma unroll
  for (int tt = 0; tt < 8; ++tt) {
    size_t o = (size_t)tt * N_TOK + n;
    tb[tt] = pb[o]; tsv[tt] = ps[o]; ttv[tt] = pt[o];
  }
  uint32_t best = tb[0];
#pragma unroll
  for (int tt = 1; tt < 8; ++tt) best = max(best, tb[tt]);
  int kb = 2047 - (int)(best & 0x7FFu);
  ind[n] = kb;   // provisional winner (final unless refined below)
  const uint32_t thr = packThrBiased(unpackBiased(best) - WND);
  int m = 0; bool full = false;
#pragma unroll
  for (int tt = 0; tt < 8; ++tt) {
    m += (tb[tt] >= thr) + (tsv[tt] >= thr);
    full = full || (ttv[tt] >= thr);   // a tile's unstored 3rd+ could be in-window
  }
  if (full) {
    listC[atomicAdd(cntC, 1u)] = n;
  } else if (m > 1) {
    uint32_t i = atomicAdd(cntA, 1u);
    candRows[i] = n; candCnt[i] = m;
    int j = 0;
#pragma unroll
    for (int tt = 0; tt < 8; ++tt) {
      if (tb[tt]  >= thr) candIdx[(size_t)i * 16 + (j++)] = 2047 - (int)(tb[tt]  & 0x7FFu);
      if (tsv[tt] >= thr) candIdx[(size_t)i * 16 + (j++)] = 2047 - (int)(tsv[tt] & 0x7FFu);
    }
  } else {
    // row is final here: codes + histogram
    outcodes[n] = (float)kb;
    atomicAdd(&cntTok[kb], 1u);
  }
}

// ---------------- fused refine: blocks [0,512) candidate path, [512,1536) full scan ----------------
#define RC_BLOCKS 512
#define RF_BLOCKS 1024
__global__ void refine_both(const float* __restrict__ x, const float* __restrict__ embed,
                            const double* __restrict__ e2d,
                            const int* __restrict__ candRows, const int* __restrict__ candIdx,
                            const int* __restrict__ candCnt,
                            const int* __restrict__ listC,
                            const uint32_t* __restrict__ cntAB,
                            int* __restrict__ ind,
                            float* __restrict__ outcodes, uint32_t* __restrict__ cntTok) {
  __shared__ double xd[DIMS];
  __shared__ double rv[256];
  __shared__ int    rk[256];
  const int tid = threadIdx.x;
  if (blockIdx.x < RC_BLOCKS) {
    // ---- wave-per-row f64 candidate decider ----
    const uint32_t nA = cntAB[0];
    const int lane = tid & 63;
    const uint32_t wid = ((uint32_t)blockIdx.x * 256 + tid) >> 6;
    const uint32_t nw = RC_BLOCKS * 4;
    for (uint32_t i = wid; i < nA; i += nw) {
      const int n = candRows[i];
      const int m = candCnt[i];
      float4 xv = ((const float4*)x)[(size_t)n * 64 + lane];
      double best = -1e300; int bk = 0x7fffffff;
      for (int j = 0; j < m; ++j) {
        int k = candIdx[(size_t)i * 16 + j];
        float4 e4 = ((const float4*)embed)[(size_t)k * 64 + lane];
        double d = (double)xv.x * e4.x + (double)xv.y * e4.y
                 + (double)xv.z * e4.z + (double)xv.w * e4.w;
#pragma unroll
        for (int mm = 1; mm < 64; mm <<= 1) d += __shfl_xor(d, mm);
        double v = 2.0 * d - e2d[k];
        if (v > best || (v == best && k < bk)) { best = v; bk = k; }
      }
      if (lane == 0) {
        ind[n] = bk;
        outcodes[n] = (float)bk;
        atomicAdd(&cntTok[bk], 1u);
      }
    }
    return;
  }
  // ---- full f64 re-scan, one row per block (rare) ----
  const uint32_t nC = cntAB[1];
  for (uint32_t it = blockIdx.x - RC_BLOCKS; it < nC; it += RF_BLOCKS) {
    const int n = listC[it];
    __syncthreads();
    xd[tid] = (double)x[(size_t)n * DIMS + tid];
    __syncthreads();
    double best = -1e300; int bk = 0x7fffffff;
    for (int k = tid; k < KCB; k += 256) {
      const float4* er = (const float4*)(embed + (size_t)k * DIMS);
      double a0 = 0.0, a1 = 0.0, a2 = 0.0, a3 = 0.0;   // ILP-4 chains
      for (int c = 0; c < 64; c += 4) {
        float4 ea = er[c], eb = er[c + 1], ec = er[c + 2], ed = er[c + 3];
        int d = c * 4;
        a0 += xd[d + 0] * ea.x + xd[d + 1] * ea.y + xd[d + 2] * ea.z + xd[d + 3] * ea.w;
        a1 += xd[d + 4] * eb.x + xd[d + 5] * eb.y + xd[d + 6] * eb.z + xd[d + 7] * eb.w;
        a2 += xd[d + 8] * ec.x + xd[d + 9] * ec.y + xd[d + 10] * ec.z + xd[d + 11] * ec.w;
        a3 += xd[d + 12] * ed.x + xd[d + 13] * ed.y + xd[d + 14] * ed.z + xd[d + 15] * ed.w;
      }
      double v = 2.0 * (a0 + a1 + a2 + a3) - e2d[k];
      if (v > best || (v == best && k < bk)) { best = v; bk = k; }
    }
    rv[tid] = best; rk[tid] = bk;
    __syncthreads();
    for (int s = 128; s > 0; s >>= 1) {
      if (tid < s) {
        double v2 = rv[tid + s]; int k2 = rk[tid + s];
        if (v2 > rv[tid] || (v2 == rv[tid] && k2 < rk[tid])) { rv[tid] = v2; rk[tid] = k2; }
      }
      __syncthreads();
    }
    if (tid == 0) {
      ind[n] = rk[0];
      outcodes[n] = (float)rk[0];
      atomicAdd(&cntTok[rk[0]], 1u);
    }
  }
}

// ---------------- fused: blocks 0-2 = three 2048-scans (+EMA), rest = outQ gather ----------------
__global__ void gather_scan(const float* __restrict__ embed, const int* __restrict__ ind,
                            float* __restrict__ outq,
                            const uint32_t* __restrict__ cntTok, uint32_t* __restrict__ tokBase,
                            uint32_t* __restrict__ tokCur,
                            const float* __restrict__ cs, float* __restrict__ out_ncs,
                            int* __restrict__ expired, double* __restrict__ nsum,
                            const uint32_t* __restrict__ bcount1, uint32_t* __restrict__ bbase1,
                            uint32_t* __restrict__ cursor1,
                            const uint32_t* __restrict__ bcount2, uint32_t* __restrict__ bbase2,
                            uint32_t* __restrict__ cursor2) {
  __shared__ uint32_t buf[2][2048];
  __shared__ double sd[1024];
  const int t = threadIdx.x;   // 1024
  if (blockIdx.x >= 3) {
    // pure gather over N_TOK*64 float4s
    int idx = (blockIdx.x - 3) * 1024 + t;
    if (idx < N_TOK * 64) {
      int n = idx >> 6, c = idx & 63;
      ((float4*)outq)[idx] = ((const float4*)embed)[(size_t)ind[n] * 64 + c];
    }
    return;
  }
  const uint32_t* in; uint32_t* out; uint32_t* cz;
  if (blockIdx.x == 0)      { in = cntTok;  out = tokBase; cz = tokCur;  }
  else if (blockIdx.x == 1) { in = bcount1; out = bbase1;  cz = cursor1; }
  else                      { in = bcount2; out = bbase2;  cz = cursor2; }
  double local = 0.0;
  for (int q = 0; q < 2; ++q) {
    int i = t + q * 1024;
    uint32_t c = in[i];
    buf[0][i] = c;
    cz[i] = 0;
    if (blockIdx.x == 0) {
      double v = 0.99 * (double)cs[i] + 0.01 * (double)c;
      out_ncs[i] = (float)v;
      expired[i] = (v < 2.0) ? 1 : 0;
      local += v;
    }
  }
  if (blockIdx.x == 0) sd[t] = local;
  __syncthreads();
  int src = 0;
  for (int off = 1; off < 2048; off <<= 1) {
    for (int q = 0; q < 2; ++q) {
      int i = t + q * 1024;
      uint32_t v = buf[src][i];
      if (i >= off) v += buf[src][i - off];
      buf[src ^ 1][i] = v;
    }
    src ^= 1; __syncthreads();
  }
  for (int q = 0; q < 2; ++q) {
    int i = t + q * 1024;
    out[i] = buf[src][i] - in[i];   // exclusive
  }
  if (blockIdx.x == 0) {
    for (int s = 512; s > 0; s >>= 1) { if (t < s) sd[t] += sd[t + s]; __syncthreads(); }
    if (t == 0) nsum[0] = sd[0];
  }
}

// ---------------- fused scatter: token buckets + round-1 key buckets ----------------
__global__ void scatter_both(const int* __restrict__ ind, const uint32_t* __restrict__ tokBase,
                             uint32_t* __restrict__ tokCur, uint32_t* __restrict__ tokBucket,
                             const uint32_t* __restrict__ keys1, const uint32_t* __restrict__ bbase1,
                             uint32_t* __restrict__ cursor1,
                             uint32_t* __restrict__ bkey, uint32_t* __restrict__ bval) {
  int n = blockIdx.x * blockDim.x + threadIdx.x;
  if (n >= N_TOK) return;
  int k = ind[n];
  uint32_t p = atomicAdd(&tokCur[k], 1u);
  tokBucket[tokBase[k] + p] = (uint32_t)n;
  uint32_t k1 = keys1[n];
  uint32_t b = k1 >> 21;
  uint32_t q = atomicAdd(&cursor1[b], 1u);
  uint32_t s = bbase1[b] + q;
  bkey[s] = k1; bval[s] = (uint32_t)n;   // value == tie-break position for round 1
}

// ---------------- fused: blocks [0,512) esum segment-sum (bf16 src), rest rank1+scatter2 ----------------
#define ES_BLOCKS 512
__global__ void esum_rank1(const unsigned short* __restrict__ xh, const uint32_t* __restrict__ tokBase,
                           const uint32_t* __restrict__ cntTok,
                           const uint32_t* __restrict__ tokBucket,
                           float* __restrict__ esum,
                           const uint32_t* __restrict__ bkey, const uint32_t* __restrict__ bval,
                           const uint32_t* __restrict__ bbase1, const uint32_t* __restrict__ bcount1,
                           const uint32_t* __restrict__ keys2,
                           const uint32_t* __restrict__ bbase2, uint32_t* __restrict__ cursor2,
                           uint32_t* __restrict__ bkey2, uint32_t* __restrict__ bval2,
                           uint32_t* __restrict__ bpos2) {
  const int tid = threadIdx.x;
  if (blockIdx.x < ES_BLOCKS) {
    // esum[k] = sum of x rows (bf16-rounded: err ~2e-4 on eavg, thr >= 3.9e-3)
    const uint32_t wv = ((uint32_t)blockIdx.x * 256 + tid) >> 6;
    const int lane = tid & 63;
    const uint32_t base = tokBase[wv], cnt = cntTok[wv];
    float4 a0 = {0.f, 0.f, 0.f, 0.f}, a1 = {0.f, 0.f, 0.f, 0.f};
    uint32_t i = 0;
    for (; i + 2 <= cnt; i += 2) {
      uint32_t n0 = tokBucket[base + i], n1 = tokBucket[base + i + 1];
      ushort4 h0 = ((const ushort4*)xh)[(size_t)n0 * 64 + lane];
      ushort4 h1 = ((const ushort4*)xh)[(size_t)n1 * 64 + lane];
      a0.x += bf16f(h0.x); a0.y += bf16f(h0.y); a0.z += bf16f(h0.z); a0.w += bf16f(h0.w);
      a1.x += bf16f(h1.x); a1.y += bf16f(h1.y); a1.z += bf16f(h1.z); a1.w += bf16f(h1.w);
    }
    if (i < cnt) {
      uint32_t n0 = tokBucket[base + i];
      ushort4 h0 = ((const ushort4*)xh)[(size_t)n0 * 64 + lane];
      a0.x += bf16f(h0.x); a0.y += bf16f(h0.y); a0.z += bf16f(h0.z); a0.w += bf16f(h0.w);
    }
    float4 r; r.x = a0.x + a1.x; r.y = a0.y + a1.y; r.z = a0.z + a1.z; r.w = a0.w + a1.w;
    ((float4*)esum)[(size_t)wv * 64 + lane] = r;
    return;
  }
  // rank round-1 elements (stable by (key,pos)) and scatter into round-2 buckets
  int b = blockIdx.x - ES_BLOCKS;   // [0, 2048)
  uint32_t base = bbase1[b], cnt = bcount1[b];
  for (uint32_t t = tid; t < cnt; t += 256) {
    uint32_t k = bkey[base + t], pv = bval[base + t];
    uint32_t r = 0;
    for (uint32_t j = 0; j < cnt; ++j) {
      uint32_t kj = bkey[base + j], pj = bval[base + j];
      r += (kj < k) | ((kj == k) & (pj < pv));
    }
    uint32_t p = base + r;          // global round-1 sorted position
    uint32_t k2 = keys2[p];
    uint32_t b2 = k2 >> 21;
    uint32_t q = atomicAdd(&cursor2[b2], 1u);
    uint32_t s = bbase2[b2] + q;
    bkey2[s] = k2; bval2[s] = pv; bpos2[s] = p;
  }
}

// ---------------- fused finalize: blocks [0,2048) rank2 (expired rows -> out_ne),
// blocks [2048,2560) EMA update + normalize (non-expired out_ne + out_eavg) ----------------
__global__ void finalize(const uint32_t* __restrict__ bkey2, const uint32_t* __restrict__ bval2,
                         const uint32_t* __restrict__ bpos2,
                         const uint32_t* __restrict__ bbase2, const uint32_t* __restrict__ bcount2,
                         const int* __restrict__ expired, const float* __restrict__ x,
                         const float* __restrict__ cs, const uint32_t* __restrict__ cntTok,
                         const float* __restrict__ eavg, const float* __restrict__ esum,
                         const double* __restrict__ nsum,
                         float* __restrict__ out_eavg, float* __restrict__ out_ne) {
  const int tid = threadIdx.x;
  if (blockIdx.x < KCB) {
    // ---- round-2 rank; expired rows written directly to out_ne ----
    int b = blockIdx.x;
    uint32_t base = bbase2[b];
    if (base >= KCB) return;          // every element lands at position >= 2048
    uint32_t cnt = bcount2[b];
    for (uint32_t t = tid; t < cnt; t += 256) {
      uint32_t k = bkey2[base + t], p = bpos2[base + t];
      uint32_t r = 0;
      for (uint32_t j = 0; j < cnt; ++j) {
        uint32_t kj = bkey2[base + j], pj = bpos2[base + j];
        r += (kj < k) | ((kj == k) & (pj < p));
      }
      uint32_t pos = base + r;
      if (pos < KCB && expired[pos]) {
        uint32_t val = bval2[base + t];         // perm[pos] = token id
        const float4* src = (const float4*)x + (size_t)val * 64;
        float4* dst = (float4*)out_ne + (size_t)pos * 64;
        for (int c = 0; c < 64; ++c) dst[c] = src[c];
      }
    }
    return;
  }
  // ---- new_embed_avg + new_embed (non-expired rows) ----
  int idx = (blockIdx.x - KCB) * 256 + tid;   // over KCB*64 float4s
  if (idx >= KCB * 64) return;
  int k = idx >> 6;
  float4 ea = ((const float4*)eavg)[idx];
  float4 es = ((const float4*)esum)[idx];
  double ax = 0.99 * (double)ea.x + 0.01 * (double)es.x;
  double ay = 0.99 * (double)ea.y + 0.01 * (double)es.y;
  double az = 0.99 * (double)ea.z + 0.01 * (double)es.z;
  double aw = 0.99 * (double)ea.w + 0.01 * (double)es.w;
  float4 nv; nv.x = (float)ax; nv.y = (float)ay; nv.z = (float)az; nv.w = (float)aw;
  ((float4*)out_eavg)[idx] = nv;
  if (!expired[k]) {
    double ncs = 0.99 * (double)cs[k] + 0.01 * (double)cntTok[k];
    double n = nsum[0];
    double sm = (ncs + 1e-5) / (n + 2048.0 * 1e-5) * n;
    float4 r;
    r.x = (float)(ax / sm); r.y = (float)(ay / sm);
    r.z = (float)(az / sm); r.w = (float)(aw / sm);
    ((float4*)out_ne)[idx] = r;
  }
}

// ---------------- launch ----------------
extern "C" void kernel_launch(void* const* d_in, const int* in_sizes, int n_in,
                              void* d_out, int out_size, void* d_ws, size_t ws_size,
                              hipStream_t stream) {
  const float* x     = (const float*)d_in[0];
  const float* embed = (const float*)d_in[1];
  const float* cs    = (const float*)d_in[2];
  const float* eavg  = (const float*)d_in[3];

  float* out = (float*)d_out;
  float* outQ    = out;                  // 12,288,000
  float* outC    = out + 12288000;       // 48,000
  float* outNCS  = out + 12336000;       // 2,048
  float* outEAVG = out + 12338048;       // 524,288
  float* outNE   = out + 12862336;       // 524,288

  char* w = (char*)d_ws;
  size_t off = 0;
  auto alloc = [&](size_t bytes) -> void* {
    void* p = w + off; off += (bytes + 255) & ~(size_t)255; return p;
  };
  unsigned short* xh = (unsigned short*)alloc((size_t)N_TOK * DIMS * 2);
  unsigned short* eh = (unsigned short*)alloc((size_t)KCB * DIMS * 2);
  float*    e2f     = (float*)alloc(KCB * 4);
  double*   e2d     = (double*)alloc(KCB * 8);
  float*    esum    = (float*)alloc((size_t)KCB * DIMS * 4);
  uint32_t* pbest   = (uint32_t*)alloc((size_t)8 * N_TOK * 4);
  uint32_t* psecond = (uint32_t*)alloc((size_t)8 * N_TOK * 4);
  uint32_t* pthird  = (uint32_t*)alloc((size_t)8 * N_TOK * 4);
  int*      ind     = (int*)alloc(N_TOK * 4);
  int*      candRows= (int*)alloc(N_TOK * 4);
  int*      candCnt = (int*)alloc(N_TOK * 4);
  int*      candIdx = (int*)alloc((size_t)N_TOK * 16 * 4);
  int*      listC   = (int*)alloc(N_TOK * 4);
  double*   nsum    = (double*)alloc(256);
  int*      expired = (int*)alloc(KCB * 4);
  uint32_t* tokBase = (uint32_t*)alloc(KCB * 4);
  uint32_t* tokCur  = (uint32_t*)alloc(KCB * 4);
  uint32_t* tokBucket = (uint32_t*)alloc(N_TOK * 4);
  uint32_t* keys1   = (uint32_t*)alloc(N_TOK * 4);
  uint32_t* keys2   = (uint32_t*)alloc(N_TOK * 4);
  uint32_t* bkey    = (uint32_t*)alloc(N_TOK * 4);
  uint32_t* bval    = (uint32_t*)alloc(N_TOK * 4);
  uint32_t* bkey2   = (uint32_t*)alloc(N_TOK * 4);
  uint32_t* bval2   = (uint32_t*)alloc(N_TOK * 4);
  uint32_t* bpos2   = (uint32_t*)alloc(N_TOK * 4);
  uint32_t* bbase1  = (uint32_t*)alloc(KCB * 4);
  uint32_t* bbase2  = (uint32_t*)alloc(KCB * 4);
  uint32_t* cursor1 = (uint32_t*)alloc(KCB * 4);
  uint32_t* cursor2 = (uint32_t*)alloc(KCB * 4);
  // contiguous zero region: cntAB(256B=64 u32) | cntTok | bcount1 | bcount2 = 6208 u32
  uint32_t* cntAB   = (uint32_t*)alloc(256);
  uint32_t* cntTok  = (uint32_t*)alloc(KCB * 4);
  uint32_t* bcount1 = (uint32_t*)alloc(KCB * 4);
  uint32_t* bcount2 = (uint32_t*)alloc(KCB * 4);

  // split + e2 + permutation keys + counter zeroing (one kernel, no memset)
  e2split_keys<<<(N_TOK * DIMS / 8 + KCB * DIMS / 8 + KCB + N_TOK + NZERO + 255) / 256,
                 256, 0, stream>>>(x, xh, embed, eh, e2f, e2d, keys1, keys2, cntAB);

  dist_mfma<<<3000, 256, 0, stream>>>(xh, eh, e2f, pbest, psecond, pthird);
  merge8<<<188, 256, 0, stream>>>(pbest, psecond, pthird,
                                  ind, candRows, candIdx, candCnt, listC,
                                  &cntAB[0], &cntAB[1], outC, cntTok,
                                  keys1, keys2, bcount1, bcount2);
  refine_both<<<RC_BLOCKS + RF_BLOCKS, 256, 0, stream>>>(
      x, embed, e2d, candRows, candIdx, candCnt, listC, cntAB, ind, outC, cntTok);

  // blocks 0-2: scans (token + both key rounds) + EMA; blocks 3+: outQ gather
  gather_scan<<<3 + (N_TOK * 64 + 1023) / 1024, 1024, 0, stream>>>(
      embed, ind, outQ,
      cntTok, tokBase, tokCur, cs, outNCS, expired, nsum,
      bcount1, bbase1, cursor1, bcount2, bbase2, cursor2);
  scatter_both<<<188, 256, 0, stream>>>(ind, tokBase, tokCur, tokBucket,
                                        keys1, bbase1, cursor1, bkey, bval);
  esum_rank1<<<ES_BLOCKS + KCB, 256, 0, stream>>>(
      xh, tokBase, cntTok, tokBucket, esum,
      bkey, bval, bbase1, bcount1, keys2, bbase2, cursor2, bkey2, bval2, bpos2);

  // rank2 (expired -> out_ne) + EMA normalize (non-expired) in one kernel
  finalize<<<KCB + KCB / 4, 256, 0, stream>>>(
      bkey2, bval2, bpos2, bbase2, bcount2, expired, x,
      cs, cntTok, eavg, esum, nsum, outEAVG, outNE);
}